// Round 1
// 743.568 us; speedup vs baseline: 1.0266x; 1.0266x over previous
//
#include <hip/hip_runtime.h>
#include <hip/hip_bf16.h>
#include <math.h>

// B=32, N=1024, D=H=E=C=256, K_top=128, TEMP=0.1, EPS=1e-15

typedef short bf16x8 __attribute__((ext_vector_type(8)));   // 8 bf16 raw bits (4 VGPRs)
typedef float f32x4 __attribute__((ext_vector_type(4)));

__device__ inline void gl_lds16(const void* g, void* l) {
    __builtin_amdgcn_global_load_lds(
        (const __attribute__((address_space(1))) void*)g,
        (__attribute__((address_space(3))) void*)l, 16, 0, 0);
}

__device__ inline unsigned short f2b(float f) {
    union { __hip_bfloat16 h; unsigned short u; } cv;
    cv.h = __float2bfloat16(f);
    return cv.u;
}
__device__ inline float b2f(unsigned short u) {
    union { unsigned short u; __hip_bfloat16 h; } cv;
    cv.u = u;
    return __bfloat162float(cv.h);
}

// ---------------------------------------------------------------------------
// Streaming adj pass: one wave per 1024-wide row. fp32 -> bf16 convert,
// per-row reciprocal degree (1/max(sum,1)) via wave shuffle reduce, and
// sum-of-squares partials (one per block). No LDS tiles, no atomics.
__global__ __launch_bounds__(256) void adjconv_kernel(
    const float* __restrict__ adj, unsigned short* __restrict__ adj_bf,
    float* __restrict__ deginv, float* __restrict__ asq_part) {
    __shared__ float sq_red[4];
    const int tid = threadIdx.x;
    const int wave = tid >> 6, lane = tid & 63;
    const long long row = (long long)blockIdx.x * 4 + wave;   // 0..32767
    const float* ip = adj + row * 1024;
    unsigned short* op = adj_bf + row * 1024;
    float sum = 0.f, sq = 0.f;
#pragma unroll
    for (int i = 0; i < 4; ++i) {
        const float4 v = *(const float4*)(ip + i * 256 + lane * 4);
        ushort4 h;
        h.x = f2b(v.x); h.y = f2b(v.y); h.z = f2b(v.z); h.w = f2b(v.w);
        *(ushort4*)(op + i * 256 + lane * 4) = h;
        sum += v.x + v.y + v.z + v.w;
        sq = fmaf(v.x, v.x, sq);
        sq = fmaf(v.y, v.y, sq);
        sq = fmaf(v.z, v.z, sq);
        sq = fmaf(v.w, v.w, sq);
    }
#pragma unroll
    for (int off = 32; off > 0; off >>= 1) {
        sum += __shfl_xor(sum, off);
        sq  += __shfl_xor(sq, off);
    }
    if (lane == 0) {
        deginv[row] = 1.0f / fmaxf(sum, 1.0f);
        sq_red[wave] = sq;
    }
    __syncthreads();
    if (tid == 0)
        asq_part[blockIdx.x] = sq_red[0] + sq_red[1] + sq_red[2] + sq_red[3];
}

// ---------------------------------------------------------------------------
// Tiled convert/transpose: fp32 [R,C] -> optional bf16 same layout (outN),
// optional bf16 transpose (outT), optional row sums (deg), optional sum of
// squares per block (sqpart).
__global__ __launch_bounds__(256) void convt_kernel(
    const float* __restrict__ in, long long sIn, int ldin,
    unsigned short* __restrict__ outN, long long sN,
    unsigned short* __restrict__ outT, long long sT, int ldT,
    float* __restrict__ rowsum, long long sRS,
    float* __restrict__ sqpart) {
    __shared__ float tile[64][65];
    __shared__ float rsum[64];
    __shared__ float sred[256];
    const int tid = threadIdx.x;
    const long long bz = blockIdx.z;
    const int rowBase = blockIdx.y * 64, colBase = blockIdx.x * 64;
    const float* ip = in + bz * sIn;
    if (rowsum && tid < 64) rsum[tid] = 0.f;
    __syncthreads();
    float sq = 0.f;
#pragma unroll
    for (int i = 0; i < 4; ++i) {
        int r = (tid >> 4) * 4 + i;
        const float4 v = *(const float4*)(ip + (long long)(rowBase + r) * ldin + colBase + (tid & 15) * 4);
        tile[r][(tid & 15) * 4 + 0] = v.x;
        tile[r][(tid & 15) * 4 + 1] = v.y;
        tile[r][(tid & 15) * 4 + 2] = v.z;
        tile[r][(tid & 15) * 4 + 3] = v.w;
        if (outN) {
            ushort4 h;
            h.x = f2b(v.x); h.y = f2b(v.y); h.z = f2b(v.z); h.w = f2b(v.w);
            *(ushort4*)(outN + bz * sN + (long long)(rowBase + r) * ldin + colBase + (tid & 15) * 4) = h;
        }
        if (rowsum) atomicAdd(&rsum[r], v.x + v.y + v.z + v.w);
        if (sqpart) sq += v.x * v.x + v.y * v.y + v.z * v.z + v.w * v.w;
    }
    __syncthreads();
    if (rowsum && tid < 64) atomicAdd(&rowsum[bz * sRS + rowBase + tid], rsum[tid]);
    if (outT) {
#pragma unroll
        for (int i = 0; i < 4; ++i) {
            int oc = (tid >> 4) * 4 + i;
            ushort4 h;
            h.x = f2b(tile[(tid & 15) * 4 + 0][oc]);
            h.y = f2b(tile[(tid & 15) * 4 + 1][oc]);
            h.z = f2b(tile[(tid & 15) * 4 + 2][oc]);
            h.w = f2b(tile[(tid & 15) * 4 + 3][oc]);
            *(ushort4*)(outT + bz * sT + (long long)(colBase + oc) * ldT + rowBase + (tid & 15) * 4) = h;
        }
    }
    if (sqpart) {
        sred[tid] = sq;
        __syncthreads();
        for (int k = 128; k > 0; k >>= 1) {
            if (tid < k) sred[tid] += sred[tid + k];
            __syncthreads();
        }
        if (tid == 0)
            sqpart[((long long)bz * gridDim.y + blockIdx.y) * gridDim.x + blockIdx.x] = sred[0];
    }
}

// bf16 -> bf16 transpose, 64x64 tiles
__global__ __launch_bounds__(256) void tbf16_kernel(
    const unsigned short* __restrict__ in, long long sIn, int ldin,
    unsigned short* __restrict__ outT, long long sT, int ldT) {
    __shared__ unsigned short tile[64][68];
    const int tid = threadIdx.x;
    const long long bz = blockIdx.z;
    const int rowBase = blockIdx.y * 64, colBase = blockIdx.x * 64;
    const unsigned short* ip = in + bz * sIn;
#pragma unroll
    for (int i = 0; i < 4; ++i) {
        int r = (tid >> 4) * 4 + i, c4 = (tid & 15) * 4;
        ushort4 v = *(const ushort4*)(ip + (long long)(rowBase + r) * ldin + colBase + c4);
        tile[r][c4 + 0] = v.x; tile[r][c4 + 1] = v.y;
        tile[r][c4 + 2] = v.z; tile[r][c4 + 3] = v.w;
    }
    __syncthreads();
#pragma unroll
    for (int i = 0; i < 4; ++i) {
        int oc = (tid >> 4) * 4 + i;
        ushort4 h;
        h.x = tile[(tid & 15) * 4 + 0][oc];
        h.y = tile[(tid & 15) * 4 + 1][oc];
        h.z = tile[(tid & 15) * 4 + 2][oc];
        h.w = tile[(tid & 15) * 4 + 3][oc];
        *(ushort4*)(outT + bz * sT + (long long)(colBase + oc) * ldT + rowBase + (tid & 15) * 4) = h;
    }
}

// 6 weight matrices [256,256] -> transposed bf16
struct WPtrs { const float* in[6]; unsigned short* out[6]; };
__global__ __launch_bounds__(256) void wconv_kernel(WPtrs wp) {
    __shared__ float tile[64][65];
    const int tid = threadIdx.x;
    const float* in = wp.in[blockIdx.z];
    unsigned short* out = wp.out[blockIdx.z];
    const int rowBase = blockIdx.y * 64, colBase = blockIdx.x * 64;
#pragma unroll
    for (int i = 0; i < 4; ++i) {
        int r = (tid >> 4) * 4 + i;
        const float4 v = *(const float4*)(in + (long long)(rowBase + r) * 256 + colBase + (tid & 15) * 4);
        tile[r][(tid & 15) * 4 + 0] = v.x;
        tile[r][(tid & 15) * 4 + 1] = v.y;
        tile[r][(tid & 15) * 4 + 2] = v.z;
        tile[r][(tid & 15) * 4 + 3] = v.w;
    }
    __syncthreads();
#pragma unroll
    for (int i = 0; i < 4; ++i) {
        int oc = (tid >> 4) * 4 + i;
        ushort4 h;
        h.x = f2b(tile[(tid & 15) * 4 + 0][oc]);
        h.y = f2b(tile[(tid & 15) * 4 + 1][oc]);
        h.z = f2b(tile[(tid & 15) * 4 + 2][oc]);
        h.w = f2b(tile[(tid & 15) * 4 + 3][oc]);
        *(ushort4*)(out + (long long)(colBase + oc) * 256 + rowBase + (tid & 15) * 4) = h;
    }
}

// ---------------------------------------------------------------------------
// MFMA GEMM: C[M,N] = A1[M,K1]·B1t[N,K1]^T (+ A2·B2t^T) (+bias) (*rowscale)
// Optional trace-dot epilogue: dot_part[block] = sum(out ∘ dotT^T).
struct GemmP {
    const unsigned short* A1; long long sA1; int lda1; int K1;
    const unsigned short* B1; long long sB1; int ldb1;
    const unsigned short* A2; long long sA2; int lda2; int K2;
    const unsigned short* B2; long long sB2; int ldb2;
    float* outF; long long sF;
    unsigned short* outH; long long sH;
    int ldc;
    const float* bias;
    const float* rowscale; long long sRS;
    const float* dotT; long long sDot;
    float* dot_part;
};

__global__ __launch_bounds__(256) void gemm_mfma(GemmP p) {
    __shared__ short As[128 * 32];
    __shared__ short Bs[128 * 32];
    __shared__ float dred[256];
    const int tid = threadIdx.x;
    const int wave = tid >> 6, lane = tid & 63;
    const int quad = lane >> 4, l15 = lane & 15;
    const int wm = (wave & 1) * 64, wn = (wave >> 1) * 64;
    const long long bz = blockIdx.z;
    const int rowBase = blockIdx.y * 128, colBase = blockIdx.x * 128;
    const int srow = tid >> 2;
    const int skg = (tid & 3) * 8;

    f32x4 acc[4][4] = {{{0.f}}};
    char* ldsA0 = (char*)As + wave * 1024;
    char* ldsA1 = (char*)As + 4096 + wave * 1024;
    char* ldsB0 = (char*)Bs + wave * 1024;
    char* ldsB1 = (char*)Bs + 4096 + wave * 1024;

    for (int pass = 0; pass < 2; ++pass) {
        const unsigned short* Aop;
        const unsigned short* Bop;
        int lda, ldb, K;
        if (pass == 0) {
            Aop = p.A1 + bz * p.sA1; Bop = p.B1 + bz * p.sB1;
            lda = p.lda1; ldb = p.ldb1; K = p.K1;
        } else {
            if (!p.A2) break;
            Aop = p.A2 + bz * p.sA2; Bop = p.B2 + bz * p.sB2;
            lda = p.lda2; ldb = p.ldb2; K = p.K2;
        }
        const unsigned short* Ab0 = Aop + (long long)(rowBase + srow) * lda + skg;
        const unsigned short* Ab1 = Aop + (long long)(rowBase + 64 + srow) * lda + skg;
        const unsigned short* Bb0 = Bop + (long long)(colBase + srow) * ldb + skg;
        const unsigned short* Bb1 = Bop + (long long)(colBase + 64 + srow) * ldb + skg;
        for (int k0 = 0; k0 < K; k0 += 32) {
            gl_lds16(Ab0 + k0, ldsA0);
            gl_lds16(Ab1 + k0, ldsA1);
            gl_lds16(Bb0 + k0, ldsB0);
            gl_lds16(Bb1 + k0, ldsB1);
            __syncthreads();
            bf16x8 af[4], bf[4];
#pragma unroll
            for (int i = 0; i < 4; ++i)
                af[i] = *(const bf16x8*)(As + (wm + i * 16 + l15) * 32 + quad * 8);
#pragma unroll
            for (int j = 0; j < 4; ++j)
                bf[j] = *(const bf16x8*)(Bs + (wn + j * 16 + l15) * 32 + quad * 8);
#pragma unroll
            for (int i = 0; i < 4; ++i)
#pragma unroll
                for (int j = 0; j < 4; ++j)
                    acc[i][j] = __builtin_amdgcn_mfma_f32_16x16x32_bf16(af[i], bf[j], acc[i][j], 0, 0, 0);
            __syncthreads();
        }
    }

    float* oF = p.outF ? p.outF + bz * p.sF : nullptr;
    unsigned short* oH = p.outH ? p.outH + bz * p.sH : nullptr;
    const float* dT = p.dotT ? p.dotT + bz * p.sDot : nullptr;
    float bcol[4];
#pragma unroll
    for (int j = 0; j < 4; ++j)
        bcol[j] = p.bias ? p.bias[colBase + wn + j * 16 + l15] : 0.0f;
    const float* rs = p.rowscale ? p.rowscale + bz * p.sRS : nullptr;
    float dacc = 0.f;
#pragma unroll
    for (int i = 0; i < 4; ++i) {
#pragma unroll
        for (int r = 0; r < 4; ++r) {
            int row = rowBase + wm + i * 16 + quad * 4 + r;
            float sc = rs ? rs[row] : 1.0f;
            long long ro = (long long)row * p.ldc;
#pragma unroll
            for (int j = 0; j < 4; ++j) {
                int col = colBase + wn + j * 16 + l15;
                float v = (acc[i][j][r] + bcol[j]) * sc;
                if (oF) oF[ro + col] = v;
                if (oH) oH[ro + col] = f2b(v);
                if (dT) dacc = fmaf(v, dT[(long long)col * p.ldc + row], dacc);
            }
        }
    }
    if (p.dot_part) {
        dred[tid] = dacc;
        __syncthreads();
        for (int k = 128; k > 0; k >>= 1) {
            if (tid < k) dred[tid] += dred[tid + k];
            __syncthreads();
        }
        if (tid == 0)
            p.dot_part[((long long)bz * gridDim.y + blockIdx.y) * gridDim.x + blockIdx.x] = dred[0];
    }
}

// ---------------------------------------------------------------------------
// G = sT · sT^T via MFMA; writes G bf16 and reduces ssq = sum(G^2), tr = trace
// partials per block (clu closed form + link ssq term).
__global__ __launch_bounds__(256) void sts_clu_mfma(
    const unsigned short* __restrict__ sT, unsigned short* __restrict__ gout,
    float* __restrict__ ssq_part, float* __restrict__ tr_part) {
    __shared__ short As[128 * 32];
    __shared__ short Bs[128 * 32];
    __shared__ float red[2][256];
    const int tid = threadIdx.x;
    const int wave = tid >> 6, lane = tid & 63;
    const int quad = lane >> 4, l15 = lane & 15;
    const int wm = (wave & 1) * 64, wn = (wave >> 1) * 64;
    const long long bz = blockIdx.z;
    const unsigned short* S = sT + bz * 262144;
    const int rowBase = blockIdx.y * 128, colBase = blockIdx.x * 128;
    const int srow = tid >> 2, skg = (tid & 3) * 8;

    f32x4 acc[4][4] = {{{0.f}}};
    const unsigned short* Ab0 = S + (long long)(rowBase + srow) * 1024 + skg;
    const unsigned short* Ab1 = S + (long long)(rowBase + 64 + srow) * 1024 + skg;
    const unsigned short* Bb0 = S + (long long)(colBase + srow) * 1024 + skg;
    const unsigned short* Bb1 = S + (long long)(colBase + 64 + srow) * 1024 + skg;
    for (int k0 = 0; k0 < 1024; k0 += 32) {
        gl_lds16(Ab0 + k0, (char*)As + wave * 1024);
        gl_lds16(Ab1 + k0, (char*)As + 4096 + wave * 1024);
        gl_lds16(Bb0 + k0, (char*)Bs + wave * 1024);
        gl_lds16(Bb1 + k0, (char*)Bs + 4096 + wave * 1024);
        __syncthreads();
        bf16x8 af[4], bf[4];
#pragma unroll
        for (int i = 0; i < 4; ++i)
            af[i] = *(const bf16x8*)(As + (wm + i * 16 + l15) * 32 + quad * 8);
#pragma unroll
        for (int j = 0; j < 4; ++j)
            bf[j] = *(const bf16x8*)(Bs + (wn + j * 16 + l15) * 32 + quad * 8);
#pragma unroll
        for (int i = 0; i < 4; ++i)
#pragma unroll
            for (int j = 0; j < 4; ++j)
                acc[i][j] = __builtin_amdgcn_mfma_f32_16x16x32_bf16(af[i], bf[j], acc[i][j], 0, 0, 0);
        __syncthreads();
    }
    unsigned short* go = gout + bz * 65536;
    float ssq = 0.f, tr = 0.f;
#pragma unroll
    for (int i = 0; i < 4; ++i)
#pragma unroll
        for (int r = 0; r < 4; ++r) {
            int row = rowBase + wm + i * 16 + quad * 4 + r;
#pragma unroll
            for (int j = 0; j < 4; ++j) {
                int col = colBase + wn + j * 16 + l15;
                float v = acc[i][j][r];
                go[(long long)row * 256 + col] = f2b(v);
                ssq = fmaf(v, v, ssq);
                if (row == col) tr += v;
            }
        }
    red[0][tid] = ssq;
    red[1][tid] = tr;
    __syncthreads();
    for (int k = 128; k > 0; k >>= 1) {
        if (tid < k) {
            red[0][tid] += red[0][tid + k];
            red[1][tid] += red[1][tid + k];
        }
        __syncthreads();
    }
    if (tid == 0) {
        int bid = (int)(blockIdx.z * 4 + blockIdx.y * 2 + blockIdx.x);
        ssq_part[bid] = red[0][0];
        tr_part[bid] = red[1][0];
    }
}

// ---------------------------------------------------------------------------
// bf16 elementwise dot over 8,388,608 elems -> per-block partials [1024]
__global__ __launch_bounds__(256) void dot_bf_kernel(const unsigned short* __restrict__ a,
                                                     const unsigned short* __restrict__ b,
                                                     float* __restrict__ part) {
    __shared__ float red[256];
    int tid = threadIdx.x;
    long long base = (long long)blockIdx.x * 8192;
    float acc = 0.f;
#pragma unroll
    for (int i = 0; i < 8; ++i) {
        long long off = base + i * 1024 + tid * 4;
        ushort4 va = *(const ushort4*)(a + off);
        ushort4 vb = *(const ushort4*)(b + off);
        acc = fmaf(b2f(va.x), b2f(vb.x), acc);
        acc = fmaf(b2f(va.y), b2f(vb.y), acc);
        acc = fmaf(b2f(va.z), b2f(vb.z), acc);
        acc = fmaf(b2f(va.w), b2f(vb.w), acc);
    }
    red[tid] = acc;
    __syncthreads();
    for (int k = 128; k > 0; k >>= 1) {
        if (tid < k) red[tid] += red[tid + k];
        __syncthreads();
    }
    if (tid == 0) part[blockIdx.x] = red[0];
}

// ---------------------------------------------------------------------------
// l2-normalize each 256-wide row then relu; bf16, in-place.
__global__ __launch_bounds__(256) void l2relu_bf_kernel(unsigned short* __restrict__ buf) {
    __shared__ float red[256];
    long long row = blockIdx.x;
    int tid = threadIdx.x;
    float v = b2f(buf[row * 256 + tid]);
    red[tid] = v * v;
    __syncthreads();
    for (int k = 128; k > 0; k >>= 1) {
        if (tid < k) red[tid] += red[tid + k];
        __syncthreads();
    }
    float rn = 1.0f / fmaxf(sqrtf(red[0]), 1e-12f);
    buf[row * 256 + tid] = f2b(fmaxf(v * rn, 0.0f));
}

__global__ __launch_bounds__(256) void softmax_kernel(float* __restrict__ s) {
    __shared__ float red[256];
    long long row = blockIdx.x;
    int tid = threadIdx.x;
    float v = s[row * 256 + tid];
    red[tid] = v;
    __syncthreads();
    for (int k = 128; k > 0; k >>= 1) {
        if (tid < k) red[tid] = fmaxf(red[tid], red[tid + k]);
        __syncthreads();
    }
    float m = red[0];
    __syncthreads();
    float e = expf(v - m);
    red[tid] = e;
    __syncthreads();
    for (int k = 128; k > 0; k >>= 1) {
        if (tid < k) red[tid] += red[tid + k];
        __syncthreads();
    }
    s[row * 256 + tid] = e / red[0];
}

// scores[b,c] = sum_n s[b,n,c]
__global__ __launch_bounds__(256) void scores_kernel(const float* __restrict__ s,
                                                     float* __restrict__ scores) {
    int b = blockIdx.x, chunk = blockIdx.y, c = threadIdx.x;
    const float* base = s + (long long)b * 262144 + (long long)chunk * 32 * 256 + c;
    float acc = 0.f;
#pragma unroll
    for (int i = 0; i < 32; ++i) acc += base[i * 256];
    atomicAdd(&scores[b * 256 + c], acc);
}

__global__ __launch_bounds__(256) void topk_kernel(const float* __restrict__ scores,
                                                   float* __restrict__ thresh) {
    __shared__ float vals[256];
    int b = blockIdx.x, tid = threadIdx.x;
    float v = scores[b * 256 + tid];
    vals[tid] = v;
    __syncthreads();
    int rank = 0;
    for (int j = 0; j < 256; ++j) {
        float u = vals[j];
        rank += (u > v) || (u == v && j < tid);
    }
    if (rank == 127) thresh[b] = v;
}

__global__ __launch_bounds__(256) void gate_kernel(const float* __restrict__ scores,
                                                   const float* __restrict__ thresh,
                                                   float* __restrict__ gate) {
    int b = blockIdx.x, c = threadIdx.x;
    float z = (scores[b * 256 + c] - thresh[b]) * 10.0f;  // 1/TEMP
    gate[b * 256 + c] = 1.0f / (1.0f + expf(-z));
}

// s *= gate (fp32, in place) + bf16 copy + entropy partials
__global__ __launch_bounds__(256) void gate_ent_kernel(float* __restrict__ s,
                                                       const float* __restrict__ gate,
                                                       unsigned short* __restrict__ sbf,
                                                       float* __restrict__ ent_part) {
    __shared__ float red[256];
    int tid = threadIdx.x;
    long long row = blockIdx.x;
    int b = blockIdx.x >> 10;
    float v = s[row * 256 + tid] * gate[b * 256 + tid];
    s[row * 256 + tid] = v;
    sbf[row * 256 + tid] = f2b(v);
    red[tid] = -v * logf(v + 1e-15f);
    __syncthreads();
    for (int k = 128; k > 0; k >>= 1) {
        if (tid < k) red[tid] += red[tid + k];
        __syncthreads();
    }
    if (tid == 0) ent_part[blockIdx.x] = red[0];
}

// ---------------------------------------------------------------------------
__global__ __launch_bounds__(256) void finalize_kernel(const float* __restrict__ ent_part,
                                                       const float* __restrict__ asq_part,
                                                       const float* __restrict__ psq_part,
                                                       const float* __restrict__ sdot_part,
                                                       const float* __restrict__ trq_part,
                                                       const float* __restrict__ ssq_part,
                                                       const float* __restrict__ tr_part,
                                                       float* __restrict__ scal) {
    __shared__ float red[7][256];
    int tid = threadIdx.x;
    float e = 0.f, asq = 0.f, psq = 0.f, sd = 0.f, tq = 0.f, clu = 0.f, ssqa = 0.f;
    for (int i = tid; i < 32768; i += 256) e += ent_part[i];
    for (int i = tid; i < 8192; i += 256) asq += asq_part[i];
    for (int i = tid; i < 512; i += 256) psq += psq_part[i];
    for (int i = tid; i < 1024; i += 256) sd += sdot_part[i];
    if (tid < 128) tq = trq_part[tid];
    if (tid < 32) {
        float ssq = 0.f, tr = 0.f;
#pragma unroll
        for (int i = 0; i < 4; ++i) {
            ssq += ssq_part[tid * 4 + i];
            tr  += tr_part[tid * 4 + i];
        }
        ssqa = ssq;
        float fro = fmaxf(sqrtf(ssq), 1e-12f);
        float val = ssq / (fro * fro) - tr / (8.0f * fro) + 1.0f;  // ||G/fro - I/16||_F^2
        clu = sqrtf(fmaxf(val, 0.0f));
    }
    red[0][tid] = e; red[1][tid] = asq; red[2][tid] = psq; red[3][tid] = sd;
    red[4][tid] = tq; red[5][tid] = clu; red[6][tid] = ssqa;
    __syncthreads();
    for (int k = 128; k > 0; k >>= 1) {
        if (tid < k) {
#pragma unroll
            for (int q = 0; q < 7; ++q) red[q][tid] += red[q][tid + k];
        }
        __syncthreads();
    }
    if (tid == 0) {
        const float numel = 33554432.0f;  // B*N*N
        float linksq  = red[1][0] - 2.0f * red[3][0] + red[6][0];   // asq - 2<S,AS> + ||G||^2
        float reconsq = red[1][0] - 2.0f * red[2][0] + red[4][0];   // asq - 2||P||^2 + tr(GP'GP)
        scal[0] = sqrtf(fmaxf(linksq, 0.0f)) / numel;   // link
        scal[1] = red[0][0] / 32768.0f;                 // ent
        scal[2] = red[5][0] / 32.0f;                    // clu
        scal[3] = sqrtf(fmaxf(reconsq, 0.0f)) / numel;  // recon
    }
}

// ---------------------------------------------------------------------------
extern "C" void kernel_launch(void* const* d_in, const int* in_sizes, int n_in,
                              void* d_out, int out_size, void* d_ws, size_t ws_size,
                              hipStream_t stream) {
    const float* x    = (const float*)d_in[0];
    const float* adj  = (const float*)d_in[1];
    const float* Wr_p = (const float*)d_in[2];
    const float* br_p = (const float*)d_in[3];
    const float* Wo_p = (const float*)d_in[4];
    const float* Wl_p = (const float*)d_in[5];
    const float* bl_p = (const float*)d_in[6];
    const float* Wr_e = (const float*)d_in[7];
    const float* br_e = (const float*)d_in[8];
    const float* Wo_e = (const float*)d_in[9];
    const float* Wl_e = (const float*)d_in[10];
    const float* bl_e = (const float*)d_in[11];

    float* out    = (float*)d_out;
    float* xp     = out;              // [32,256,256]
    float* adj_p  = out + 2097152;    // [32,256,256]
    float* s      = out + 4194304;    // [32,1024,256] fp32
    float* scal   = out + 12582912;
    float* node_x = out + 12582916;   // [32,1024,256] fp32

    char* w = (char*)d_ws;
    float* degsum     = (float*)w; w += 32768 * 4;   // now holds 1/max(deg,1) directly
    float* scores     = (float*)w; w += 8192 * 4;
    float* thresh     = (float*)w; w += 256 * 4;
    float* gatep      = (float*)w; w += 8192 * 4;
    float* ent_part   = (float*)w; w += 32768 * 4;
    float* asq_part   = (float*)w; w += 8192 * 4;
    float* psq_part   = (float*)w; w += 512 * 4;
    float* sdot_part  = (float*)w; w += 1024 * 4;
    float* trq_part   = (float*)w; w += 256 * 4;
    float* ssq_part   = (float*)w; w += 256 * 4;
    float* tr_part    = (float*)w; w += 256 * 4;
    unsigned short* WT   = (unsigned short*)w; w += 6LL * 65536 * 2;
    unsigned short* bufA = (unsigned short*)w; w += 33554432LL * 2;  // adj_bf
    unsigned short* bufB = (unsigned short*)w; w += 8388608LL * 2;   // x_bf -> {G_bf, PT_bf, M1}
    unsigned short* bufC = (unsigned short*)w; w += 8388608LL * 2;   // xT_bf -> sT_bf
    unsigned short* bufD = (unsigned short*)w; w += 8388608LL * 2;   // agg_bf -> nxT_bf
    unsigned short* bufE = (unsigned short*)w; w += 8388608LL * 2;   // h_bf -> aTs_bf
    unsigned short* bufF = (unsigned short*)w; w += 8388608LL * 2;   // aTsT_bf
    unsigned short* bufG = (unsigned short*)w; w += 8388608LL * 2;   // s_bf
    unsigned short* bufH = (unsigned short*)w; w += 2097152LL * 2;   // P_bf

    unsigned short* G_bf  = bufB;                        // [32,256,256] bf16 (after x_bf dead)
    unsigned short* PT_bf = bufB + 2097152;              // [32,256,256] bf16
    float*          M1    = (float*)(bufB + 4194304);    // [32,256,256] fp32

    hipMemsetAsync(scores, 0, 8192 * sizeof(float), stream);

    // 1) adj -> adj_bf + 1/deg + sum(adj^2) partials, streaming (no LDS tiles,
    //    no atomics): one wave per row, folds the old recip_kernel in.
    adjconv_kernel<<<8192, 256, 0, stream>>>(adj, bufA, degsum, asq_part);

    // 2) x -> x_bf + xT_bf
    convt_kernel<<<dim3(4, 16, 32), 256, 0, stream>>>(
        x, 262144LL, 256, bufB, 262144LL, bufC, 262144LL, 1024, nullptr, 0, nullptr);

    // 3) weights -> transposed bf16
    WPtrs wp;
    wp.in[0] = Wr_p; wp.in[1] = Wo_p; wp.in[2] = Wl_p;
    wp.in[3] = Wr_e; wp.in[4] = Wo_e; wp.in[5] = Wl_e;
    for (int i = 0; i < 6; ++i) wp.out[i] = WT + (long long)i * 65536;
    wconv_kernel<<<dim3(4, 4, 6), 256, 0, stream>>>(wp);

    GemmP g;
    // 4) agg = (adj @ x) * deg -> agg_bf (bufD)
    g = {};
    g.A1 = bufA; g.sA1 = 1048576; g.lda1 = 1024; g.K1 = 1024;
    g.B1 = bufC; g.sB1 = 262144; g.ldb1 = 1024;
    g.outH = bufD; g.sH = 262144; g.ldc = 256;
    g.rowscale = degsum; g.sRS = 1024;
    gemm_mfma<<<dim3(2, 8, 32), 256, 0, stream>>>(g);

    // 5) pool pre-norm: h = agg@Wr_p + x@Wo_p + br_p -> bufE; l2relu in place
    g = {};
    g.A1 = bufD; g.sA1 = 0; g.lda1 = 256; g.K1 = 256; g.B1 = WT + 0 * 65536; g.sB1 = 0; g.ldb1 = 256;
    g.A2 = bufB; g.sA2 = 0; g.lda2 = 256; g.K2 = 256; g.B2 = WT + 1 * 65536; g.sB2 = 0; g.ldb2 = 256;
    g.outH = bufE; g.sH = 0; g.ldc = 256; g.bias = br_p;
    gemm_mfma<<<dim3(2, 256, 1), 256, 0, stream>>>(g);
    l2relu_bf_kernel<<<32768, 256, 0, stream>>>(bufE);

    // 6) s_logits = h @ Wl_p + bl_p -> s (fp32)
    g = {};
    g.A1 = bufE; g.sA1 = 0; g.lda1 = 256; g.K1 = 256; g.B1 = WT + 2 * 65536; g.sB1 = 0; g.ldb1 = 256;
    g.outF = s; g.sF = 0; g.ldc = 256; g.bias = bl_p;
    gemm_mfma<<<dim3(2, 256, 1), 256, 0, stream>>>(g);

    // 7) embed branch (reuses bufE)
    g = {};
    g.A1 = bufD; g.sA1 = 0; g.lda1 = 256; g.K1 = 256; g.B1 = WT + 3 * 65536; g.sB1 = 0; g.ldb1 = 256;
    g.A2 = bufB; g.sA2 = 0; g.lda2 = 256; g.K2 = 256; g.B2 = WT + 4 * 65536; g.sB2 = 0; g.ldb2 = 256;
    g.outH = bufE; g.sH = 0; g.ldc = 256; g.bias = br_e;
    gemm_mfma<<<dim3(2, 256, 1), 256, 0, stream>>>(g);
    l2relu_bf_kernel<<<32768, 256, 0, stream>>>(bufE);
    g = {};
    g.A1 = bufE; g.sA1 = 0; g.lda1 = 256; g.K1 = 256; g.B1 = WT + 5 * 65536; g.sB1 = 0; g.ldb1 = 256;
    g.outF = node_x; g.sF = 0; g.ldc = 256; g.bias = bl_e;
    gemm_mfma<<<dim3(2, 256, 1), 256, 0, stream>>>(g);

    // 8) softmax, scores, topk, gate, apply+entropy (+s_bf in bufG)
    softmax_kernel<<<32768, 256, 0, stream>>>(s);
    scores_kernel<<<dim3(32, 32, 1), 256, 0, stream>>>(s, scores);
    topk_kernel<<<32, 256, 0, stream>>>(scores, thresh);
    gate_kernel<<<32, 256, 0, stream>>>(scores, thresh, gatep);
    gate_ent_kernel<<<32768, 256, 0, stream>>>(s, gatep, bufG, ent_part);

    // 9) transposes: s -> sT_bf (bufC), node_x -> nxT_bf (bufD)
    convt_kernel<<<dim3(4, 16, 32), 256, 0, stream>>>(
        s, 262144LL, 256, nullptr, 0, bufC, 262144LL, 1024, nullptr, 0, nullptr);
    convt_kernel<<<dim3(4, 16, 32), 256, 0, stream>>>(
        node_x, 262144LL, 256, nullptr, 0, bufD, 262144LL, 1024, nullptr, 0, nullptr);

    // 10) xp = sT · nxT^T (fp32 out)
    g = {};
    g.A1 = bufC; g.sA1 = 262144; g.lda1 = 1024; g.K1 = 1024;
    g.B1 = bufD; g.sB1 = 262144; g.ldb1 = 1024;
    g.outF = xp; g.sF = 65536; g.ldc = 256;
    gemm_mfma<<<dim3(2, 2, 32), 256, 0, stream>>>(g);

    // 11) aTs = adj · s -> bufE bf16 [1024,256]
    g = {};
    g.A1 = bufA; g.sA1 = 1048576; g.lda1 = 1024; g.K1 = 1024;
    g.B1 = bufC; g.sB1 = 262144; g.ldb1 = 1024;
    g.outH = bufE; g.sH = 262144; g.ldc = 256;
    gemm_mfma<<<dim3(2, 8, 32), 256, 0, stream>>>(g);

    // 12) aTs -> aTsT_bf (bufF, [256,1024])
    tbf16_kernel<<<dim3(4, 16, 32), 256, 0, stream>>>(
        bufE, 262144LL, 256, bufF, 262144LL, 1024);

    // 13) G = sT·sT^T -> G_bf + ssq/tr partials (clu & link terms)
    sts_clu_mfma<<<dim3(2, 2, 32), 256, 0, stream>>>(bufC, G_bf, ssq_part, tr_part);

    // 14) adj_p = sT · aTsT^T (fp32 out)  [= S^T (A S)]
    g = {};
    g.A1 = bufC; g.sA1 = 262144; g.lda1 = 1024; g.K1 = 1024;
    g.B1 = bufF; g.sB1 = 262144; g.ldb1 = 1024;
    g.outF = adj_p; g.sF = 65536; g.ldc = 256;
    gemm_mfma<<<dim3(2, 2, 32), 256, 0, stream>>>(g);

    // 15) adj_p -> P_bf (bufH) + PT_bf + ||P||^2 partials
    convt_kernel<<<dim3(4, 4, 32), 256, 0, stream>>>(
        adj_p, 65536LL, 256, bufH, 65536LL, PT_bf, 65536LL, 256, nullptr, 0, psq_part);

    // 16) sdot = <S, A·S> partials (link cross term)
    dot_bf_kernel<<<1024, 256, 0, stream>>>(bufG, bufE, sdot_part);

    // 17) M1 = G · P (fp32 out)
    g = {};
    g.A1 = G_bf; g.sA1 = 65536; g.lda1 = 256; g.K1 = 256;
    g.B1 = PT_bf; g.sB1 = 65536; g.ldb1 = 256;
    g.outF = M1; g.sF = 65536; g.ldc = 256;
    gemm_mfma<<<dim3(2, 2, 32), 256, 0, stream>>>(g);

    // 18) M2 = G · P^T with trace-dot vs M1: trq = sum M2_ij * M1_ji
    g = {};
    g.A1 = G_bf; g.sA1 = 65536; g.lda1 = 256; g.K1 = 256;
    g.B1 = bufH; g.sB1 = 65536; g.ldb1 = 256;
    g.ldc = 256;
    g.dotT = M1; g.sDot = 65536; g.dot_part = trq_part;
    gemm_mfma<<<dim3(2, 2, 32), 256, 0, stream>>>(g);

    // 19) finalize
    finalize_kernel<<<1, 256, 0, stream>>>(ent_part, asq_part, psq_part, sdot_part,
                                           trq_part, ssq_part, tr_part, scal);
}

// Round 2
// 665.696 us; speedup vs baseline: 1.1467x; 1.1170x over previous
//
#include <hip/hip_runtime.h>
#include <hip/hip_bf16.h>
#include <math.h>

// B=32, N=1024, D=H=E=C=256, K_top=128, TEMP=0.1, EPS=1e-15

typedef short bf16x8 __attribute__((ext_vector_type(8)));   // 8 bf16 raw bits (4 VGPRs)
typedef float f32x4 __attribute__((ext_vector_type(4)));

__device__ inline void gl_lds16(const void* g, void* l) {
    __builtin_amdgcn_global_load_lds(
        (const __attribute__((address_space(1))) void*)g,
        (__attribute__((address_space(3))) void*)l, 16, 0, 0);
}

__device__ inline unsigned short f2b(float f) {
    union { __hip_bfloat16 h; unsigned short u; } cv;
    cv.h = __float2bfloat16(f);
    return cv.u;
}
__device__ inline float b2f(unsigned short u) {
    union { unsigned short u; __hip_bfloat16 h; } cv;
    cv.u = u;
    return __bfloat162float(cv.h);
}

// ---------------------------------------------------------------------------
// Streaming adj pass: one wave per 1024-wide row. fp32 -> bf16 convert,
// per-row reciprocal degree (1/max(sum,1)) via wave shuffle reduce, and
// sum-of-squares partials (one per block). No LDS tiles, no atomics.
__global__ __launch_bounds__(256) void adjconv_kernel(
    const float* __restrict__ adj, unsigned short* __restrict__ adj_bf,
    float* __restrict__ deginv, float* __restrict__ asq_part) {
    __shared__ float sq_red[4];
    const int tid = threadIdx.x;
    const int wave = tid >> 6, lane = tid & 63;
    const long long row = (long long)blockIdx.x * 4 + wave;   // 0..32767
    const float* ip = adj + row * 1024;
    unsigned short* op = adj_bf + row * 1024;
    float sum = 0.f, sq = 0.f;
#pragma unroll
    for (int i = 0; i < 4; ++i) {
        const float4 v = *(const float4*)(ip + i * 256 + lane * 4);
        ushort4 h;
        h.x = f2b(v.x); h.y = f2b(v.y); h.z = f2b(v.z); h.w = f2b(v.w);
        *(ushort4*)(op + i * 256 + lane * 4) = h;
        sum += v.x + v.y + v.z + v.w;
        sq = fmaf(v.x, v.x, sq);
        sq = fmaf(v.y, v.y, sq);
        sq = fmaf(v.z, v.z, sq);
        sq = fmaf(v.w, v.w, sq);
    }
#pragma unroll
    for (int off = 32; off > 0; off >>= 1) {
        sum += __shfl_xor(sum, off);
        sq  += __shfl_xor(sq, off);
    }
    if (lane == 0) {
        deginv[row] = 1.0f / fmaxf(sum, 1.0f);
        sq_red[wave] = sq;
    }
    __syncthreads();
    if (tid == 0)
        asq_part[blockIdx.x] = sq_red[0] + sq_red[1] + sq_red[2] + sq_red[3];
}

// ---------------------------------------------------------------------------
// Tiled convert/transpose: fp32 [R,C] -> optional bf16 same layout (outN),
// optional bf16 transpose (outT), optional sum of squares per block (sqpart).
__global__ __launch_bounds__(256) void convt_kernel(
    const float* __restrict__ in, long long sIn, int ldin,
    unsigned short* __restrict__ outN, long long sN,
    unsigned short* __restrict__ outT, long long sT, int ldT,
    float* __restrict__ sqpart) {
    __shared__ float tile[64][65];
    __shared__ float sred[256];
    const int tid = threadIdx.x;
    const long long bz = blockIdx.z;
    const int rowBase = blockIdx.y * 64, colBase = blockIdx.x * 64;
    const float* ip = in + bz * sIn;
    float sq = 0.f;
#pragma unroll
    for (int i = 0; i < 4; ++i) {
        int r = (tid >> 4) * 4 + i;
        const float4 v = *(const float4*)(ip + (long long)(rowBase + r) * ldin + colBase + (tid & 15) * 4);
        tile[r][(tid & 15) * 4 + 0] = v.x;
        tile[r][(tid & 15) * 4 + 1] = v.y;
        tile[r][(tid & 15) * 4 + 2] = v.z;
        tile[r][(tid & 15) * 4 + 3] = v.w;
        if (outN) {
            ushort4 h;
            h.x = f2b(v.x); h.y = f2b(v.y); h.z = f2b(v.z); h.w = f2b(v.w);
            *(ushort4*)(outN + bz * sN + (long long)(rowBase + r) * ldin + colBase + (tid & 15) * 4) = h;
        }
        if (sqpart) sq += v.x * v.x + v.y * v.y + v.z * v.z + v.w * v.w;
    }
    __syncthreads();
    if (outT) {
#pragma unroll
        for (int i = 0; i < 4; ++i) {
            int oc = (tid >> 4) * 4 + i;
            ushort4 h;
            h.x = f2b(tile[(tid & 15) * 4 + 0][oc]);
            h.y = f2b(tile[(tid & 15) * 4 + 1][oc]);
            h.z = f2b(tile[(tid & 15) * 4 + 2][oc]);
            h.w = f2b(tile[(tid & 15) * 4 + 3][oc]);
            *(ushort4*)(outT + bz * sT + (long long)(colBase + oc) * ldT + rowBase + (tid & 15) * 4) = h;
        }
    }
    if (sqpart) {
        sred[tid] = sq;
        __syncthreads();
        for (int k = 128; k > 0; k >>= 1) {
            if (tid < k) sred[tid] += sred[tid + k];
            __syncthreads();
        }
        if (tid == 0)
            sqpart[((long long)bz * gridDim.y + blockIdx.y) * gridDim.x + blockIdx.x] = sred[0];
    }
}

// bf16 -> bf16 transpose, 64x64 tiles
__global__ __launch_bounds__(256) void tbf16_kernel(
    const unsigned short* __restrict__ in, long long sIn, int ldin,
    unsigned short* __restrict__ outT, long long sT, int ldT) {
    __shared__ unsigned short tile[64][68];
    const int tid = threadIdx.x;
    const long long bz = blockIdx.z;
    const int rowBase = blockIdx.y * 64, colBase = blockIdx.x * 64;
    const unsigned short* ip = in + bz * sIn;
#pragma unroll
    for (int i = 0; i < 4; ++i) {
        int r = (tid >> 4) * 4 + i, c4 = (tid & 15) * 4;
        ushort4 v = *(const ushort4*)(ip + (long long)(rowBase + r) * ldin + colBase + c4);
        tile[r][c4 + 0] = v.x; tile[r][c4 + 1] = v.y;
        tile[r][c4 + 2] = v.z; tile[r][c4 + 3] = v.w;
    }
    __syncthreads();
#pragma unroll
    for (int i = 0; i < 4; ++i) {
        int oc = (tid >> 4) * 4 + i;
        ushort4 h;
        h.x = tile[(tid & 15) * 4 + 0][oc];
        h.y = tile[(tid & 15) * 4 + 1][oc];
        h.z = tile[(tid & 15) * 4 + 2][oc];
        h.w = tile[(tid & 15) * 4 + 3][oc];
        *(ushort4*)(outT + bz * sT + (long long)(colBase + oc) * ldT + rowBase + (tid & 15) * 4) = h;
    }
}

// 6 weight matrices [256,256] -> transposed bf16
struct WPtrs { const float* in[6]; unsigned short* out[6]; };
__global__ __launch_bounds__(256) void wconv_kernel(WPtrs wp) {
    __shared__ float tile[64][65];
    const int tid = threadIdx.x;
    const float* in = wp.in[blockIdx.z];
    unsigned short* out = wp.out[blockIdx.z];
    const int rowBase = blockIdx.y * 64, colBase = blockIdx.x * 64;
#pragma unroll
    for (int i = 0; i < 4; ++i) {
        int r = (tid >> 4) * 4 + i;
        const float4 v = *(const float4*)(in + (long long)(rowBase + r) * 256 + colBase + (tid & 15) * 4);
        tile[r][(tid & 15) * 4 + 0] = v.x;
        tile[r][(tid & 15) * 4 + 1] = v.y;
        tile[r][(tid & 15) * 4 + 2] = v.z;
        tile[r][(tid & 15) * 4 + 3] = v.w;
    }
    __syncthreads();
#pragma unroll
    for (int i = 0; i < 4; ++i) {
        int oc = (tid >> 4) * 4 + i;
        ushort4 h;
        h.x = f2b(tile[(tid & 15) * 4 + 0][oc]);
        h.y = f2b(tile[(tid & 15) * 4 + 1][oc]);
        h.z = f2b(tile[(tid & 15) * 4 + 2][oc]);
        h.w = f2b(tile[(tid & 15) * 4 + 3][oc]);
        *(ushort4*)(out + (long long)(colBase + oc) * 256 + rowBase + (tid & 15) * 4) = h;
    }
}

// ---------------------------------------------------------------------------
// MFMA GEMM: C[M,N] = A1[M,K1]·B1t[N,K1]^T (+ A2·B2t^T) (+bias) (*rowscale)
// Double-buffered LDS (2-phase pipeline), XOR-swizzled staging (conflict-free
// ds_read_b128: slot ^= (row>>1)&3, applied on global src + ds_read addr).
// Optional trace-dot epilogue: dot_part[block] = sum(out ∘ dotT^T).
struct GemmP {
    const unsigned short* A1; long long sA1; int lda1; int K1;
    const unsigned short* B1; long long sB1; int ldb1;
    const unsigned short* A2; long long sA2; int lda2; int K2;
    const unsigned short* B2; long long sB2; int ldb2;
    float* outF; long long sF;
    unsigned short* outH; long long sH;
    int ldc;
    const float* bias;
    const float* rowscale; long long sRS;
    const float* dotT; long long sDot;
    float* dot_part;
};

__global__ __launch_bounds__(256) void gemm_mfma(GemmP p) {
    __shared__ short As[2][128 * 32];
    __shared__ short Bs[2][128 * 32];
    __shared__ float dred[256];
    const int tid = threadIdx.x;
    const int wave = tid >> 6, lane = tid & 63;
    const int quad = lane >> 4, l15 = lane & 15;
    const int wm = (wave & 1) * 64, wn = (wave >> 1) * 64;
    const long long bz = blockIdx.z;
    const int rowBase = blockIdx.y * 128, colBase = blockIdx.x * 128;
    const int srow = tid >> 2;
    const int skg = (((tid & 3) ^ ((srow >> 1) & 3)) * 8);  // swizzled source k-offset
    const int rsw = (l15 >> 1) & 3;                          // read-side swizzle

    const int n1 = p.K1 >> 5;
    const int n2 = p.A2 ? (p.K2 >> 5) : 0;
    const int nTot = n1 + n2;

    const unsigned short* A1p = p.A1 + bz * p.sA1;
    const unsigned short* B1p = p.B1 + bz * p.sB1;
    const unsigned short* A2p = p.A2 ? p.A2 + bz * p.sA2 : nullptr;
    const unsigned short* B2p = p.B2 ? p.B2 + bz * p.sB2 : nullptr;

    auto stage = [&](int t, int buf) {
        const unsigned short *Ao, *Bo; int lda, ldb, ko;
        if (t < n1) { Ao = A1p; Bo = B1p; lda = p.lda1; ldb = p.ldb1; ko = t * 32; }
        else        { Ao = A2p; Bo = B2p; lda = p.lda2; ldb = p.ldb2; ko = (t - n1) * 32; }
        char* la = (char*)As + buf * 8192 + wave * 1024;
        char* lb = (char*)Bs + buf * 8192 + wave * 1024;
        gl_lds16(Ao + (long long)(rowBase + srow) * lda + ko + skg, la);
        gl_lds16(Ao + (long long)(rowBase + 64 + srow) * lda + ko + skg, la + 4096);
        gl_lds16(Bo + (long long)(colBase + srow) * ldb + ko + skg, lb);
        gl_lds16(Bo + (long long)(colBase + 64 + srow) * ldb + ko + skg, lb + 4096);
    };

    f32x4 acc[4][4] = {{{0.f}}};
    stage(0, 0);
    __syncthreads();
    int cur = 0;
    for (int t = 0; t < nTot; ++t) {
        if (t + 1 < nTot) stage(t + 1, cur ^ 1);
        const short* Ab = As[cur];
        const short* Bb = Bs[cur];
        bf16x8 af[4], bf[4];
#pragma unroll
        for (int i = 0; i < 4; ++i)
            af[i] = *(const bf16x8*)(Ab + (wm + i * 16 + l15) * 32 + (quad ^ rsw) * 8);
#pragma unroll
        for (int j = 0; j < 4; ++j)
            bf[j] = *(const bf16x8*)(Bb + (wn + j * 16 + l15) * 32 + (quad ^ rsw) * 8);
#pragma unroll
        for (int i = 0; i < 4; ++i)
#pragma unroll
            for (int j = 0; j < 4; ++j)
                acc[i][j] = __builtin_amdgcn_mfma_f32_16x16x32_bf16(af[i], bf[j], acc[i][j], 0, 0, 0);
        __syncthreads();
        cur ^= 1;
    }

    float* oF = p.outF ? p.outF + bz * p.sF : nullptr;
    unsigned short* oH = p.outH ? p.outH + bz * p.sH : nullptr;
    const float* dT = p.dotT ? p.dotT + bz * p.sDot : nullptr;
    float bcol[4];
#pragma unroll
    for (int j = 0; j < 4; ++j)
        bcol[j] = p.bias ? p.bias[colBase + wn + j * 16 + l15] : 0.0f;
    const float* rs = p.rowscale ? p.rowscale + bz * p.sRS : nullptr;
    float dacc = 0.f;
#pragma unroll
    for (int i = 0; i < 4; ++i) {
#pragma unroll
        for (int r = 0; r < 4; ++r) {
            int row = rowBase + wm + i * 16 + quad * 4 + r;
            float sc = rs ? rs[row] : 1.0f;
            long long ro = (long long)row * p.ldc;
#pragma unroll
            for (int j = 0; j < 4; ++j) {
                int col = colBase + wn + j * 16 + l15;
                float v = (acc[i][j][r] + bcol[j]) * sc;
                if (oF) oF[ro + col] = v;
                if (oH) oH[ro + col] = f2b(v);
                if (dT) dacc = fmaf(v, dT[(long long)col * p.ldc + row], dacc);
            }
        }
    }
    if (p.dot_part) {
        dred[tid] = dacc;
        __syncthreads();
        for (int k = 128; k > 0; k >>= 1) {
            if (tid < k) dred[tid] += dred[tid + k];
            __syncthreads();
        }
        if (tid == 0)
            p.dot_part[((long long)bz * gridDim.y + blockIdx.y) * gridDim.x + blockIdx.x] = dred[0];
    }
}

// ---------------------------------------------------------------------------
// G = sT · sT^T via MFMA (dbuf + swizzle); writes G bf16 and reduces
// ssq = sum(G^2), tr = trace partials per block.
__global__ __launch_bounds__(256) void sts_clu_mfma(
    const unsigned short* __restrict__ sT, unsigned short* __restrict__ gout,
    float* __restrict__ ssq_part, float* __restrict__ tr_part) {
    __shared__ short As[2][128 * 32];
    __shared__ short Bs[2][128 * 32];
    __shared__ float red[2][256];
    const int tid = threadIdx.x;
    const int wave = tid >> 6, lane = tid & 63;
    const int quad = lane >> 4, l15 = lane & 15;
    const int wm = (wave & 1) * 64, wn = (wave >> 1) * 64;
    const long long bz = blockIdx.z;
    const unsigned short* S = sT + bz * 262144;
    const int rowBase = blockIdx.y * 128, colBase = blockIdx.x * 128;
    const int srow = tid >> 2;
    const int skg = (((tid & 3) ^ ((srow >> 1) & 3)) * 8);
    const int rsw = (l15 >> 1) & 3;

    auto stage = [&](int t, int buf) {
        int ko = t * 32;
        char* la = (char*)As + buf * 8192 + wave * 1024;
        char* lb = (char*)Bs + buf * 8192 + wave * 1024;
        gl_lds16(S + (long long)(rowBase + srow) * 1024 + ko + skg, la);
        gl_lds16(S + (long long)(rowBase + 64 + srow) * 1024 + ko + skg, la + 4096);
        gl_lds16(S + (long long)(colBase + srow) * 1024 + ko + skg, lb);
        gl_lds16(S + (long long)(colBase + 64 + srow) * 1024 + ko + skg, lb + 4096);
    };

    f32x4 acc[4][4] = {{{0.f}}};
    stage(0, 0);
    __syncthreads();
    int cur = 0;
    for (int t = 0; t < 32; ++t) {
        if (t + 1 < 32) stage(t + 1, cur ^ 1);
        const short* Ab = As[cur];
        const short* Bb = Bs[cur];
        bf16x8 af[4], bf[4];
#pragma unroll
        for (int i = 0; i < 4; ++i)
            af[i] = *(const bf16x8*)(Ab + (wm + i * 16 + l15) * 32 + (quad ^ rsw) * 8);
#pragma unroll
        for (int j = 0; j < 4; ++j)
            bf[j] = *(const bf16x8*)(Bb + (wn + j * 16 + l15) * 32 + (quad ^ rsw) * 8);
#pragma unroll
        for (int i = 0; i < 4; ++i)
#pragma unroll
            for (int j = 0; j < 4; ++j)
                acc[i][j] = __builtin_amdgcn_mfma_f32_16x16x32_bf16(af[i], bf[j], acc[i][j], 0, 0, 0);
        __syncthreads();
        cur ^= 1;
    }
    unsigned short* go = gout + bz * 65536;
    float ssq = 0.f, tr = 0.f;
#pragma unroll
    for (int i = 0; i < 4; ++i)
#pragma unroll
        for (int r = 0; r < 4; ++r) {
            int row = rowBase + wm + i * 16 + quad * 4 + r;
#pragma unroll
            for (int j = 0; j < 4; ++j) {
                int col = colBase + wn + j * 16 + l15;
                float v = acc[i][j][r];
                go[(long long)row * 256 + col] = f2b(v);
                ssq = fmaf(v, v, ssq);
                if (row == col) tr += v;
            }
        }
    red[0][tid] = ssq;
    red[1][tid] = tr;
    __syncthreads();
    for (int k = 128; k > 0; k >>= 1) {
        if (tid < k) {
            red[0][tid] += red[0][tid + k];
            red[1][tid] += red[1][tid + k];
        }
        __syncthreads();
    }
    if (tid == 0) {
        int bid = (int)(blockIdx.z * 4 + blockIdx.y * 2 + blockIdx.x);
        ssq_part[bid] = red[0][0];
        tr_part[bid] = red[1][0];
    }
}

// ---------------------------------------------------------------------------
// bf16 elementwise dot over 8,388,608 elems -> per-block partials [1024]
__global__ __launch_bounds__(256) void dot_bf_kernel(const unsigned short* __restrict__ a,
                                                     const unsigned short* __restrict__ b,
                                                     float* __restrict__ part) {
    __shared__ float red[256];
    int tid = threadIdx.x;
    long long base = (long long)blockIdx.x * 8192;
    float acc = 0.f;
#pragma unroll
    for (int i = 0; i < 8; ++i) {
        long long off = base + i * 1024 + tid * 4;
        ushort4 va = *(const ushort4*)(a + off);
        ushort4 vb = *(const ushort4*)(b + off);
        acc = fmaf(b2f(va.x), b2f(vb.x), acc);
        acc = fmaf(b2f(va.y), b2f(vb.y), acc);
        acc = fmaf(b2f(va.z), b2f(vb.z), acc);
        acc = fmaf(b2f(va.w), b2f(vb.w), acc);
    }
    red[tid] = acc;
    __syncthreads();
    for (int k = 128; k > 0; k >>= 1) {
        if (tid < k) red[tid] += red[tid + k];
        __syncthreads();
    }
    if (tid == 0) part[blockIdx.x] = red[0];
}

// ---------------------------------------------------------------------------
// l2-normalize each 256-wide row then relu; bf16, in-place.
__global__ __launch_bounds__(256) void l2relu_bf_kernel(unsigned short* __restrict__ buf) {
    __shared__ float red[256];
    long long row = blockIdx.x;
    int tid = threadIdx.x;
    float v = b2f(buf[row * 256 + tid]);
    red[tid] = v * v;
    __syncthreads();
    for (int k = 128; k > 0; k >>= 1) {
        if (tid < k) red[tid] += red[tid + k];
        __syncthreads();
    }
    float rn = 1.0f / fmaxf(sqrtf(red[0]), 1e-12f);
    buf[row * 256 + tid] = f2b(fmaxf(v * rn, 0.0f));
}

// ---------------------------------------------------------------------------
// Pass 1 over logits: per-row softmax stats (max, 1/den) + column scores
// (sum over rows of normalized softmax). One wave per row; 32 rows/block.
__global__ __launch_bounds__(256) void smstat_kernel(
    const float* __restrict__ s, float* __restrict__ rowmax,
    float* __restrict__ rowrden, float* __restrict__ scores) {
    __shared__ float sacc[4][256];
    const int tid = threadIdx.x;
    const int wave = tid >> 6, lane = tid & 63;
    const int b = blockIdx.x >> 5;
    const long long row0 = (long long)blockIdx.x * 32;
    float c0 = 0.f, c1 = 0.f, c2 = 0.f, c3 = 0.f;
#pragma unroll
    for (int q = 0; q < 8; ++q) {
        long long row = row0 + wave * 8 + q;
        const float4 v = *(const float4*)(s + row * 256 + lane * 4);
        float m = fmaxf(fmaxf(v.x, v.y), fmaxf(v.z, v.w));
#pragma unroll
        for (int off = 32; off > 0; off >>= 1) m = fmaxf(m, __shfl_xor(m, off));
        float e0 = expf(v.x - m), e1 = expf(v.y - m);
        float e2 = expf(v.z - m), e3 = expf(v.w - m);
        float den = e0 + e1 + e2 + e3;
#pragma unroll
        for (int off = 32; off > 0; off >>= 1) den += __shfl_xor(den, off);
        float rd = 1.0f / den;
        if (lane == 0) { rowmax[row] = m; rowrden[row] = rd; }
        c0 = fmaf(e0, rd, c0); c1 = fmaf(e1, rd, c1);
        c2 = fmaf(e2, rd, c2); c3 = fmaf(e3, rd, c3);
    }
    sacc[wave][lane * 4 + 0] = c0;
    sacc[wave][lane * 4 + 1] = c1;
    sacc[wave][lane * 4 + 2] = c2;
    sacc[wave][lane * 4 + 3] = c3;
    __syncthreads();
    float t0 = sacc[0][tid] + sacc[1][tid] + sacc[2][tid] + sacc[3][tid];
    atomicAdd(&scores[b * 256 + tid], t0);
}

__global__ __launch_bounds__(256) void topk_kernel(const float* __restrict__ scores,
                                                   float* __restrict__ thresh) {
    __shared__ float vals[256];
    int b = blockIdx.x, tid = threadIdx.x;
    float v = scores[b * 256 + tid];
    vals[tid] = v;
    __syncthreads();
    int rank = 0;
    for (int j = 0; j < 256; ++j) {
        float u = vals[j];
        rank += (u > v) || (u == v && j < tid);
    }
    if (rank == 127) thresh[b] = v;
}

__global__ __launch_bounds__(256) void gate_kernel(const float* __restrict__ scores,
                                                   const float* __restrict__ thresh,
                                                   float* __restrict__ gate) {
    int b = blockIdx.x, c = threadIdx.x;
    float z = (scores[b * 256 + c] - thresh[b]) * 10.0f;  // 1/TEMP
    gate[b * 256 + c] = 1.0f / (1.0f + expf(-z));
}

// ---------------------------------------------------------------------------
// Pass 2: gated softmax from logits + stats. Writes s fp32 (final output),
// s_bf row-major, sT bf16 transposed (64x64 tiles), entropy partials.
__global__ __launch_bounds__(256) void gatefin_kernel(
    float* __restrict__ s, const float* __restrict__ rowmax,
    const float* __restrict__ rowrden, const float* __restrict__ gate,
    unsigned short* __restrict__ sbf, unsigned short* __restrict__ sT,
    float* __restrict__ ent_part) {
    __shared__ float tile[64][65];
    __shared__ float red[256];
    const int tid = threadIdx.x;
    const long long bz = blockIdx.z;
    const int rowBase = blockIdx.y * 64, colBase = blockIdx.x * 64;
    const int c4 = (tid & 15) * 4;
    const float g0 = gate[bz * 256 + colBase + c4 + 0];
    const float g1 = gate[bz * 256 + colBase + c4 + 1];
    const float g2 = gate[bz * 256 + colBase + c4 + 2];
    const float g3 = gate[bz * 256 + colBase + c4 + 3];
    float ent = 0.f;
#pragma unroll
    for (int i = 0; i < 4; ++i) {
        int r = (tid >> 4) * 4 + i;
        long long grow = bz * 1024 + rowBase + r;
        float4 v = *(const float4*)(s + grow * 256 + colBase + c4);
        float m = rowmax[grow], rd = rowrden[grow];
        float p0 = expf(v.x - m) * rd * g0;
        float p1 = expf(v.y - m) * rd * g1;
        float p2 = expf(v.z - m) * rd * g2;
        float p3 = expf(v.w - m) * rd * g3;
        float4 pv; pv.x = p0; pv.y = p1; pv.z = p2; pv.w = p3;
        *(float4*)(s + grow * 256 + colBase + c4) = pv;
        ushort4 h;
        h.x = f2b(p0); h.y = f2b(p1); h.z = f2b(p2); h.w = f2b(p3);
        *(ushort4*)(sbf + grow * 256 + colBase + c4) = h;
        tile[r][c4 + 0] = p0; tile[r][c4 + 1] = p1;
        tile[r][c4 + 2] = p2; tile[r][c4 + 3] = p3;
        ent -= p0 * logf(p0 + 1e-15f) + p1 * logf(p1 + 1e-15f) +
               p2 * logf(p2 + 1e-15f) + p3 * logf(p3 + 1e-15f);
    }
    __syncthreads();
#pragma unroll
    for (int i = 0; i < 4; ++i) {
        int oc = (tid >> 4) * 4 + i;
        ushort4 h;
        h.x = f2b(tile[c4 + 0][oc]);
        h.y = f2b(tile[c4 + 1][oc]);
        h.z = f2b(tile[c4 + 2][oc]);
        h.w = f2b(tile[c4 + 3][oc]);
        *(ushort4*)(sT + bz * 262144 + (long long)(colBase + oc) * 1024 + rowBase + c4) = h;
    }
    red[tid] = ent;
    __syncthreads();
    for (int k = 128; k > 0; k >>= 1) {
        if (tid < k) red[tid] += red[tid + k];
        __syncthreads();
    }
    if (tid == 0)
        ent_part[((long long)bz * gridDim.y + blockIdx.y) * gridDim.x + blockIdx.x] = red[0];
}

// ---------------------------------------------------------------------------
__global__ __launch_bounds__(256) void finalize_kernel(const float* __restrict__ ent_part,
                                                       const float* __restrict__ asq_part,
                                                       const float* __restrict__ psq_part,
                                                       const float* __restrict__ sdot_part,
                                                       const float* __restrict__ trq_part,
                                                       const float* __restrict__ ssq_part,
                                                       const float* __restrict__ tr_part,
                                                       float* __restrict__ scal) {
    __shared__ float red[7][256];
    int tid = threadIdx.x;
    float e = 0.f, asq = 0.f, psq = 0.f, sd = 0.f, tq = 0.f, clu = 0.f, ssqa = 0.f;
    for (int i = tid; i < 2048; i += 256) e += ent_part[i];
    for (int i = tid; i < 8192; i += 256) asq += asq_part[i];
    for (int i = tid; i < 512; i += 256) psq += psq_part[i];
    for (int i = tid; i < 1024; i += 256) sd += sdot_part[i];
    if (tid < 128) tq = trq_part[tid];
    if (tid < 32) {
        float ssq = 0.f, tr = 0.f;
#pragma unroll
        for (int i = 0; i < 4; ++i) {
            ssq += ssq_part[tid * 4 + i];
            tr  += tr_part[tid * 4 + i];
        }
        ssqa = ssq;
        float fro = fmaxf(sqrtf(ssq), 1e-12f);
        float val = ssq / (fro * fro) - tr / (8.0f * fro) + 1.0f;  // ||G/fro - I/16||_F^2
        clu = sqrtf(fmaxf(val, 0.0f));
    }
    red[0][tid] = e; red[1][tid] = asq; red[2][tid] = psq; red[3][tid] = sd;
    red[4][tid] = tq; red[5][tid] = clu; red[6][tid] = ssqa;
    __syncthreads();
    for (int k = 128; k > 0; k >>= 1) {
        if (tid < k) {
#pragma unroll
            for (int q = 0; q < 7; ++q) red[q][tid] += red[q][tid + k];
        }
        __syncthreads();
    }
    if (tid == 0) {
        const float numel = 33554432.0f;  // B*N*N
        float linksq  = red[1][0] - 2.0f * red[3][0] + red[6][0];   // asq - 2<S,AS> + ||G||^2
        float reconsq = red[1][0] - 2.0f * red[2][0] + red[4][0];   // asq - 2||P||^2 + tr(GP'GP)
        scal[0] = sqrtf(fmaxf(linksq, 0.0f)) / numel;   // link
        scal[1] = red[0][0] / 32768.0f;                 // ent
        scal[2] = red[5][0] / 32.0f;                    // clu
        scal[3] = sqrtf(fmaxf(reconsq, 0.0f)) / numel;  // recon
    }
}

// ---------------------------------------------------------------------------
extern "C" void kernel_launch(void* const* d_in, const int* in_sizes, int n_in,
                              void* d_out, int out_size, void* d_ws, size_t ws_size,
                              hipStream_t stream) {
    const float* x    = (const float*)d_in[0];
    const float* adj  = (const float*)d_in[1];
    const float* Wr_p = (const float*)d_in[2];
    const float* br_p = (const float*)d_in[3];
    const float* Wo_p = (const float*)d_in[4];
    const float* Wl_p = (const float*)d_in[5];
    const float* bl_p = (const float*)d_in[6];
    const float* Wr_e = (const float*)d_in[7];
    const float* br_e = (const float*)d_in[8];
    const float* Wo_e = (const float*)d_in[9];
    const float* Wl_e = (const float*)d_in[10];
    const float* bl_e = (const float*)d_in[11];

    float* out    = (float*)d_out;
    float* xp     = out;              // [32,256,256]
    float* adj_p  = out + 2097152;    // [32,256,256]
    float* s      = out + 4194304;    // [32,1024,256] fp32
    float* scal   = out + 12582912;
    float* node_x = out + 12582916;   // [32,1024,256] fp32

    char* w = (char*)d_ws;
    float* degsum     = (float*)w; w += 32768 * 4;   // deginv; reused as rowmax after gemm4
    float* scores     = (float*)w; w += 8192 * 4;
    float* thresh     = (float*)w; w += 256 * 4;
    float* gatep      = (float*)w; w += 8192 * 4;
    float* ent_part   = (float*)w; w += 32768 * 4;   // only 2048 used now
    float* asq_part   = (float*)w; w += 8192 * 4;
    float* psq_part   = (float*)w; w += 512 * 4;
    float* sdot_part  = (float*)w; w += 1024 * 4;
    float* trq_part   = (float*)w; w += 256 * 4;
    float* ssq_part   = (float*)w; w += 256 * 4;
    float* tr_part    = (float*)w; w += 256 * 4;
    unsigned short* WT   = (unsigned short*)w; w += 6LL * 65536 * 2;
    unsigned short* bufA = (unsigned short*)w; w += 33554432LL * 2;  // adj_bf
    unsigned short* bufB = (unsigned short*)w; w += 8388608LL * 2;   // x_bf -> {G_bf, PT_bf, M1}
    unsigned short* bufC = (unsigned short*)w; w += 8388608LL * 2;   // xT_bf -> sT_bf
    unsigned short* bufD = (unsigned short*)w; w += 8388608LL * 2;   // agg_bf -> nxT_bf
    unsigned short* bufE = (unsigned short*)w; w += 8388608LL * 2;   // h_bf -> aTs_bf
    unsigned short* bufF = (unsigned short*)w; w += 8388608LL * 2;   // nx_bf -> aTsT_bf
    unsigned short* bufG = (unsigned short*)w; w += 8388608LL * 2;   // s_bf
    unsigned short* bufH = (unsigned short*)w; w += 2097152LL * 2;   // rowrden, then P_bf

    unsigned short* G_bf  = bufB;                        // [32,256,256] bf16 (after x_bf dead)
    unsigned short* PT_bf = bufB + 2097152;              // [32,256,256] bf16
    float*          M1    = (float*)(bufB + 4194304);    // [32,256,256] fp32
    float* rowmax  = degsum;         // dead after gemm4
    float* rowrden = (float*)bufH;   // bufH not P_bf until step 15

    hipMemsetAsync(scores, 0, 8192 * sizeof(float), stream);

    // 1) adj -> adj_bf + 1/deg + sum(adj^2) partials (streaming, waves own rows)
    adjconv_kernel<<<8192, 256, 0, stream>>>(adj, bufA, degsum, asq_part);

    // 2) x -> x_bf + xT_bf
    convt_kernel<<<dim3(4, 16, 32), 256, 0, stream>>>(
        x, 262144LL, 256, bufB, 262144LL, bufC, 262144LL, 1024, nullptr);

    // 3) weights -> transposed bf16
    WPtrs wp;
    wp.in[0] = Wr_p; wp.in[1] = Wo_p; wp.in[2] = Wl_p;
    wp.in[3] = Wr_e; wp.in[4] = Wo_e; wp.in[5] = Wl_e;
    for (int i = 0; i < 6; ++i) wp.out[i] = WT + (long long)i * 65536;
    wconv_kernel<<<dim3(4, 4, 6), 256, 0, stream>>>(wp);

    GemmP g;
    // 4) agg = (adj @ x) * deg -> agg_bf (bufD)
    g = {};
    g.A1 = bufA; g.sA1 = 1048576; g.lda1 = 1024; g.K1 = 1024;
    g.B1 = bufC; g.sB1 = 262144; g.ldb1 = 1024;
    g.outH = bufD; g.sH = 262144; g.ldc = 256;
    g.rowscale = degsum; g.sRS = 1024;
    gemm_mfma<<<dim3(2, 8, 32), 256, 0, stream>>>(g);

    // 5) pool pre-norm: h = agg@Wr_p + x@Wo_p + br_p -> bufE; l2relu in place
    g = {};
    g.A1 = bufD; g.sA1 = 0; g.lda1 = 256; g.K1 = 256; g.B1 = WT + 0 * 65536; g.sB1 = 0; g.ldb1 = 256;
    g.A2 = bufB; g.sA2 = 0; g.lda2 = 256; g.K2 = 256; g.B2 = WT + 1 * 65536; g.sB2 = 0; g.ldb2 = 256;
    g.outH = bufE; g.sH = 0; g.ldc = 256; g.bias = br_p;
    gemm_mfma<<<dim3(2, 256, 1), 256, 0, stream>>>(g);
    l2relu_bf_kernel<<<32768, 256, 0, stream>>>(bufE);

    // 6) s_logits = h @ Wl_p + bl_p -> s (fp32)
    g = {};
    g.A1 = bufE; g.sA1 = 0; g.lda1 = 256; g.K1 = 256; g.B1 = WT + 2 * 65536; g.sB1 = 0; g.ldb1 = 256;
    g.outF = s; g.sF = 0; g.ldc = 256; g.bias = bl_p;
    gemm_mfma<<<dim3(2, 256, 1), 256, 0, stream>>>(g);

    // 7) embed branch (reuses bufE); final gemm also emits bf16 copy -> bufF
    g = {};
    g.A1 = bufD; g.sA1 = 0; g.lda1 = 256; g.K1 = 256; g.B1 = WT + 3 * 65536; g.sB1 = 0; g.ldb1 = 256;
    g.A2 = bufB; g.sA2 = 0; g.lda2 = 256; g.K2 = 256; g.B2 = WT + 4 * 65536; g.sB2 = 0; g.ldb2 = 256;
    g.outH = bufE; g.sH = 0; g.ldc = 256; g.bias = br_e;
    gemm_mfma<<<dim3(2, 256, 1), 256, 0, stream>>>(g);
    l2relu_bf_kernel<<<32768, 256, 0, stream>>>(bufE);
    g = {};
    g.A1 = bufE; g.sA1 = 0; g.lda1 = 256; g.K1 = 256; g.B1 = WT + 5 * 65536; g.sB1 = 0; g.ldb1 = 256;
    g.outF = node_x; g.sF = 0; g.outH = bufF; g.sH = 0; g.ldc = 256; g.bias = bl_e;
    gemm_mfma<<<dim3(2, 256, 1), 256, 0, stream>>>(g);

    // 8) softmax stats + scores; topk; gate; gated finalize (s, s_bf, sT, ent)
    smstat_kernel<<<1024, 256, 0, stream>>>(s, rowmax, rowrden, scores);
    topk_kernel<<<32, 256, 0, stream>>>(scores, thresh);
    gate_kernel<<<32, 256, 0, stream>>>(scores, thresh, gatep);
    gatefin_kernel<<<dim3(4, 16, 32), 256, 0, stream>>>(
        s, rowmax, rowrden, gatep, bufG, bufC, ent_part);

    // 9) node_x bf16 -> nxT_bf (bufD), from the gemm's bf16 copy
    tbf16_kernel<<<dim3(4, 16, 32), 256, 0, stream>>>(
        bufF, 262144LL, 256, bufD, 262144LL, 1024);

    // 10) xp = sT · nxT^T (fp32 out)
    g = {};
    g.A1 = bufC; g.sA1 = 262144; g.lda1 = 1024; g.K1 = 1024;
    g.B1 = bufD; g.sB1 = 262144; g.ldb1 = 1024;
    g.outF = xp; g.sF = 65536; g.ldc = 256;
    gemm_mfma<<<dim3(2, 2, 32), 256, 0, stream>>>(g);

    // 11) aTs = adj · s -> bufE bf16 [1024,256]
    g = {};
    g.A1 = bufA; g.sA1 = 1048576; g.lda1 = 1024; g.K1 = 1024;
    g.B1 = bufC; g.sB1 = 262144; g.ldb1 = 1024;
    g.outH = bufE; g.sH = 262144; g.ldc = 256;
    gemm_mfma<<<dim3(2, 8, 32), 256, 0, stream>>>(g);

    // 12) aTs -> aTsT_bf (bufF, [256,1024])
    tbf16_kernel<<<dim3(4, 16, 32), 256, 0, stream>>>(
        bufE, 262144LL, 256, bufF, 262144LL, 1024);

    // 13) G = sT·sT^T -> G_bf + ssq/tr partials (clu & link terms)
    sts_clu_mfma<<<dim3(2, 2, 32), 256, 0, stream>>>(bufC, G_bf, ssq_part, tr_part);

    // 14) adj_p = sT · aTsT^T (fp32 out)  [= S^T (A S)]
    g = {};
    g.A1 = bufC; g.sA1 = 262144; g.lda1 = 1024; g.K1 = 1024;
    g.B1 = bufF; g.sB1 = 262144; g.ldb1 = 1024;
    g.outF = adj_p; g.sF = 65536; g.ldc = 256;
    gemm_mfma<<<dim3(2, 2, 32), 256, 0, stream>>>(g);

    // 15) adj_p -> P_bf (bufH) + PT_bf + ||P||^2 partials
    convt_kernel<<<dim3(4, 4, 32), 256, 0, stream>>>(
        adj_p, 65536LL, 256, bufH, 65536LL, PT_bf, 65536LL, 256, psq_part);

    // 16) sdot = <S, A·S> partials (link cross term)
    dot_bf_kernel<<<1024, 256, 0, stream>>>(bufG, bufE, sdot_part);

    // 17) M1 = G · P (fp32 out)
    g = {};
    g.A1 = G_bf; g.sA1 = 65536; g.lda1 = 256; g.K1 = 256;
    g.B1 = PT_bf; g.sB1 = 65536; g.ldb1 = 256;
    g.outF = M1; g.sF = 65536; g.ldc = 256;
    gemm_mfma<<<dim3(2, 2, 32), 256, 0, stream>>>(g);

    // 18) M2 = G · P^T with trace-dot vs M1: trq = sum M2_ij * M1_ji
    g = {};
    g.A1 = G_bf; g.sA1 = 65536; g.lda1 = 256; g.K1 = 256;
    g.B1 = bufH; g.sB1 = 65536; g.ldb1 = 256;
    g.ldc = 256;
    g.dotT = M1; g.sDot = 65536; g.dot_part = trq_part;
    gemm_mfma<<<dim3(2, 2, 32), 256, 0, stream>>>(g);

    // 19) finalize
    finalize_kernel<<<1, 256, 0, stream>>>(ent_part, asq_part, psq_part, sdot_part,
                                           trq_part, ssq_part, tr_part, scal);
}

// Round 3
// 580.041 us; speedup vs baseline: 1.3160x; 1.1477x over previous
//
#include <hip/hip_runtime.h>
#include <hip/hip_bf16.h>
#include <math.h>

// B=32, N=1024, D=H=E=C=256, K_top=128, TEMP=0.1, EPS=1e-15

typedef short bf16x8 __attribute__((ext_vector_type(8)));   // 8 bf16 raw bits (4 VGPRs)
typedef float f32x4 __attribute__((ext_vector_type(4)));
typedef unsigned short u16x8 __attribute__((ext_vector_type(8)));

__device__ inline void gl_lds16(const void* g, void* l) {
    __builtin_amdgcn_global_load_lds(
        (const __attribute__((address_space(1))) void*)g,
        (__attribute__((address_space(3))) void*)l, 16, 0, 0);
}

__device__ inline unsigned short f2b(float f) {
    union { __hip_bfloat16 h; unsigned short u; } cv;
    cv.h = __float2bfloat16(f);
    return cv.u;
}
__device__ inline float b2f(unsigned short u) {
    union { unsigned short u; __hip_bfloat16 h; } cv;
    cv.u = u;
    return __bfloat162float(cv.h);
}

// ---------------------------------------------------------------------------
// Streaming adj pass: one wave per 1024-wide row. fp32 -> bf16 convert (16B
// stores), per-row 1/max(deg,1) via wave shuffle reduce, sum-sq partials.
__global__ __launch_bounds__(256) void adjconv_kernel(
    const float* __restrict__ adj, unsigned short* __restrict__ adj_bf,
    float* __restrict__ deginv, float* __restrict__ asq_part) {
    __shared__ float sq_red[4];
    const int tid = threadIdx.x;
    const int wave = tid >> 6, lane = tid & 63;
    const long long row = (long long)blockIdx.x * 4 + wave;   // 0..32767
    const float* ip = adj + row * 1024;
    unsigned short* op = adj_bf + row * 1024;
    float sum = 0.f, sq = 0.f;
#pragma unroll
    for (int i = 0; i < 2; ++i) {
        const float4 v0 = *(const float4*)(ip + i * 512 + lane * 8);
        const float4 v1 = *(const float4*)(ip + i * 512 + lane * 8 + 4);
        u16x8 h;
        h[0] = f2b(v0.x); h[1] = f2b(v0.y); h[2] = f2b(v0.z); h[3] = f2b(v0.w);
        h[4] = f2b(v1.x); h[5] = f2b(v1.y); h[6] = f2b(v1.z); h[7] = f2b(v1.w);
        *(u16x8*)(op + i * 512 + lane * 8) = h;
        sum += (v0.x + v0.y + v0.z + v0.w) + (v1.x + v1.y + v1.z + v1.w);
        sq = fmaf(v0.x, v0.x, sq); sq = fmaf(v0.y, v0.y, sq);
        sq = fmaf(v0.z, v0.z, sq); sq = fmaf(v0.w, v0.w, sq);
        sq = fmaf(v1.x, v1.x, sq); sq = fmaf(v1.y, v1.y, sq);
        sq = fmaf(v1.z, v1.z, sq); sq = fmaf(v1.w, v1.w, sq);
    }
#pragma unroll
    for (int off = 32; off > 0; off >>= 1) {
        sum += __shfl_xor(sum, off);
        sq  += __shfl_xor(sq, off);
    }
    if (lane == 0) {
        deginv[row] = 1.0f / fmaxf(sum, 1.0f);
        sq_red[wave] = sq;
    }
    __syncthreads();
    if (tid == 0)
        asq_part[blockIdx.x] = sq_red[0] + sq_red[1] + sq_red[2] + sq_red[3];
}

// ---------------------------------------------------------------------------
// Tiled convert/transpose: fp32 [R,C] -> optional bf16 same layout (outN),
// optional bf16 transpose (outT).
__global__ __launch_bounds__(256) void convt_kernel(
    const float* __restrict__ in, long long sIn, int ldin,
    unsigned short* __restrict__ outN, long long sN,
    unsigned short* __restrict__ outT, long long sT, int ldT) {
    __shared__ float tile[64][65];
    const int tid = threadIdx.x;
    const long long bz = blockIdx.z;
    const int rowBase = blockIdx.y * 64, colBase = blockIdx.x * 64;
    const float* ip = in + bz * sIn;
#pragma unroll
    for (int i = 0; i < 4; ++i) {
        int r = (tid >> 4) * 4 + i;
        const float4 v = *(const float4*)(ip + (long long)(rowBase + r) * ldin + colBase + (tid & 15) * 4);
        tile[r][(tid & 15) * 4 + 0] = v.x;
        tile[r][(tid & 15) * 4 + 1] = v.y;
        tile[r][(tid & 15) * 4 + 2] = v.z;
        tile[r][(tid & 15) * 4 + 3] = v.w;
        if (outN) {
            ushort4 h;
            h.x = f2b(v.x); h.y = f2b(v.y); h.z = f2b(v.z); h.w = f2b(v.w);
            *(ushort4*)(outN + bz * sN + (long long)(rowBase + r) * ldin + colBase + (tid & 15) * 4) = h;
        }
    }
    __syncthreads();
    if (outT) {
#pragma unroll
        for (int i = 0; i < 4; ++i) {
            int oc = (tid >> 4) * 4 + i;
            ushort4 h;
            h.x = f2b(tile[(tid & 15) * 4 + 0][oc]);
            h.y = f2b(tile[(tid & 15) * 4 + 1][oc]);
            h.z = f2b(tile[(tid & 15) * 4 + 2][oc]);
            h.w = f2b(tile[(tid & 15) * 4 + 3][oc]);
            *(ushort4*)(outT + bz * sT + (long long)(colBase + oc) * ldT + rowBase + (tid & 15) * 4) = h;
        }
    }
}

// 6 weight matrices [256,256] -> transposed bf16
struct WPtrs { const float* in[6]; unsigned short* out[6]; };
__global__ __launch_bounds__(256) void wconv_kernel(WPtrs wp) {
    __shared__ float tile[64][65];
    const int tid = threadIdx.x;
    const float* in = wp.in[blockIdx.z];
    unsigned short* out = wp.out[blockIdx.z];
    const int rowBase = blockIdx.y * 64, colBase = blockIdx.x * 64;
#pragma unroll
    for (int i = 0; i < 4; ++i) {
        int r = (tid >> 4) * 4 + i;
        const float4 v = *(const float4*)(in + (long long)(rowBase + r) * 256 + colBase + (tid & 15) * 4);
        tile[r][(tid & 15) * 4 + 0] = v.x;
        tile[r][(tid & 15) * 4 + 1] = v.y;
        tile[r][(tid & 15) * 4 + 2] = v.z;
        tile[r][(tid & 15) * 4 + 3] = v.w;
    }
    __syncthreads();
#pragma unroll
    for (int i = 0; i < 4; ++i) {
        int oc = (tid >> 4) * 4 + i;
        ushort4 h;
        h.x = f2b(tile[(tid & 15) * 4 + 0][oc]);
        h.y = f2b(tile[(tid & 15) * 4 + 1][oc]);
        h.z = f2b(tile[(tid & 15) * 4 + 2][oc]);
        h.w = f2b(tile[(tid & 15) * 4 + 3][oc]);
        *(ushort4*)(out + (long long)(colBase + oc) * 256 + rowBase + (tid & 15) * 4) = h;
    }
}

// ---------------------------------------------------------------------------
// MFMA GEMM: C[M,N] = A1[M,K1]·B1t[N,K1]^T (+ A2·B2t^T) (+bias) (*rowscale)
// Double-buffered LDS + XOR-swizzled staging. Epilogue options:
//   outF fp32, outH bf16, outT bf16 TRANSPOSED (via swizzled LDS round-trip,
//   batch inferred as bz + (row>>10)), dotN coalesced bf16 dot -> dot_part,
//   sq_part = sum(out^2) per block.
struct GemmP {
    const unsigned short* A1; long long sA1; int lda1; int K1;
    const unsigned short* B1; long long sB1; int ldb1;
    const unsigned short* A2; long long sA2; int lda2; int K2;
    const unsigned short* B2; long long sB2; int ldb2;
    float* outF; long long sF;
    unsigned short* outH; long long sH;
    unsigned short* outT; long long sT; int ldt;
    int ldc;
    const float* bias;
    const float* rowscale; long long sRS;
    const unsigned short* dotN; long long sDot;
    float* dot_part;
    float* sq_part;
};

__global__ __launch_bounds__(256) void gemm_mfma(GemmP p) {
    __shared__ char smem[32768];     // dbuf staging; reused as 128x128 T-tile
    __shared__ float dred[256];
    const int tid = threadIdx.x;
    const int wave = tid >> 6, lane = tid & 63;
    const int quad = lane >> 4, l15 = lane & 15;
    const int wm = (wave & 1) * 64, wn = (wave >> 1) * 64;
    const long long bz = blockIdx.z;
    const int rowBase = blockIdx.y * 128, colBase = blockIdx.x * 128;
    const int srow = tid >> 2;
    const int skg = (((tid & 3) ^ ((srow >> 1) & 3)) * 8);  // swizzled source k-offset
    const int rsw = (l15 >> 1) & 3;                          // read-side swizzle

    const int n1 = p.K1 >> 5;
    const int n2 = p.A2 ? (p.K2 >> 5) : 0;
    const int nTot = n1 + n2;

    const unsigned short* A1p = p.A1 + bz * p.sA1;
    const unsigned short* B1p = p.B1 + bz * p.sB1;
    const unsigned short* A2p = p.A2 ? p.A2 + bz * p.sA2 : nullptr;
    const unsigned short* B2p = p.B2 ? p.B2 + bz * p.sB2 : nullptr;

    auto stage = [&](int t, int buf) {
        const unsigned short *Ao, *Bo; int lda, ldb, ko;
        if (t < n1) { Ao = A1p; Bo = B1p; lda = p.lda1; ldb = p.ldb1; ko = t * 32; }
        else        { Ao = A2p; Bo = B2p; lda = p.lda2; ldb = p.ldb2; ko = (t - n1) * 32; }
        char* la = smem + buf * 16384 + wave * 1024;
        char* lb = smem + buf * 16384 + 8192 + wave * 1024;
        gl_lds16(Ao + (long long)(rowBase + srow) * lda + ko + skg, la);
        gl_lds16(Ao + (long long)(rowBase + 64 + srow) * lda + ko + skg, la + 4096);
        gl_lds16(Bo + (long long)(colBase + srow) * ldb + ko + skg, lb);
        gl_lds16(Bo + (long long)(colBase + 64 + srow) * ldb + ko + skg, lb + 4096);
    };

    f32x4 acc[4][4] = {{{0.f}}};
    stage(0, 0);
    __syncthreads();
    int cur = 0;
    for (int t = 0; t < nTot; ++t) {
        if (t + 1 < nTot) stage(t + 1, cur ^ 1);
        const short* Ab = (const short*)(smem + cur * 16384);
        const short* Bb = (const short*)(smem + cur * 16384 + 8192);
        bf16x8 af[4], bf[4];
#pragma unroll
        for (int i = 0; i < 4; ++i)
            af[i] = *(const bf16x8*)(Ab + (wm + i * 16 + l15) * 32 + (quad ^ rsw) * 8);
#pragma unroll
        for (int j = 0; j < 4; ++j)
            bf[j] = *(const bf16x8*)(Bb + (wn + j * 16 + l15) * 32 + (quad ^ rsw) * 8);
#pragma unroll
        for (int i = 0; i < 4; ++i)
#pragma unroll
            for (int j = 0; j < 4; ++j)
                acc[i][j] = __builtin_amdgcn_mfma_f32_16x16x32_bf16(af[i], bf[j], acc[i][j], 0, 0, 0);
        __syncthreads();
        cur ^= 1;
    }

    float* oF = p.outF ? p.outF + bz * p.sF : nullptr;
    unsigned short* oH = p.outH ? p.outH + bz * p.sH : nullptr;
    const unsigned short* dN = p.dotN ? p.dotN + bz * p.sDot : nullptr;
    unsigned short* tt = (unsigned short*)smem;   // swizzled 128x128 T-tile
    float bcol[4];
#pragma unroll
    for (int j = 0; j < 4; ++j)
        bcol[j] = p.bias ? p.bias[colBase + wn + j * 16 + l15] : 0.0f;
    const float* rs = p.rowscale ? p.rowscale + bz * p.sRS : nullptr;
    float dacc = 0.f;
#pragma unroll
    for (int i = 0; i < 4; ++i) {
        ushort4 tp[4];
#pragma unroll
        for (int r = 0; r < 4; ++r) {
            int row = rowBase + wm + i * 16 + quad * 4 + r;
            float sc = rs ? rs[row] : 1.0f;
            long long ro = (long long)row * p.ldc;
#pragma unroll
            for (int j = 0; j < 4; ++j) {
                int col = colBase + wn + j * 16 + l15;
                float v = (acc[i][j][r] + bcol[j]) * sc;
                if (oF) oF[ro + col] = v;
                if (oH) oH[ro + col] = f2b(v);
                if (dN) dacc = fmaf(v, b2f(dN[ro + col]), dacc);
                if (p.sq_part) dacc = fmaf(v, v, dacc);
                ((unsigned short*)&tp[j])[r] = f2b(v);
            }
        }
        if (p.outT) {
            int lr = wm + i * 16 + quad * 4;
#pragma unroll
            for (int j = 0; j < 4; ++j) {
                int lc = wn + j * 16 + l15;
                *(ushort4*)&tt[lc * 128 + (lr ^ ((lc & 15) << 3))] = tp[j];
            }
        }
    }
    if (p.outT) {
        __syncthreads();
#pragma unroll
        for (int u = 0; u < 8; ++u) {
            int idx = u * 256 + tid;
            int c = idx >> 4;                // 0..127
            int r0 = (idx & 15) * 8;         // 0..120
            u16x8 val = *(const u16x8*)&tt[c * 128 + (r0 ^ ((c & 15) << 3))];
            int gr = rowBase + r0;
            long long tb = bz + (gr >> 10);
            *(u16x8*)(p.outT + tb * p.sT + (long long)(colBase + c) * p.ldt + (gr & 1023)) = val;
        }
    }
    if (p.dot_part || p.sq_part) {
        dred[tid] = dacc;
        __syncthreads();
        for (int k = 128; k > 0; k >>= 1) {
            if (tid < k) dred[tid] += dred[tid + k];
            __syncthreads();
        }
        if (tid == 0) {
            float* dst = p.dot_part ? p.dot_part : p.sq_part;
            dst[((long long)bz * gridDim.y + blockIdx.y) * gridDim.x + blockIdx.x] = dred[0];
        }
    }
}

// ---------------------------------------------------------------------------
// Fused SAGE pre-norm GEMM: out[32768,256] = l2norm_relu(A1·B1t^T + A2·B2t^T
// + bias), bf16 out. Full row width in one block (128x256 tile, 8 waves)
// so the per-row l2 norm is computed in-block.
struct SageP {
    const unsigned short* A1; const unsigned short* B1;
    const unsigned short* A2; const unsigned short* B2;
    const float* bias;
    unsigned short* out;
};

__global__ __launch_bounds__(512) void sage_mfma(SageP p) {
    __shared__ short As[2][4096];      // 128x32
    __shared__ short Bs[2][8192];      // 256x32
    __shared__ float rsum[4][128];
    const int tid = threadIdx.x;
    const int wave = tid >> 6, lane = tid & 63;
    const int quad = lane >> 4, l15 = lane & 15;
    const int wm = (wave & 1) * 64, wn = (wave >> 1) * 64;  // 2m x 4n waves
    const int rowBase = blockIdx.x * 128;
    const int srow = tid >> 2;                 // 0..127
    const int skg = (((tid & 3) ^ ((srow >> 1) & 3)) * 8);
    const int rsw = (l15 >> 1) & 3;

    auto stage = [&](int t, int buf) {
        const unsigned short* Ao = (t < 8) ? p.A1 : p.A2;
        const unsigned short* Bo = (t < 8) ? p.B1 : p.B2;
        int ko = (t & 7) * 32;
        char* la = (char*)As[buf] + wave * 1024;
        char* lb = (char*)Bs[buf] + wave * 1024;
        gl_lds16(Ao + (long long)(rowBase + srow) * 256 + ko + skg, la);
        gl_lds16(Bo + (long long)srow * 256 + ko + skg, lb);
        gl_lds16(Bo + (long long)(128 + srow) * 256 + ko + skg, lb + 8192);
    };

    f32x4 acc[4][4] = {{{0.f}}};
    stage(0, 0);
    __syncthreads();
    int cur = 0;
    for (int t = 0; t < 16; ++t) {
        if (t + 1 < 16) stage(t + 1, cur ^ 1);
        const short* Ab = As[cur];
        const short* Bb = Bs[cur];
        bf16x8 af[4], bf[4];
#pragma unroll
        for (int i = 0; i < 4; ++i)
            af[i] = *(const bf16x8*)(Ab + (wm + i * 16 + l15) * 32 + (quad ^ rsw) * 8);
#pragma unroll
        for (int j = 0; j < 4; ++j)
            bf[j] = *(const bf16x8*)(Bb + (wn + j * 16 + l15) * 32 + (quad ^ rsw) * 8);
#pragma unroll
        for (int i = 0; i < 4; ++i)
#pragma unroll
            for (int j = 0; j < 4; ++j)
                acc[i][j] = __builtin_amdgcn_mfma_f32_16x16x32_bf16(af[i], bf[j], acc[i][j], 0, 0, 0);
        __syncthreads();
        cur ^= 1;
    }

    float bcol[4];
#pragma unroll
    for (int j = 0; j < 4; ++j)
        bcol[j] = p.bias[wn + j * 16 + l15];

    // per-row sum of squares: 16-lane shuffle reduce, cross-wave via LDS
#pragma unroll
    for (int i = 0; i < 4; ++i)
#pragma unroll
        for (int r = 0; r < 4; ++r) {
            float ss = 0.f;
#pragma unroll
            for (int j = 0; j < 4; ++j) {
                float v = acc[i][j][r] + bcol[j];
                ss = fmaf(v, v, ss);
            }
#pragma unroll
            for (int off = 1; off < 16; off <<= 1) ss += __shfl_xor(ss, off);
            if (l15 == 0) rsum[wave >> 1][wm + i * 16 + quad * 4 + r] = ss;
        }
    __syncthreads();
#pragma unroll
    for (int i = 0; i < 4; ++i)
#pragma unroll
        for (int r = 0; r < 4; ++r) {
            int lrow = wm + i * 16 + quad * 4 + r;
            float tot = rsum[0][lrow] + rsum[1][lrow] + rsum[2][lrow] + rsum[3][lrow];
            float rn = 1.0f / fmaxf(sqrtf(tot), 1e-12f);
            long long ro = (long long)(rowBase + lrow) * 256;
#pragma unroll
            for (int j = 0; j < 4; ++j) {
                float v = (acc[i][j][r] + bcol[j]) * rn;
                p.out[ro + wn + j * 16 + l15] = f2b(fmaxf(v, 0.0f));
            }
        }
}

// ---------------------------------------------------------------------------
// G = sT · sT^T via MFMA (dbuf + swizzle); writes G bf16 and reduces
// ssq = sum(G^2), tr = trace partials per block.
__global__ __launch_bounds__(256) void sts_clu_mfma(
    const unsigned short* __restrict__ sT, unsigned short* __restrict__ gout,
    float* __restrict__ ssq_part, float* __restrict__ tr_part) {
    __shared__ short As[2][128 * 32];
    __shared__ short Bs[2][128 * 32];
    __shared__ float red[2][256];
    const int tid = threadIdx.x;
    const int wave = tid >> 6, lane = tid & 63;
    const int quad = lane >> 4, l15 = lane & 15;
    const int wm = (wave & 1) * 64, wn = (wave >> 1) * 64;
    const long long bz = blockIdx.z;
    const unsigned short* S = sT + bz * 262144;
    const int rowBase = blockIdx.y * 128, colBase = blockIdx.x * 128;
    const int srow = tid >> 2;
    const int skg = (((tid & 3) ^ ((srow >> 1) & 3)) * 8);
    const int rsw = (l15 >> 1) & 3;

    auto stage = [&](int t, int buf) {
        int ko = t * 32;
        char* la = (char*)As + buf * 8192 + wave * 1024;
        char* lb = (char*)Bs + buf * 8192 + wave * 1024;
        gl_lds16(S + (long long)(rowBase + srow) * 1024 + ko + skg, la);
        gl_lds16(S + (long long)(rowBase + 64 + srow) * 1024 + ko + skg, la + 4096);
        gl_lds16(S + (long long)(colBase + srow) * 1024 + ko + skg, lb);
        gl_lds16(S + (long long)(colBase + 64 + srow) * 1024 + ko + skg, lb + 4096);
    };

    f32x4 acc[4][4] = {{{0.f}}};
    stage(0, 0);
    __syncthreads();
    int cur = 0;
    for (int t = 0; t < 32; ++t) {
        if (t + 1 < 32) stage(t + 1, cur ^ 1);
        const short* Ab = (const short*)((char*)As + cur * 8192);
        const short* Bb = (const short*)((char*)Bs + cur * 8192);
        bf16x8 af[4], bf[4];
#pragma unroll
        for (int i = 0; i < 4; ++i)
            af[i] = *(const bf16x8*)(Ab + (wm + i * 16 + l15) * 32 + (quad ^ rsw) * 8);
#pragma unroll
        for (int j = 0; j < 4; ++j)
            bf[j] = *(const bf16x8*)(Bb + (wn + j * 16 + l15) * 32 + (quad ^ rsw) * 8);
#pragma unroll
        for (int i = 0; i < 4; ++i)
#pragma unroll
            for (int j = 0; j < 4; ++j)
                acc[i][j] = __builtin_amdgcn_mfma_f32_16x16x32_bf16(af[i], bf[j], acc[i][j], 0, 0, 0);
        __syncthreads();
        cur ^= 1;
    }
    unsigned short* go = gout + bz * 65536;
    float ssq = 0.f, tr = 0.f;
#pragma unroll
    for (int i = 0; i < 4; ++i)
#pragma unroll
        for (int r = 0; r < 4; ++r) {
            int row = rowBase + wm + i * 16 + quad * 4 + r;
#pragma unroll
            for (int j = 0; j < 4; ++j) {
                int col = colBase + wn + j * 16 + l15;
                float v = acc[i][j][r];
                go[(long long)row * 256 + col] = f2b(v);
                ssq = fmaf(v, v, ssq);
                if (row == col) tr += v;
            }
        }
    red[0][tid] = ssq;
    red[1][tid] = tr;
    __syncthreads();
    for (int k = 128; k > 0; k >>= 1) {
        if (tid < k) {
            red[0][tid] += red[0][tid + k];
            red[1][tid] += red[1][tid + k];
        }
        __syncthreads();
    }
    if (tid == 0) {
        int bid = (int)(blockIdx.z * 4 + blockIdx.y * 2 + blockIdx.x);
        ssq_part[bid] = red[0][0];
        tr_part[bid] = red[1][0];
    }
}

// ---------------------------------------------------------------------------
// trq = sum( (P·G) ∘ (G·P) ) = tr(G P^T G P)  [G symmetric].
// Computes M1=G·P and M3=P·G tiles in registers at the same (r,c) and dots
// them locally — no M1 materialization, no uncoalesced transposed read.
__global__ __launch_bounds__(256) void trq_mfma(
    const unsigned short* __restrict__ G, const unsigned short* __restrict__ P,
    const unsigned short* __restrict__ PT, float* __restrict__ trq_part) {
    __shared__ short sm[4][2][4096];   // [GA,PB,PA,GB][buf][128x32]
    __shared__ float dred[256];
    const int tid = threadIdx.x;
    const int wave = tid >> 6, lane = tid & 63;
    const int quad = lane >> 4, l15 = lane & 15;
    const int wm = (wave & 1) * 64, wn = (wave >> 1) * 64;
    const long long bz = blockIdx.z;
    const int rowBase = blockIdx.y * 128, colBase = blockIdx.x * 128;
    const int srow = tid >> 2;
    const int skg = (((tid & 3) ^ ((srow >> 1) & 3)) * 8);
    const int rsw = (l15 >> 1) & 3;
    const unsigned short* Gb = G + bz * 65536;
    const unsigned short* Pb = P + bz * 65536;
    const unsigned short* PTb = PT + bz * 65536;

    auto stage = [&](int t, int buf) {
        int ko = t * 32;
#pragma unroll
        for (int h = 0; h < 2; ++h) {
            int rr = rowBase + h * 64 + srow, cc = colBase + h * 64 + srow;
            gl_lds16(Gb + (long long)rr * 256 + ko + skg, (char*)sm[0][buf] + h * 4096 + wave * 1024);
            gl_lds16(PTb + (long long)cc * 256 + ko + skg, (char*)sm[1][buf] + h * 4096 + wave * 1024);
            gl_lds16(Pb + (long long)rr * 256 + ko + skg, (char*)sm[2][buf] + h * 4096 + wave * 1024);
            gl_lds16(Gb + (long long)cc * 256 + ko + skg, (char*)sm[3][buf] + h * 4096 + wave * 1024);
        }
    };

    f32x4 a1[4][4] = {{{0.f}}};
    f32x4 a3[4][4] = {{{0.f}}};
    stage(0, 0);
    __syncthreads();
    int cur = 0;
    for (int t = 0; t < 8; ++t) {
        if (t + 1 < 8) stage(t + 1, cur ^ 1);
        bf16x8 gA[4], pB[4], pA[4], gB[4];
#pragma unroll
        for (int i = 0; i < 4; ++i) {
            int ro = (wm + i * 16 + l15) * 32 + (quad ^ rsw) * 8;
            gA[i] = *(const bf16x8*)(sm[0][cur] + ro);
            pA[i] = *(const bf16x8*)(sm[2][cur] + ro);
        }
#pragma unroll
        for (int j = 0; j < 4; ++j) {
            int co = (wn + j * 16 + l15) * 32 + (quad ^ rsw) * 8;
            pB[j] = *(const bf16x8*)(sm[1][cur] + co);
            gB[j] = *(const bf16x8*)(sm[3][cur] + co);
        }
#pragma unroll
        for (int i = 0; i < 4; ++i)
#pragma unroll
            for (int j = 0; j < 4; ++j) {
                a1[i][j] = __builtin_amdgcn_mfma_f32_16x16x32_bf16(gA[i], pB[j], a1[i][j], 0, 0, 0);
                a3[i][j] = __builtin_amdgcn_mfma_f32_16x16x32_bf16(pA[i], gB[j], a3[i][j], 0, 0, 0);
            }
        __syncthreads();
        cur ^= 1;
    }
    float dacc = 0.f;
#pragma unroll
    for (int i = 0; i < 4; ++i)
#pragma unroll
        for (int j = 0; j < 4; ++j)
#pragma unroll
            for (int r = 0; r < 4; ++r)
                dacc = fmaf(a3[i][j][r], a1[i][j][r], dacc);
    dred[tid] = dacc;
    __syncthreads();
    for (int k = 128; k > 0; k >>= 1) {
        if (tid < k) dred[tid] += dred[tid + k];
        __syncthreads();
    }
    if (tid == 0)
        trq_part[(blockIdx.z * 2 + blockIdx.y) * 2 + blockIdx.x] = dred[0];
}

// ---------------------------------------------------------------------------
// Pass 1 over logits: per-row softmax stats (max, 1/den) + column scores.
__global__ __launch_bounds__(256) void smstat_kernel(
    const float* __restrict__ s, float* __restrict__ rowmax,
    float* __restrict__ rowrden, float* __restrict__ scores) {
    __shared__ float sacc[4][256];
    const int tid = threadIdx.x;
    const int wave = tid >> 6, lane = tid & 63;
    const int b = blockIdx.x >> 5;
    const long long row0 = (long long)blockIdx.x * 32;
    float c0 = 0.f, c1 = 0.f, c2 = 0.f, c3 = 0.f;
#pragma unroll
    for (int q = 0; q < 8; ++q) {
        long long row = row0 + wave * 8 + q;
        const float4 v = *(const float4*)(s + row * 256 + lane * 4);
        float m = fmaxf(fmaxf(v.x, v.y), fmaxf(v.z, v.w));
#pragma unroll
        for (int off = 32; off > 0; off >>= 1) m = fmaxf(m, __shfl_xor(m, off));
        float e0 = expf(v.x - m), e1 = expf(v.y - m);
        float e2 = expf(v.z - m), e3 = expf(v.w - m);
        float den = e0 + e1 + e2 + e3;
#pragma unroll
        for (int off = 32; off > 0; off >>= 1) den += __shfl_xor(den, off);
        float rd = 1.0f / den;
        if (lane == 0) { rowmax[row] = m; rowrden[row] = rd; }
        c0 = fmaf(e0, rd, c0); c1 = fmaf(e1, rd, c1);
        c2 = fmaf(e2, rd, c2); c3 = fmaf(e3, rd, c3);
    }
    sacc[wave][lane * 4 + 0] = c0;
    sacc[wave][lane * 4 + 1] = c1;
    sacc[wave][lane * 4 + 2] = c2;
    sacc[wave][lane * 4 + 3] = c3;
    __syncthreads();
    float t0 = sacc[0][tid] + sacc[1][tid] + sacc[2][tid] + sacc[3][tid];
    atomicAdd(&scores[b * 256 + tid], t0);
}

// fused top-k threshold + sigmoid gate
__global__ __launch_bounds__(256) void topkgate_kernel(const float* __restrict__ scores,
                                                       float* __restrict__ gate) {
    __shared__ float vals[256];
    __shared__ float th;
    int b = blockIdx.x, tid = threadIdx.x;
    float v = scores[b * 256 + tid];
    vals[tid] = v;
    __syncthreads();
    int rank = 0;
    for (int j = 0; j < 256; ++j) {
        float u = vals[j];
        rank += (u > v) || (u == v && j < tid);
    }
    if (rank == 127) th = v;
    __syncthreads();
    float z = (v - th) * 10.0f;  // 1/TEMP
    gate[b * 256 + tid] = 1.0f / (1.0f + expf(-z));
}

// ---------------------------------------------------------------------------
// Pass 2: gated softmax from logits + stats. Writes s fp32 (final output),
// s_bf row-major, sT bf16 transposed (64x64 tiles), entropy partials.
__global__ __launch_bounds__(256) void gatefin_kernel(
    float* __restrict__ s, const float* __restrict__ rowmax,
    const float* __restrict__ rowrden, const float* __restrict__ gate,
    unsigned short* __restrict__ sbf, unsigned short* __restrict__ sT,
    float* __restrict__ ent_part) {
    __shared__ float tile[64][65];
    __shared__ float red[256];
    const int tid = threadIdx.x;
    const long long bz = blockIdx.z;
    const int rowBase = blockIdx.y * 64, colBase = blockIdx.x * 64;
    const int c4 = (tid & 15) * 4;
    const float g0 = gate[bz * 256 + colBase + c4 + 0];
    const float g1 = gate[bz * 256 + colBase + c4 + 1];
    const float g2 = gate[bz * 256 + colBase + c4 + 2];
    const float g3 = gate[bz * 256 + colBase + c4 + 3];
    float ent = 0.f;
#pragma unroll
    for (int i = 0; i < 4; ++i) {
        int r = (tid >> 4) * 4 + i;
        long long grow = bz * 1024 + rowBase + r;
        float4 v = *(const float4*)(s + grow * 256 + colBase + c4);
        float m = rowmax[grow], rd = rowrden[grow];
        float p0 = expf(v.x - m) * rd * g0;
        float p1 = expf(v.y - m) * rd * g1;
        float p2 = expf(v.z - m) * rd * g2;
        float p3 = expf(v.w - m) * rd * g3;
        float4 pv; pv.x = p0; pv.y = p1; pv.z = p2; pv.w = p3;
        *(float4*)(s + grow * 256 + colBase + c4) = pv;
        ushort4 h;
        h.x = f2b(p0); h.y = f2b(p1); h.z = f2b(p2); h.w = f2b(p3);
        *(ushort4*)(sbf + grow * 256 + colBase + c4) = h;
        tile[r][c4 + 0] = p0; tile[r][c4 + 1] = p1;
        tile[r][c4 + 2] = p2; tile[r][c4 + 3] = p3;
        ent -= p0 * logf(p0 + 1e-15f) + p1 * logf(p1 + 1e-15f) +
               p2 * logf(p2 + 1e-15f) + p3 * logf(p3 + 1e-15f);
    }
    __syncthreads();
#pragma unroll
    for (int i = 0; i < 4; ++i) {
        int oc = (tid >> 4) * 4 + i;
        ushort4 h;
        h.x = f2b(tile[c4 + 0][oc]);
        h.y = f2b(tile[c4 + 1][oc]);
        h.z = f2b(tile[c4 + 2][oc]);
        h.w = f2b(tile[c4 + 3][oc]);
        *(ushort4*)(sT + bz * 262144 + (long long)(colBase + oc) * 1024 + rowBase + c4) = h;
    }
    red[tid] = ent;
    __syncthreads();
    for (int k = 128; k > 0; k >>= 1) {
        if (tid < k) red[tid] += red[tid + k];
        __syncthreads();
    }
    if (tid == 0)
        ent_part[((long long)bz * gridDim.y + blockIdx.y) * gridDim.x + blockIdx.x] = red[0];
}

// ---------------------------------------------------------------------------
__global__ __launch_bounds__(256) void finalize_kernel(const float* __restrict__ ent_part,
                                                       const float* __restrict__ asq_part,
                                                       const float* __restrict__ psq_part,
                                                       const float* __restrict__ sdot_part,
                                                       const float* __restrict__ trq_part,
                                                       const float* __restrict__ ssq_part,
                                                       const float* __restrict__ tr_part,
                                                       float* __restrict__ scal) {
    __shared__ float red[7][256];
    int tid = threadIdx.x;
    float e = 0.f, asq = 0.f, psq = 0.f, sd = 0.f, tq = 0.f, clu = 0.f, ssqa = 0.f;
    for (int i = tid; i < 2048; i += 256) e += ent_part[i];
    for (int i = tid; i < 8192; i += 256) asq += asq_part[i];
    if (tid < 128) psq = psq_part[tid];
    for (int i = tid; i < 512; i += 256) sd += sdot_part[i];
    if (tid < 128) tq = trq_part[tid];
    if (tid < 32) {
        float ssq = 0.f, tr = 0.f;
#pragma unroll
        for (int i = 0; i < 4; ++i) {
            ssq += ssq_part[tid * 4 + i];
            tr  += tr_part[tid * 4 + i];
        }
        ssqa = ssq;
        float fro = fmaxf(sqrtf(ssq), 1e-12f);
        float val = ssq / (fro * fro) - tr / (8.0f * fro) + 1.0f;  // ||G/fro - I/16||_F^2
        clu = sqrtf(fmaxf(val, 0.0f));
    }
    red[0][tid] = e; red[1][tid] = asq; red[2][tid] = psq; red[3][tid] = sd;
    red[4][tid] = tq; red[5][tid] = clu; red[6][tid] = ssqa;
    __syncthreads();
    for (int k = 128; k > 0; k >>= 1) {
        if (tid < k) {
#pragma unroll
            for (int q = 0; q < 7; ++q) red[q][tid] += red[q][tid + k];
        }
        __syncthreads();
    }
    if (tid == 0) {
        const float numel = 33554432.0f;  // B*N*N
        float linksq  = red[1][0] - 2.0f * red[3][0] + red[6][0];   // asq - 2<S,AS> + ||G||^2
        float reconsq = red[1][0] - 2.0f * red[2][0] + red[4][0];   // asq - 2||P||^2 + tr(GP'GP)
        scal[0] = sqrtf(fmaxf(linksq, 0.0f)) / numel;   // link
        scal[1] = red[0][0] / 32768.0f;                 // ent
        scal[2] = red[5][0] / 32.0f;                    // clu
        scal[3] = sqrtf(fmaxf(reconsq, 0.0f)) / numel;  // recon
    }
}

// ---------------------------------------------------------------------------
extern "C" void kernel_launch(void* const* d_in, const int* in_sizes, int n_in,
                              void* d_out, int out_size, void* d_ws, size_t ws_size,
                              hipStream_t stream) {
    const float* x    = (const float*)d_in[0];
    const float* adj  = (const float*)d_in[1];
    const float* Wr_p = (const float*)d_in[2];
    const float* br_p = (const float*)d_in[3];
    const float* Wo_p = (const float*)d_in[4];
    const float* Wl_p = (const float*)d_in[5];
    const float* bl_p = (const float*)d_in[6];
    const float* Wr_e = (const float*)d_in[7];
    const float* br_e = (const float*)d_in[8];
    const float* Wo_e = (const float*)d_in[9];
    const float* Wl_e = (const float*)d_in[10];
    const float* bl_e = (const float*)d_in[11];

    float* out    = (float*)d_out;
    float* xp     = out;              // [32,256,256]
    float* adj_p  = out + 2097152;    // [32,256,256]
    float* s      = out + 4194304;    // [32,1024,256] fp32
    float* scal   = out + 12582912;
    float* node_x = out + 12582916;   // [32,1024,256] fp32

    char* w = (char*)d_ws;
    float* degsum     = (float*)w; w += 32768 * 4;   // deginv; reused as rowmax
    float* scores     = (float*)w; w += 8192 * 4;
    float* thresh     = (float*)w; w += 256 * 4;     // (unused now, kept for layout)
    float* gatep      = (float*)w; w += 8192 * 4;
    float* ent_part   = (float*)w; w += 32768 * 4;   // 2048 used
    float* asq_part   = (float*)w; w += 8192 * 4;
    float* psq_part   = (float*)w; w += 512 * 4;     // 128 used
    float* sdot_part  = (float*)w; w += 1024 * 4;    // 512 used
    float* trq_part   = (float*)w; w += 256 * 4;     // 128 used
    float* ssq_part   = (float*)w; w += 256 * 4;
    float* tr_part    = (float*)w; w += 256 * 4;
    unsigned short* WT   = (unsigned short*)w; w += 6LL * 65536 * 2;
    unsigned short* bufA = (unsigned short*)w; w += 33554432LL * 2;  // adj_bf
    unsigned short* bufB = (unsigned short*)w; w += 8388608LL * 2;   // x_bf -> {G_bf, PT_bf}
    unsigned short* bufC = (unsigned short*)w; w += 8388608LL * 2;   // xT_bf -> sT_bf
    unsigned short* bufD = (unsigned short*)w; w += 8388608LL * 2;   // agg_bf -> nxT_bf
    unsigned short* bufE = (unsigned short*)w; w += 8388608LL * 2;   // h_bf
    unsigned short* bufF = (unsigned short*)w; w += 8388608LL * 2;   // aTsT_bf
    unsigned short* bufG = (unsigned short*)w; w += 8388608LL * 2;   // s_bf
    unsigned short* bufH = (unsigned short*)w; w += 2097152LL * 2;   // rowrden, then P_bf

    unsigned short* G_bf  = bufB;                        // [32,256,256] bf16
    unsigned short* PT_bf = bufB + 2097152;              // [32,256,256] bf16
    float* rowmax  = degsum;         // dead after gemm4
    float* rowrden = (float*)bufH;   // bufH not P_bf until step 14
    (void)thresh;

    hipMemsetAsync(scores, 0, 8192 * sizeof(float), stream);

    // 1) adj -> adj_bf + 1/deg + sum(adj^2) partials
    adjconv_kernel<<<8192, 256, 0, stream>>>(adj, bufA, degsum, asq_part);

    // 2) x -> x_bf + xT_bf
    convt_kernel<<<dim3(4, 16, 32), 256, 0, stream>>>(
        x, 262144LL, 256, bufB, 262144LL, bufC, 262144LL, 1024);

    // 3) weights -> transposed bf16
    WPtrs wp;
    wp.in[0] = Wr_p; wp.in[1] = Wo_p; wp.in[2] = Wl_p;
    wp.in[3] = Wr_e; wp.in[4] = Wo_e; wp.in[5] = Wl_e;
    for (int i = 0; i < 6; ++i) wp.out[i] = WT + (long long)i * 65536;
    wconv_kernel<<<dim3(4, 4, 6), 256, 0, stream>>>(wp);

    GemmP g;
    // 4) agg = (adj @ x) * deg -> agg_bf (bufD)
    g = {};
    g.A1 = bufA; g.sA1 = 1048576; g.lda1 = 1024; g.K1 = 1024;
    g.B1 = bufC; g.sB1 = 262144; g.ldb1 = 1024;
    g.outH = bufD; g.sH = 262144; g.ldc = 256;
    g.rowscale = degsum; g.sRS = 1024;
    gemm_mfma<<<dim3(2, 8, 32), 256, 0, stream>>>(g);

    // 5) pool pre-norm fused: h_p = l2relu(agg@Wr_p + x@Wo_p + br_p) -> bufE
    SageP sp;
    sp.A1 = bufD; sp.B1 = WT + 0 * 65536;
    sp.A2 = bufB; sp.B2 = WT + 1 * 65536;
    sp.bias = br_p; sp.out = bufE;
    sage_mfma<<<256, 512, 0, stream>>>(sp);

    // 6) s_logits = h @ Wl_p + bl_p -> s (fp32)
    g = {};
    g.A1 = bufE; g.sA1 = 0; g.lda1 = 256; g.K1 = 256; g.B1 = WT + 2 * 65536; g.sB1 = 0; g.ldb1 = 256;
    g.outF = s; g.sF = 0; g.ldc = 256; g.bias = bl_p;
    gemm_mfma<<<dim3(2, 256, 1), 256, 0, stream>>>(g);

    // 7) embed pre-norm fused -> bufE
    sp.A1 = bufD; sp.B1 = WT + 3 * 65536;
    sp.A2 = bufB; sp.B2 = WT + 4 * 65536;
    sp.bias = br_e; sp.out = bufE;
    sage_mfma<<<256, 512, 0, stream>>>(sp);

    // 8) node_x = h_e @ Wl_e + bl_e (fp32) + transposed bf16 -> bufD (nxT)
    g = {};
    g.A1 = bufE; g.sA1 = 0; g.lda1 = 256; g.K1 = 256; g.B1 = WT + 5 * 65536; g.sB1 = 0; g.ldb1 = 256;
    g.outF = node_x; g.sF = 0; g.ldc = 256; g.bias = bl_e;
    g.outT = bufD; g.sT = 262144; g.ldt = 1024;
    gemm_mfma<<<dim3(2, 256, 1), 256, 0, stream>>>(g);

    // 9) softmax stats + scores; topk+gate; gated finalize (s, s_bf, sT, ent)
    smstat_kernel<<<1024, 256, 0, stream>>>(s, rowmax, rowrden, scores);
    topkgate_kernel<<<32, 256, 0, stream>>>(scores, gatep);
    gatefin_kernel<<<dim3(4, 16, 32), 256, 0, stream>>>(
        s, rowmax, rowrden, gatep, bufG, bufC, ent_part);

    // 10) xp = sT · nxT^T (fp32 out)
    g = {};
    g.A1 = bufC; g.sA1 = 262144; g.lda1 = 1024; g.K1 = 1024;
    g.B1 = bufD; g.sB1 = 262144; g.ldb1 = 1024;
    g.outF = xp; g.sF = 65536; g.ldc = 256;
    gemm_mfma<<<dim3(2, 2, 32), 256, 0, stream>>>(g);

    // 11) aTs = adj · s: transposed bf16 -> bufF, link dot <S, A·S> -> sdot
    g = {};
    g.A1 = bufA; g.sA1 = 1048576; g.lda1 = 1024; g.K1 = 1024;
    g.B1 = bufC; g.sB1 = 262144; g.ldb1 = 1024;
    g.ldc = 256;
    g.outT = bufF; g.sT = 262144; g.ldt = 1024;
    g.dotN = bufG; g.sDot = 262144; g.dot_part = sdot_part;
    gemm_mfma<<<dim3(2, 8, 32), 256, 0, stream>>>(g);

    // 12) G = sT·sT^T -> G_bf + ssq/tr partials (clu & link terms)
    sts_clu_mfma<<<dim3(2, 2, 32), 256, 0, stream>>>(bufC, G_bf, ssq_part, tr_part);

    // 13) adj_p = sT · aTsT^T: fp32 out + P_bf + PT_bf + ||P||^2 partials
    g = {};
    g.A1 = bufC; g.sA1 = 262144; g.lda1 = 1024; g.K1 = 1024;
    g.B1 = bufF; g.sB1 = 262144; g.ldb1 = 1024;
    g.outF = adj_p; g.sF = 65536; g.ldc = 256;
    g.outH = bufH; g.sH = 65536;
    g.outT = PT_bf; g.sT = 65536; g.ldt = 256;
    g.sq_part = psq_part;
    gemm_mfma<<<dim3(2, 2, 32), 256, 0, stream>>>(g);

    // 14) trq = <P·G, G·P> (recon trace term), register-local dot
    trq_mfma<<<dim3(2, 2, 32), 256, 0, stream>>>(G_bf, bufH, PT_bf, trq_part);

    // 15) finalize
    finalize_kernel<<<1, 256, 0, stream>>>(ent_part, asq_part, psq_part, sdot_part,
                                           trq_part, ssq_part, tr_part, scal);
}

// Round 5
// 554.100 us; speedup vs baseline: 1.3776x; 1.0468x over previous
//
#include <hip/hip_runtime.h>
#include <hip/hip_bf16.h>
#include <math.h>

// B=32, N=1024, D=H=E=C=256, K_top=128, TEMP=0.1, EPS=1e-15

typedef short bf16x8 __attribute__((ext_vector_type(8)));   // 8 bf16 raw bits (4 VGPRs)
typedef float f32x4 __attribute__((ext_vector_type(4)));
typedef unsigned short u16x8 __attribute__((ext_vector_type(8)));

__device__ inline void gl_lds16(const void* g, void* l) {
    __builtin_amdgcn_global_load_lds(
        (const __attribute__((address_space(1))) void*)g,
        (__attribute__((address_space(3))) void*)l, 16, 0, 0);
}

__device__ inline unsigned short f2b(float f) {
    union { __hip_bfloat16 h; unsigned short u; } cv;
    cv.h = __float2bfloat16(f);
    return cv.u;
}
__device__ inline float b2f(unsigned short u) {
    union { unsigned short u; __hip_bfloat16 h; } cv;
    cv.u = u;
    return __bfloat162float(cv.h);
}

// ---------------------------------------------------------------------------
// Tiled convert/transpose: fp32 [R,C] -> optional bf16 same layout (outN),
// optional bf16 transpose (outT).
__global__ __launch_bounds__(256) void convt_kernel(
    const float* __restrict__ in, long long sIn, int ldin,
    unsigned short* __restrict__ outN, long long sN,
    unsigned short* __restrict__ outT, long long sT, int ldT) {
    __shared__ float tile[64][65];
    const int tid = threadIdx.x;
    const long long bz = blockIdx.z;
    const int rowBase = blockIdx.y * 64, colBase = blockIdx.x * 64;
    const float* ip = in + bz * sIn;
#pragma unroll
    for (int i = 0; i < 4; ++i) {
        int r = (tid >> 4) * 4 + i;
        const float4 v = *(const float4*)(ip + (long long)(rowBase + r) * ldin + colBase + (tid & 15) * 4);
        tile[r][(tid & 15) * 4 + 0] = v.x;
        tile[r][(tid & 15) * 4 + 1] = v.y;
        tile[r][(tid & 15) * 4 + 2] = v.z;
        tile[r][(tid & 15) * 4 + 3] = v.w;
        if (outN) {
            ushort4 h;
            h.x = f2b(v.x); h.y = f2b(v.y); h.z = f2b(v.z); h.w = f2b(v.w);
            *(ushort4*)(outN + bz * sN + (long long)(rowBase + r) * ldin + colBase + (tid & 15) * 4) = h;
        }
    }
    __syncthreads();
    if (outT) {
#pragma unroll
        for (int i = 0; i < 4; ++i) {
            int oc = (tid >> 4) * 4 + i;
            ushort4 h;
            h.x = f2b(tile[(tid & 15) * 4 + 0][oc]);
            h.y = f2b(tile[(tid & 15) * 4 + 1][oc]);
            h.z = f2b(tile[(tid & 15) * 4 + 2][oc]);
            h.w = f2b(tile[(tid & 15) * 4 + 3][oc]);
            *(ushort4*)(outT + bz * sT + (long long)(colBase + oc) * ldT + rowBase + (tid & 15) * 4) = h;
        }
    }
}

// 6 weight matrices [256,256] -> transposed bf16
struct WPtrs { const float* in[6]; unsigned short* out[6]; };
__global__ __launch_bounds__(256) void wconv_kernel(WPtrs wp) {
    __shared__ float tile[64][65];
    const int tid = threadIdx.x;
    const float* in = wp.in[blockIdx.z];
    unsigned short* out = wp.out[blockIdx.z];
    const int rowBase = blockIdx.y * 64, colBase = blockIdx.x * 64;
#pragma unroll
    for (int i = 0; i < 4; ++i) {
        int r = (tid >> 4) * 4 + i;
        const float4 v = *(const float4*)(in + (long long)(rowBase + r) * 256 + colBase + (tid & 15) * 4);
        tile[r][(tid & 15) * 4 + 0] = v.x;
        tile[r][(tid & 15) * 4 + 1] = v.y;
        tile[r][(tid & 15) * 4 + 2] = v.z;
        tile[r][(tid & 15) * 4 + 3] = v.w;
    }
    __syncthreads();
#pragma unroll
    for (int i = 0; i < 4; ++i) {
        int oc = (tid >> 4) * 4 + i;
        ushort4 h;
        h.x = f2b(tile[(tid & 15) * 4 + 0][oc]);
        h.y = f2b(tile[(tid & 15) * 4 + 1][oc]);
        h.z = f2b(tile[(tid & 15) * 4 + 2][oc]);
        h.w = f2b(tile[(tid & 15) * 4 + 3][oc]);
        *(ushort4*)(out + (long long)(colBase + oc) * 256 + rowBase + (tid & 15) * 4) = h;
    }
}

// ---------------------------------------------------------------------------
// Fused adj pass + agg GEMM: reads adj fp32 ONCE, reg-stages to bf16 LDS
// (write-side swizzle), emits adj_bf for later reuse, computes per-row
// 1/max(deg,1) in-flight (LDS only), sum(adj^2) partials, and
// agg = (adj @ x) * deginv -> bf16. Tile 128x256 (full N), 8 waves.
struct AggP {
    const float* adj;            // [32,1024,1024] fp32
    const unsigned short* xT;    // [32,256,1024] bf16
    unsigned short* adj_bf;      // [32,1024,1024] bf16 out
    unsigned short* agg;         // [32,1024,256] bf16 out
    float* asq_part;             // [256]
};

__global__ __launch_bounds__(512) void aggdeg_mfma(AggP p) {
    __shared__ short As[2][128 * 32];
    __shared__ short Bs[2][256 * 32];
    __shared__ float deginv_lds[128];
    __shared__ float sred[512];
    const int tid = threadIdx.x;
    const int wave = tid >> 6, lane = tid & 63;
    const int quad = lane >> 4, l15 = lane & 15;
    const int wm = (wave & 1) * 64, wn = (wave >> 1) * 64;   // 2m x 4n waves
    const int rowBase = blockIdx.x * 128;
    const long long bz = blockIdx.y;
    const int srow = tid >> 2, kq = tid & 3;
    const int sw = (srow >> 1) & 3;
    const int skg = ((kq ^ sw) * 8);
    const int rsw = (l15 >> 1) & 3;

    const float* adjp = p.adj + bz * 1048576 + (long long)(rowBase + srow) * 1024 + kq * 8;
    unsigned short* abf = p.adj_bf + bz * 1048576 + (long long)(rowBase + srow) * 1024 + kq * 8;
    const unsigned short* xTp = p.xT + bz * 262144;

    float4 ra, rb;
    float degacc = 0.f, sqacc = 0.f;

    auto loadA = [&](int t) {
        ra = *(const float4*)(adjp + t * 32);
        rb = *(const float4*)(adjp + t * 32 + 4);
    };
    auto procA = [&](int t, int buf) {
        u16x8 h;
        h[0] = f2b(ra.x); h[1] = f2b(ra.y); h[2] = f2b(ra.z); h[3] = f2b(ra.w);
        h[4] = f2b(rb.x); h[5] = f2b(rb.y); h[6] = f2b(rb.z); h[7] = f2b(rb.w);
        *(u16x8*)(abf + t * 32) = h;
        degacc += (ra.x + ra.y + ra.z + ra.w) + (rb.x + rb.y + rb.z + rb.w);
        sqacc = fmaf(ra.x, ra.x, sqacc); sqacc = fmaf(ra.y, ra.y, sqacc);
        sqacc = fmaf(ra.z, ra.z, sqacc); sqacc = fmaf(ra.w, ra.w, sqacc);
        sqacc = fmaf(rb.x, rb.x, sqacc); sqacc = fmaf(rb.y, rb.y, sqacc);
        sqacc = fmaf(rb.z, rb.z, sqacc); sqacc = fmaf(rb.w, rb.w, sqacc);
        // swizzled LDS write: lds[srow][kq^sw] = global chunk kq
        *(u16x8*)((unsigned short*)As[buf] + srow * 32 + ((kq ^ sw) * 8)) = h;
    };
    auto stageB = [&](int t, int buf) {
        char* lb = (char*)Bs[buf] + wave * 1024;
        gl_lds16(xTp + (long long)srow * 1024 + t * 32 + skg, lb);
        gl_lds16(xTp + (long long)(128 + srow) * 1024 + t * 32 + skg, lb + 8192);
    };

    f32x4 acc[4][4] = {{{0.f}}};
    loadA(0);
    stageB(0, 0);
    procA(0, 0);
    __syncthreads();
    int cur = 0;
    for (int t = 0; t < 32; ++t) {
        const bool more = (t + 1 < 32);
        if (more) { loadA(t + 1); stageB(t + 1, cur ^ 1); }
        bf16x8 af[4], bv[4];
#pragma unroll
        for (int i = 0; i < 4; ++i)
            af[i] = *(const bf16x8*)(As[cur] + (wm + i * 16 + l15) * 32 + (quad ^ rsw) * 8);
#pragma unroll
        for (int j = 0; j < 4; ++j)
            bv[j] = *(const bf16x8*)(Bs[cur] + (wn + j * 16 + l15) * 32 + (quad ^ rsw) * 8);
#pragma unroll
        for (int i = 0; i < 4; ++i)
#pragma unroll
            for (int j = 0; j < 4; ++j)
                acc[i][j] = __builtin_amdgcn_mfma_f32_16x16x32_bf16(af[i], bv[j], acc[i][j], 0, 0, 0);
        if (more) procA(t + 1, cur ^ 1);
        __syncthreads();
        cur ^= 1;
    }

    // per-row degree: reduce over 4 k-slot lanes (same wave, xor 1,2)
    degacc += __shfl_xor(degacc, 1);
    degacc += __shfl_xor(degacc, 2);
    if (kq == 0) deginv_lds[srow] = 1.0f / fmaxf(degacc, 1.0f);
    sred[tid] = sqacc;
    __syncthreads();
    for (int k = 256; k > 0; k >>= 1) {
        if (tid < k) sred[tid] += sred[tid + k];
        __syncthreads();
    }
    if (tid == 0) p.asq_part[bz * 8 + blockIdx.x] = sred[0];

    unsigned short* og = p.agg + bz * 262144;
#pragma unroll
    for (int i = 0; i < 4; ++i)
#pragma unroll
        for (int r = 0; r < 4; ++r) {
            int lrow = wm + i * 16 + quad * 4 + r;
            float sc = deginv_lds[lrow];
            long long ro = (long long)(rowBase + lrow) * 256;
#pragma unroll
            for (int j = 0; j < 4; ++j)
                og[ro + wn + j * 16 + l15] = f2b(acc[i][j][r] * sc);
        }
}

// ---------------------------------------------------------------------------
// MFMA GEMM: C[M,N] = A1[M,K1]·B1t[N,K1]^T (+ A2·B2t^T) (+bias)
// Double-buffered LDS + XOR-swizzled staging. Epilogue options:
//   outF fp32, outH bf16, outT bf16 TRANSPOSED (swizzled LDS round-trip,
//   batch inferred as bz + (row>>10)), dotN coalesced bf16 dot -> dot_part,
//   sq_part = sum(out^2) per block.
struct GemmP {
    const unsigned short* A1; long long sA1; int lda1; int K1;
    const unsigned short* B1; long long sB1; int ldb1;
    const unsigned short* A2; long long sA2; int lda2; int K2;
    const unsigned short* B2; long long sB2; int ldb2;
    float* outF; long long sF;
    unsigned short* outH; long long sH;
    unsigned short* outT; long long sT; int ldt;
    int ldc;
    const float* bias;
    const unsigned short* dotN; long long sDot;
    float* dot_part;
    float* sq_part;
};

__global__ __launch_bounds__(256) void gemm_mfma(GemmP p) {
    __shared__ char smem[32768];     // dbuf staging; reused as 128x128 T-tile
    __shared__ float dred[256];
    const int tid = threadIdx.x;
    const int wave = tid >> 6, lane = tid & 63;
    const int quad = lane >> 4, l15 = lane & 15;
    const int wm = (wave & 1) * 64, wn = (wave >> 1) * 64;
    const long long bz = blockIdx.z;
    const int rowBase = blockIdx.y * 128, colBase = blockIdx.x * 128;
    const int srow = tid >> 2;
    const int skg = (((tid & 3) ^ ((srow >> 1) & 3)) * 8);  // swizzled source k-offset
    const int rsw = (l15 >> 1) & 3;                          // read-side swizzle

    const int n1 = p.K1 >> 5;
    const int n2 = p.A2 ? (p.K2 >> 5) : 0;
    const int nTot = n1 + n2;

    const unsigned short* A1p = p.A1 + bz * p.sA1;
    const unsigned short* B1p = p.B1 + bz * p.sB1;
    const unsigned short* A2p = p.A2 ? p.A2 + bz * p.sA2 : nullptr;
    const unsigned short* B2p = p.B2 ? p.B2 + bz * p.sB2 : nullptr;

    auto stage = [&](int t, int buf) {
        const unsigned short *Ao, *Bo; int lda, ldb, ko;
        if (t < n1) { Ao = A1p; Bo = B1p; lda = p.lda1; ldb = p.ldb1; ko = t * 32; }
        else        { Ao = A2p; Bo = B2p; lda = p.lda2; ldb = p.ldb2; ko = (t - n1) * 32; }
        char* la = smem + buf * 16384 + wave * 1024;
        char* lb = smem + buf * 16384 + 8192 + wave * 1024;
        gl_lds16(Ao + (long long)(rowBase + srow) * lda + ko + skg, la);
        gl_lds16(Ao + (long long)(rowBase + 64 + srow) * lda + ko + skg, la + 4096);
        gl_lds16(Bo + (long long)(colBase + srow) * ldb + ko + skg, lb);
        gl_lds16(Bo + (long long)(colBase + 64 + srow) * ldb + ko + skg, lb + 4096);
    };

    f32x4 acc[4][4] = {{{0.f}}};
    stage(0, 0);
    __syncthreads();
    int cur = 0;
    for (int t = 0; t < nTot; ++t) {
        if (t + 1 < nTot) stage(t + 1, cur ^ 1);
        const short* Ab = (const short*)(smem + cur * 16384);
        const short* Bb = (const short*)(smem + cur * 16384 + 8192);
        bf16x8 af[4], bf[4];
#pragma unroll
        for (int i = 0; i < 4; ++i)
            af[i] = *(const bf16x8*)(Ab + (wm + i * 16 + l15) * 32 + (quad ^ rsw) * 8);
#pragma unroll
        for (int j = 0; j < 4; ++j)
            bf[j] = *(const bf16x8*)(Bb + (wn + j * 16 + l15) * 32 + (quad ^ rsw) * 8);
#pragma unroll
        for (int i = 0; i < 4; ++i)
#pragma unroll
            for (int j = 0; j < 4; ++j)
                acc[i][j] = __builtin_amdgcn_mfma_f32_16x16x32_bf16(af[i], bf[j], acc[i][j], 0, 0, 0);
        __syncthreads();
        cur ^= 1;
    }

    float* oF = p.outF ? p.outF + bz * p.sF : nullptr;
    unsigned short* oH = p.outH ? p.outH + bz * p.sH : nullptr;
    const unsigned short* dN = p.dotN ? p.dotN + bz * p.sDot : nullptr;
    unsigned short* tt = (unsigned short*)smem;   // swizzled 128x128 T-tile
    float bcol[4];
#pragma unroll
    for (int j = 0; j < 4; ++j)
        bcol[j] = p.bias ? p.bias[colBase + wn + j * 16 + l15] : 0.0f;
    float dacc = 0.f;
#pragma unroll
    for (int i = 0; i < 4; ++i) {
        ushort4 tp[4];
#pragma unroll
        for (int r = 0; r < 4; ++r) {
            int row = rowBase + wm + i * 16 + quad * 4 + r;
            long long ro = (long long)row * p.ldc;
#pragma unroll
            for (int j = 0; j < 4; ++j) {
                int col = colBase + wn + j * 16 + l15;
                float v = acc[i][j][r] + bcol[j];
                if (oF) oF[ro + col] = v;
                if (oH) oH[ro + col] = f2b(v);
                if (dN) dacc = fmaf(v, b2f(dN[ro + col]), dacc);
                if (p.sq_part) dacc = fmaf(v, v, dacc);
                ((unsigned short*)&tp[j])[r] = f2b(v);
            }
        }
        if (p.outT) {
            int lr = wm + i * 16 + quad * 4;
#pragma unroll
            for (int j = 0; j < 4; ++j) {
                int lc = wn + j * 16 + l15;
                *(ushort4*)&tt[lc * 128 + (lr ^ ((lc & 15) << 3))] = tp[j];
            }
        }
    }
    if (p.outT) {
        __syncthreads();
#pragma unroll
        for (int u = 0; u < 8; ++u) {
            int idx = u * 256 + tid;
            int c = idx >> 4;                // 0..127
            int r0 = (idx & 15) * 8;         // 0..120
            u16x8 val = *(const u16x8*)&tt[c * 128 + (r0 ^ ((c & 15) << 3))];
            int gr = rowBase + r0;
            long long tb = bz + (gr >> 10);
            *(u16x8*)(p.outT + tb * p.sT + (long long)(colBase + c) * p.ldt + (gr & 1023)) = val;
        }
    }
    if (p.dot_part || p.sq_part) {
        dred[tid] = dacc;
        __syncthreads();
        for (int k = 128; k > 0; k >>= 1) {
            if (tid < k) dred[tid] += dred[tid + k];
            __syncthreads();
        }
        if (tid == 0) {
            float* dst = p.dot_part ? p.dot_part : p.sq_part;
            dst[((long long)bz * gridDim.y + blockIdx.y) * gridDim.x + blockIdx.x] = dred[0];
        }
    }
}

// ---------------------------------------------------------------------------
// Fused SAGE pre-norm GEMM: out[32768,256] = l2norm_relu(A1·B1t^T + A2·B2t^T
// + bias), bf16 out. Full row width in one block (128x256 tile, 8 waves).
struct SageP {
    const unsigned short* A1; const unsigned short* B1;
    const unsigned short* A2; const unsigned short* B2;
    const float* bias;
    unsigned short* out;
};

__global__ __launch_bounds__(512) void sage_mfma(SageP p) {
    __shared__ short As[2][4096];      // 128x32
    __shared__ short Bs[2][8192];      // 256x32
    __shared__ float rsum[4][128];
    const int tid = threadIdx.x;
    const int wave = tid >> 6, lane = tid & 63;
    const int quad = lane >> 4, l15 = lane & 15;
    const int wm = (wave & 1) * 64, wn = (wave >> 1) * 64;  // 2m x 4n waves
    const int rowBase = blockIdx.x * 128;
    const int srow = tid >> 2;                 // 0..127
    const int skg = (((tid & 3) ^ ((srow >> 1) & 3)) * 8);
    const int rsw = (l15 >> 1) & 3;

    auto stage = [&](int t, int buf) {
        const unsigned short* Ao = (t < 8) ? p.A1 : p.A2;
        const unsigned short* Bo = (t < 8) ? p.B1 : p.B2;
        int ko = (t & 7) * 32;
        char* la = (char*)As[buf] + wave * 1024;
        char* lb = (char*)Bs[buf] + wave * 1024;
        gl_lds16(Ao + (long long)(rowBase + srow) * 256 + ko + skg, la);
        gl_lds16(Bo + (long long)srow * 256 + ko + skg, lb);
        gl_lds16(Bo + (long long)(128 + srow) * 256 + ko + skg, lb + 8192);
    };

    f32x4 acc[4][4] = {{{0.f}}};
    stage(0, 0);
    __syncthreads();
    int cur = 0;
    for (int t = 0; t < 16; ++t) {
        if (t + 1 < 16) stage(t + 1, cur ^ 1);
        const short* Ab = As[cur];
        const short* Bb = Bs[cur];
        bf16x8 af[4], bf[4];
#pragma unroll
        for (int i = 0; i < 4; ++i)
            af[i] = *(const bf16x8*)(Ab + (wm + i * 16 + l15) * 32 + (quad ^ rsw) * 8);
#pragma unroll
        for (int j = 0; j < 4; ++j)
            bf[j] = *(const bf16x8*)(Bb + (wn + j * 16 + l15) * 32 + (quad ^ rsw) * 8);
#pragma unroll
        for (int i = 0; i < 4; ++i)
#pragma unroll
            for (int j = 0; j < 4; ++j)
                acc[i][j] = __builtin_amdgcn_mfma_f32_16x16x32_bf16(af[i], bf[j], acc[i][j], 0, 0, 0);
        __syncthreads();
        cur ^= 1;
    }

    float bcol[4];
#pragma unroll
    for (int j = 0; j < 4; ++j)
        bcol[j] = p.bias[wn + j * 16 + l15];

#pragma unroll
    for (int i = 0; i < 4; ++i)
#pragma unroll
        for (int r = 0; r < 4; ++r) {
            float ss = 0.f;
#pragma unroll
            for (int j = 0; j < 4; ++j) {
                float v = acc[i][j][r] + bcol[j];
                ss = fmaf(v, v, ss);
            }
#pragma unroll
            for (int off = 1; off < 16; off <<= 1) ss += __shfl_xor(ss, off);
            if (l15 == 0) rsum[wave >> 1][wm + i * 16 + quad * 4 + r] = ss;
        }
    __syncthreads();
#pragma unroll
    for (int i = 0; i < 4; ++i)
#pragma unroll
        for (int r = 0; r < 4; ++r) {
            int lrow = wm + i * 16 + quad * 4 + r;
            float tot = rsum[0][lrow] + rsum[1][lrow] + rsum[2][lrow] + rsum[3][lrow];
            float rn = 1.0f / fmaxf(sqrtf(tot), 1e-12f);
            long long ro = (long long)(rowBase + lrow) * 256;
#pragma unroll
            for (int j = 0; j < 4; ++j) {
                float v = (acc[i][j][r] + bcol[j]) * rn;
                p.out[ro + wn + j * 16 + l15] = f2b(fmaxf(v, 0.0f));
            }
        }
}

// ---------------------------------------------------------------------------
// Merged: xp = sT·nxT^T (fp32) AND G = sT·sT^T (bf16 + ssq/tr partials).
// One A-tile staging feeds two B-streams.
__global__ __launch_bounds__(256) void xpg_mfma(
    const unsigned short* __restrict__ sT, const unsigned short* __restrict__ nxT,
    float* __restrict__ xp, unsigned short* __restrict__ gout,
    float* __restrict__ ssq_part, float* __restrict__ tr_part) {
    __shared__ char smem[49152];   // A:0, B1:16384, B2:32768 (each 2x8KB dbuf)
    __shared__ float red[2][256];
    const int tid = threadIdx.x;
    const int wave = tid >> 6, lane = tid & 63;
    const int quad = lane >> 4, l15 = lane & 15;
    const int wm = (wave & 1) * 64, wn = (wave >> 1) * 64;
    const long long bz = blockIdx.z;
    const unsigned short* S = sT + bz * 262144;
    const unsigned short* NX = nxT + bz * 262144;
    const int rowBase = blockIdx.y * 128, colBase = blockIdx.x * 128;
    const int srow = tid >> 2;
    const int skg = (((tid & 3) ^ ((srow >> 1) & 3)) * 8);
    const int rsw = (l15 >> 1) & 3;

    auto stage = [&](int t, int buf) {
        int ko = t * 32;
        char* la = smem + buf * 8192 + wave * 1024;
        char* l1 = smem + 16384 + buf * 8192 + wave * 1024;
        char* l2 = smem + 32768 + buf * 8192 + wave * 1024;
        gl_lds16(S + (long long)(rowBase + srow) * 1024 + ko + skg, la);
        gl_lds16(S + (long long)(rowBase + 64 + srow) * 1024 + ko + skg, la + 4096);
        gl_lds16(NX + (long long)(colBase + srow) * 1024 + ko + skg, l1);
        gl_lds16(NX + (long long)(colBase + 64 + srow) * 1024 + ko + skg, l1 + 4096);
        gl_lds16(S + (long long)(colBase + srow) * 1024 + ko + skg, l2);
        gl_lds16(S + (long long)(colBase + 64 + srow) * 1024 + ko + skg, l2 + 4096);
    };

    f32x4 a1[4][4] = {{{0.f}}};
    f32x4 a2[4][4] = {{{0.f}}};
    stage(0, 0);
    __syncthreads();
    int cur = 0;
    for (int t = 0; t < 32; ++t) {
        if (t + 1 < 32) stage(t + 1, cur ^ 1);
        const short* Ab  = (const short*)(smem + cur * 8192);
        const short* B1b = (const short*)(smem + 16384 + cur * 8192);
        const short* B2b = (const short*)(smem + 32768 + cur * 8192);
        bf16x8 af[4], b1[4], b2[4];
#pragma unroll
        for (int i = 0; i < 4; ++i)
            af[i] = *(const bf16x8*)(Ab + (wm + i * 16 + l15) * 32 + (quad ^ rsw) * 8);
#pragma unroll
        for (int j = 0; j < 4; ++j) {
            int co = (wn + j * 16 + l15) * 32 + (quad ^ rsw) * 8;
            b1[j] = *(const bf16x8*)(B1b + co);
            b2[j] = *(const bf16x8*)(B2b + co);
        }
#pragma unroll
        for (int i = 0; i < 4; ++i)
#pragma unroll
            for (int j = 0; j < 4; ++j) {
                a1[i][j] = __builtin_amdgcn_mfma_f32_16x16x32_bf16(af[i], b1[j], a1[i][j], 0, 0, 0);
                a2[i][j] = __builtin_amdgcn_mfma_f32_16x16x32_bf16(af[i], b2[j], a2[i][j], 0, 0, 0);
            }
        __syncthreads();
        cur ^= 1;
    }

    float* xo = xp + bz * 65536;
    unsigned short* go = gout + bz * 65536;
    float ssq = 0.f, tr = 0.f;
#pragma unroll
    for (int i = 0; i < 4; ++i)
#pragma unroll
        for (int r = 0; r < 4; ++r) {
            int row = rowBase + wm + i * 16 + quad * 4 + r;
            long long ro = (long long)row * 256;
#pragma unroll
            for (int j = 0; j < 4; ++j) {
                int col = colBase + wn + j * 16 + l15;
                xo[ro + col] = a1[i][j][r];
                float v = a2[i][j][r];
                go[ro + col] = f2b(v);
                ssq = fmaf(v, v, ssq);
                if (row == col) tr += v;
            }
        }
    red[0][tid] = ssq;
    red[1][tid] = tr;
    __syncthreads();
    for (int k = 128; k > 0; k >>= 1) {
        if (tid < k) {
            red[0][tid] += red[0][tid + k];
            red[1][tid] += red[1][tid + k];
        }
        __syncthreads();
    }
    if (tid == 0) {
        int bid = (int)(blockIdx.z * 4 + blockIdx.y * 2 + blockIdx.x);
        ssq_part[bid] = red[0][0];
        tr_part[bid] = red[1][0];
    }
}

// ---------------------------------------------------------------------------
// trq = sum( (P·G) ∘ (G·P) ) = tr(G P^T G P)  [G symmetric].
__global__ __launch_bounds__(256) void trq_mfma(
    const unsigned short* __restrict__ G, const unsigned short* __restrict__ P,
    const unsigned short* __restrict__ PT, float* __restrict__ trq_part) {
    __shared__ short sm[4][2][4096];   // [GA,PB,PA,GB][buf][128x32]
    __shared__ float dred[256];
    const int tid = threadIdx.x;
    const int wave = tid >> 6, lane = tid & 63;
    const int quad = lane >> 4, l15 = lane & 15;
    const int wm = (wave & 1) * 64, wn = (wave >> 1) * 64;
    const long long bz = blockIdx.z;
    const int rowBase = blockIdx.y * 128, colBase = blockIdx.x * 128;
    const int srow = tid >> 2;
    const int skg = (((tid & 3) ^ ((srow >> 1) & 3)) * 8);
    const int rsw = (l15 >> 1) & 3;
    const unsigned short* Gb = G + bz * 65536;
    const unsigned short* Pb = P + bz * 65536;
    const unsigned short* PTb = PT + bz * 65536;

    auto stage = [&](int t, int buf) {
        int ko = t * 32;
#pragma unroll
        for (int h = 0; h < 2; ++h) {
            int rr = rowBase + h * 64 + srow, cc = colBase + h * 64 + srow;
            gl_lds16(Gb + (long long)rr * 256 + ko + skg, (char*)sm[0][buf] + h * 4096 + wave * 1024);
            gl_lds16(PTb + (long long)cc * 256 + ko + skg, (char*)sm[1][buf] + h * 4096 + wave * 1024);
            gl_lds16(Pb + (long long)rr * 256 + ko + skg, (char*)sm[2][buf] + h * 4096 + wave * 1024);
            gl_lds16(Gb + (long long)cc * 256 + ko + skg, (char*)sm[3][buf] + h * 4096 + wave * 1024);
        }
    };

    f32x4 a1[4][4] = {{{0.f}}};
    f32x4 a3[4][4] = {{{0.f}}};
    stage(0, 0);
    __syncthreads();
    int cur = 0;
    for (int t = 0; t < 8; ++t) {
        if (t + 1 < 8) stage(t + 1, cur ^ 1);
        bf16x8 gA[4], pB[4], pA[4], gB[4];
#pragma unroll
        for (int i = 0; i < 4; ++i) {
            int ro = (wm + i * 16 + l15) * 32 + (quad ^ rsw) * 8;
            gA[i] = *(const bf16x8*)(sm[0][cur] + ro);
            pA[i] = *(const bf16x8*)(sm[2][cur] + ro);
        }
#pragma unroll
        for (int j = 0; j < 4; ++j) {
            int co = (wn + j * 16 + l15) * 32 + (quad ^ rsw) * 8;
            pB[j] = *(const bf16x8*)(sm[1][cur] + co);
            gB[j] = *(const bf16x8*)(sm[3][cur] + co);
        }
#pragma unroll
        for (int i = 0; i < 4; ++i)
#pragma unroll
            for (int j = 0; j < 4; ++j) {
                a1[i][j] = __builtin_amdgcn_mfma_f32_16x16x32_bf16(gA[i], pB[j], a1[i][j], 0, 0, 0);
                a3[i][j] = __builtin_amdgcn_mfma_f32_16x16x32_bf16(pA[i], gB[j], a3[i][j], 0, 0, 0);
            }
        __syncthreads();
        cur ^= 1;
    }
    float dacc = 0.f;
#pragma unroll
    for (int i = 0; i < 4; ++i)
#pragma unroll
        for (int j = 0; j < 4; ++j)
#pragma unroll
            for (int r = 0; r < 4; ++r)
                dacc = fmaf(a3[i][j][r], a1[i][j][r], dacc);
    dred[tid] = dacc;
    __syncthreads();
    for (int k = 128; k > 0; k >>= 1) {
        if (tid < k) dred[tid] += dred[tid + k];
        __syncthreads();
    }
    if (tid == 0)
        trq_part[(blockIdx.z * 2 + blockIdx.y) * 2 + blockIdx.x] = dred[0];
}

// ---------------------------------------------------------------------------
// Pass 1 over bf16 logits: per-row softmax stats (max, 1/den) + column scores.
__global__ __launch_bounds__(256) void smstat_kernel(
    const unsigned short* __restrict__ s, float* __restrict__ rowmax,
    float* __restrict__ rowrden, float* __restrict__ scores) {
    __shared__ float sacc[4][256];
    const int tid = threadIdx.x;
    const int wave = tid >> 6, lane = tid & 63;
    const int b = blockIdx.x >> 5;
    const long long row0 = (long long)blockIdx.x * 32;
    float c0 = 0.f, c1 = 0.f, c2 = 0.f, c3 = 0.f;
#pragma unroll
    for (int q = 0; q < 8; ++q) {
        long long row = row0 + wave * 8 + q;
        const ushort4 v4 = *(const ushort4*)(s + row * 256 + lane * 4);
        float vx = b2f(v4.x), vy = b2f(v4.y), vz = b2f(v4.z), vw = b2f(v4.w);
        float m = fmaxf(fmaxf(vx, vy), fmaxf(vz, vw));
#pragma unroll
        for (int off = 32; off > 0; off >>= 1) m = fmaxf(m, __shfl_xor(m, off));
        float e0 = expf(vx - m), e1 = expf(vy - m);
        float e2 = expf(vz - m), e3 = expf(vw - m);
        float den = e0 + e1 + e2 + e3;
#pragma unroll
        for (int off = 32; off > 0; off >>= 1) den += __shfl_xor(den, off);
        float rd = 1.0f / den;
        if (lane == 0) { rowmax[row] = m; rowrden[row] = rd; }
        c0 = fmaf(e0, rd, c0); c1 = fmaf(e1, rd, c1);
        c2 = fmaf(e2, rd, c2); c3 = fmaf(e3, rd, c3);
    }
    sacc[wave][lane * 4 + 0] = c0;
    sacc[wave][lane * 4 + 1] = c1;
    sacc[wave][lane * 4 + 2] = c2;
    sacc[wave][lane * 4 + 3] = c3;
    __syncthreads();
    float t0 = sacc[0][tid] + sacc[1][tid] + sacc[2][tid] + sacc[3][tid];
    atomicAdd(&scores[b * 256 + tid], t0);
}

// fused top-k threshold + sigmoid gate
__global__ __launch_bounds__(256) void topkgate_kernel(const float* __restrict__ scores,
                                                       float* __restrict__ gate) {
    __shared__ float vals[256];
    __shared__ float th;
    int b = blockIdx.x, tid = threadIdx.x;
    float v = scores[b * 256 + tid];
    vals[tid] = v;
    __syncthreads();
    int rank = 0;
    for (int j = 0; j < 256; ++j) {
        float u = vals[j];
        rank += (u > v) || (u == v && j < tid);
    }
    if (rank == 127) th = v;
    __syncthreads();
    float z = (v - th) * 10.0f;  // 1/TEMP
    gate[b * 256 + tid] = 1.0f / (1.0f + expf(-z));
}

// ---------------------------------------------------------------------------
// Pass 2: gated softmax from bf16 logits + stats. Writes s fp32 (final out),
// s_bf (in-place over logits; slog/sbf intentionally NOT restrict — alias),
// sT bf16 transposed, entropy partials.
__global__ __launch_bounds__(256) void gatefin_kernel(
    const unsigned short* slog, float* __restrict__ s,
    const float* __restrict__ rowmax, const float* __restrict__ rowrden,
    const float* __restrict__ gate, unsigned short* sbf,
    unsigned short* __restrict__ sT, float* __restrict__ ent_part) {
    __shared__ float tile[64][65];
    __shared__ float red[256];
    const int tid = threadIdx.x;
    const long long bz = blockIdx.z;
    const int rowBase = blockIdx.y * 64, colBase = blockIdx.x * 64;
    const int c4 = (tid & 15) * 4;
    const float g0 = gate[bz * 256 + colBase + c4 + 0];
    const float g1 = gate[bz * 256 + colBase + c4 + 1];
    const float g2 = gate[bz * 256 + colBase + c4 + 2];
    const float g3 = gate[bz * 256 + colBase + c4 + 3];
    float ent = 0.f;
#pragma unroll
    for (int i = 0; i < 4; ++i) {
        int r = (tid >> 4) * 4 + i;
        long long grow = bz * 1024 + rowBase + r;
        ushort4 lv = *(const ushort4*)(slog + grow * 256 + colBase + c4);
        float m = rowmax[grow], rd = rowrden[grow];
        float p0 = expf(b2f(lv.x) - m) * rd * g0;
        float p1 = expf(b2f(lv.y) - m) * rd * g1;
        float p2 = expf(b2f(lv.z) - m) * rd * g2;
        float p3 = expf(b2f(lv.w) - m) * rd * g3;
        float4 pv; pv.x = p0; pv.y = p1; pv.z = p2; pv.w = p3;
        *(float4*)(s + grow * 256 + colBase + c4) = pv;
        ushort4 h;
        h.x = f2b(p0); h.y = f2b(p1); h.z = f2b(p2); h.w = f2b(p3);
        *(ushort4*)(sbf + grow * 256 + colBase + c4) = h;
        tile[r][c4 + 0] = p0; tile[r][c4 + 1] = p1;
        tile[r][c4 + 2] = p2; tile[r][c4 + 3] = p3;
        ent -= p0 * logf(p0 + 1e-15f) + p1 * logf(p1 + 1e-15f) +
               p2 * logf(p2 + 1e-15f) + p3 * logf(p3 + 1e-15f);
    }
    __syncthreads();
#pragma unroll
    for (int i = 0; i < 4; ++i) {
        int oc = (tid >> 4) * 4 + i;
        ushort4 h;
        h.x = f2b(tile[c4 + 0][oc]);
        h.y = f2b(tile[c4 + 1][oc]);
        h.z = f2b(tile[c4 + 2][oc]);
        h.w = f2b(tile[c4 + 3][oc]);
        *(ushort4*)(sT + bz * 262144 + (long long)(colBase + oc) * 1024 + rowBase + c4) = h;
    }
    red[tid] = ent;
    __syncthreads();
    for (int k = 128; k > 0; k >>= 1) {
        if (tid < k) red[tid] += red[tid + k];
        __syncthreads();
    }
    if (tid == 0)
        ent_part[((long long)bz * gridDim.y + blockIdx.y) * gridDim.x + blockIdx.x] = red[0];
}

// ---------------------------------------------------------------------------
__global__ __launch_bounds__(256) void finalize_kernel(const float* __restrict__ ent_part,
                                                       const float* __restrict__ asq_part,
                                                       const float* __restrict__ psq_part,
                                                       const float* __restrict__ sdot_part,
                                                       const float* __restrict__ trq_part,
                                                       const float* __restrict__ ssq_part,
                                                       const float* __restrict__ tr_part,
                                                       float* __restrict__ scal) {
    __shared__ float red[7][256];
    int tid = threadIdx.x;
    float e = 0.f, asq = 0.f, psq = 0.f, sd = 0.f, tq = 0.f, clu = 0.f, ssqa = 0.f;
    for (int i = tid; i < 2048; i += 256) e += ent_part[i];
    asq = asq_part[tid];                    // 256 entries
    if (tid < 128) psq = psq_part[tid];
    for (int i = tid; i < 512; i += 256) sd += sdot_part[i];
    if (tid < 128) tq = trq_part[tid];
    if (tid < 32) {
        float ssq = 0.f, tr = 0.f;
#pragma unroll
        for (int i = 0; i < 4; ++i) {
            ssq += ssq_part[tid * 4 + i];
            tr  += tr_part[tid * 4 + i];
        }
        ssqa = ssq;
        float fro = fmaxf(sqrtf(ssq), 1e-12f);
        float val = ssq / (fro * fro) - tr / (8.0f * fro) + 1.0f;  // ||G/fro - I/16||_F^2
        clu = sqrtf(fmaxf(val, 0.0f));
    }
    red[0][tid] = e; red[1][tid] = asq; red[2][tid] = psq; red[3][tid] = sd;
    red[4][tid] = tq; red[5][tid] = clu; red[6][tid] = ssqa;
    __syncthreads();
    for (int k = 128; k > 0; k >>= 1) {
        if (tid < k) {
#pragma unroll
            for (int q = 0; q < 7; ++q) red[q][tid] += red[q][tid + k];
        }
        __syncthreads();
    }
    if (tid == 0) {
        const float numel = 33554432.0f;  // B*N*N
        float linksq  = red[1][0] - 2.0f * red[3][0] + red[6][0];   // asq - 2<S,AS> + ||G||^2
        float reconsq = red[1][0] - 2.0f * red[2][0] + red[4][0];   // asq - 2||P||^2 + tr(GP'GP)
        scal[0] = sqrtf(fmaxf(linksq, 0.0f)) / numel;   // link
        scal[1] = red[0][0] / 32768.0f;                 // ent
        scal[2] = red[5][0] / 32.0f;                    // clu
        scal[3] = sqrtf(fmaxf(reconsq, 0.0f)) / numel;  // recon
    }
}

// ---------------------------------------------------------------------------
extern "C" void kernel_launch(void* const* d_in, const int* in_sizes, int n_in,
                              void* d_out, int out_size, void* d_ws, size_t ws_size,
                              hipStream_t stream) {
    const float* x    = (const float*)d_in[0];
    const float* adj  = (const float*)d_in[1];
    const float* Wr_p = (const float*)d_in[2];
    const float* br_p = (const float*)d_in[3];
    const float* Wo_p = (const float*)d_in[4];
    const float* Wl_p = (const float*)d_in[5];
    const float* bl_p = (const float*)d_in[6];
    const float* Wr_e = (const float*)d_in[7];
    const float* br_e = (const float*)d_in[8];
    const float* Wo_e = (const float*)d_in[9];
    const float* Wl_e = (const float*)d_in[10];
    const float* bl_e = (const float*)d_in[11];

    float* out    = (float*)d_out;
    float* xp     = out;              // [32,256,256]
    float* adj_p  = out + 2097152;    // [32,256,256]
    float* s      = out + 4194304;    // [32,1024,256] fp32
    float* scal   = out + 12582912;
    float* node_x = out + 12582916;   // [32,1024,256] fp32

    char* w = (char*)d_ws;
    float* rowmax     = (float*)w; w += 32768 * 4;
    float* scores     = (float*)w; w += 8192 * 4;
    float* thresh     = (float*)w; w += 256 * 4;     // unused, layout keep
    float* gatep      = (float*)w; w += 8192 * 4;
    float* ent_part   = (float*)w; w += 32768 * 4;   // 2048 used
    float* asq_part   = (float*)w; w += 8192 * 4;    // 256 used
    float* psq_part   = (float*)w; w += 512 * 4;     // 128 used
    float* sdot_part  = (float*)w; w += 1024 * 4;    // 512 used
    float* trq_part   = (float*)w; w += 256 * 4;     // 128 used
    float* ssq_part   = (float*)w; w += 256 * 4;     // 128 used
    float* tr_part    = (float*)w; w += 256 * 4;     // 128 used
    unsigned short* WT   = (unsigned short*)w; w += 6LL * 65536 * 2;
    unsigned short* bufA = (unsigned short*)w; w += 33554432LL * 2;  // adj_bf
    unsigned short* bufB = (unsigned short*)w; w += 8388608LL * 2;   // x_bf -> {G_bf, PT_bf}
    unsigned short* bufC = (unsigned short*)w; w += 8388608LL * 2;   // xT_bf -> sT_bf
    unsigned short* bufD = (unsigned short*)w; w += 8388608LL * 2;   // agg_bf -> nxT_bf
    unsigned short* bufE = (unsigned short*)w; w += 8388608LL * 2;   // h_bf
    unsigned short* bufF = (unsigned short*)w; w += 8388608LL * 2;   // aTsT_bf
    unsigned short* bufG = (unsigned short*)w; w += 8388608LL * 2;   // logits_bf -> s_bf
    unsigned short* bufH = (unsigned short*)w; w += 2097152LL * 2;   // rowrden, then P_bf

    unsigned short* G_bf  = bufB;                        // [32,256,256] bf16
    unsigned short* PT_bf = bufB + 2097152;              // [32,256,256] bf16
    float* rowrden = (float*)bufH;   // bufH not P_bf until step 11
    (void)thresh;

    hipMemsetAsync(scores, 0, 8192 * sizeof(float), stream);

    // 1) x -> x_bf + xT_bf
    convt_kernel<<<dim3(4, 16, 32), 256, 0, stream>>>(
        x, 262144LL, 256, bufB, 262144LL, bufC, 262144LL, 1024);

    // 2) weights -> transposed bf16
    WPtrs wp;
    wp.in[0] = Wr_p; wp.in[1] = Wo_p; wp.in[2] = Wl_p;
    wp.in[3] = Wr_e; wp.in[4] = Wo_e; wp.in[5] = Wl_e;
    for (int i = 0; i < 6; ++i) wp.out[i] = WT + (long long)i * 65536;
    wconv_kernel<<<dim3(4, 4, 6), 256, 0, stream>>>(wp);

    // 3) fused adj pass: adj_bf + deg (in LDS) + asq + agg = (adj@x)/deg
    AggP ap;
    ap.adj = adj; ap.xT = bufC; ap.adj_bf = bufA; ap.agg = bufD; ap.asq_part = asq_part;
    aggdeg_mfma<<<dim3(8, 32), 512, 0, stream>>>(ap);

    // 4) pool pre-norm fused: h_p = l2relu(agg@Wr_p + x@Wo_p + br_p) -> bufE
    SageP sp;
    sp.A1 = bufD; sp.B1 = WT + 0 * 65536;
    sp.A2 = bufB; sp.B2 = WT + 1 * 65536;
    sp.bias = br_p; sp.out = bufE;
    sage_mfma<<<256, 512, 0, stream>>>(sp);

    GemmP g;
    // 5) s_logits = h @ Wl_p + bl_p -> bf16 logits (bufG)
    g = {};
    g.A1 = bufE; g.sA1 = 0; g.lda1 = 256; g.K1 = 256; g.B1 = WT + 2 * 65536; g.sB1 = 0; g.ldb1 = 256;
    g.outH = bufG; g.sH = 0; g.ldc = 256; g.bias = bl_p;
    gemm_mfma<<<dim3(2, 256, 1), 256, 0, stream>>>(g);

    // 6) embed pre-norm fused -> bufE
    sp.A1 = bufD; sp.B1 = WT + 3 * 65536;
    sp.A2 = bufB; sp.B2 = WT + 4 * 65536;
    sp.bias = br_e; sp.out = bufE;
    sage_mfma<<<256, 512, 0, stream>>>(sp);

    // 7) node_x = h_e @ Wl_e + bl_e (fp32) + transposed bf16 -> bufD (nxT)
    g = {};
    g.A1 = bufE; g.sA1 = 0; g.lda1 = 256; g.K1 = 256; g.B1 = WT + 5 * 65536; g.sB1 = 0; g.ldb1 = 256;
    g.outF = node_x; g.sF = 0; g.ldc = 256; g.bias = bl_e;
    g.outT = bufD; g.sT = 262144; g.ldt = 1024;
    gemm_mfma<<<dim3(2, 256, 1), 256, 0, stream>>>(g);

    // 8) softmax stats + scores; topk+gate; gated finalize (s, s_bf, sT, ent)
    smstat_kernel<<<1024, 256, 0, stream>>>(bufG, rowmax, rowrden, scores);
    topkgate_kernel<<<32, 256, 0, stream>>>(scores, gatep);
    gatefin_kernel<<<dim3(4, 16, 32), 256, 0, stream>>>(
        bufG, s, rowmax, rowrden, gatep, bufG, bufC, ent_part);

    // 9) xp = sT·nxT^T (fp32) + G = sT·sT^T (bf16 + ssq/tr) — merged
    xpg_mfma<<<dim3(2, 2, 32), 256, 0, stream>>>(bufC, bufD, xp, G_bf, ssq_part, tr_part);

    // 10) aTs = adj · s: transposed bf16 -> bufF, link dot <S, A·S> -> sdot
    g = {};
    g.A1 = bufA; g.sA1 = 1048576; g.lda1 = 1024; g.K1 = 1024;
    g.B1 = bufC; g.sB1 = 262144; g.ldb1 = 1024;
    g.ldc = 256;
    g.outT = bufF; g.sT = 262144; g.ldt = 1024;
    g.dotN = bufG; g.sDot = 262144; g.dot_part = sdot_part;
    gemm_mfma<<<dim3(2, 8, 32), 256, 0, stream>>>(g);

    // 11) adj_p = sT · aTsT^T: fp32 out + P_bf + PT_bf + ||P||^2 partials
    g = {};
    g.A1 = bufC; g.sA1 = 262144; g.lda1 = 1024; g.K1 = 1024;
    g.B1 = bufF; g.sB1 = 262144; g.ldb1 = 1024;
    g.outF = adj_p; g.sF = 65536; g.ldc = 256;
    g.outH = bufH; g.sH = 65536;
    g.outT = PT_bf; g.sT = 65536; g.ldt = 256;
    g.sq_part = psq_part;
    gemm_mfma<<<dim3(2, 2, 32), 256, 0, stream>>>(g);

    // 12) trq = <P·G, G·P> (recon trace term), register-local dot
    trq_mfma<<<dim3(2, 2, 32), 256, 0, stream>>>(G_bf, bufH, PT_bf, trq_part);

    // 13) finalize
    finalize_kernel<<<1, 256, 0, stream>>>(ent_part, asq_part, psq_part, sdot_part,
                                           trq_part, ssq_part, tr_part, scal);
}

// Round 6
// 547.083 us; speedup vs baseline: 1.3953x; 1.0128x over previous
//
#include <hip/hip_runtime.h>
#include <hip/hip_bf16.h>
#include <math.h>

// B=32, N=1024, D=H=E=C=256, K_top=128, TEMP=0.1, EPS=1e-15

typedef short bf16x8 __attribute__((ext_vector_type(8)));   // 8 bf16 raw bits (4 VGPRs)
typedef float f32x4 __attribute__((ext_vector_type(4)));
typedef unsigned short u16x8 __attribute__((ext_vector_type(8)));

__device__ inline void gl_lds16(const void* g, void* l) {
    __builtin_amdgcn_global_load_lds(
        (const __attribute__((address_space(1))) void*)g,
        (__attribute__((address_space(3))) void*)l, 16, 0, 0);
}

__device__ inline unsigned short f2b(float f) {
    union { __hip_bfloat16 h; unsigned short u; } cv;
    cv.h = __float2bfloat16(f);
    return cv.u;
}
__device__ inline float b2f(unsigned short u) {
    union { unsigned short u; __hip_bfloat16 h; } cv;
    cv.u = u;
    return __bfloat162float(cv.h);
}

// ---------------------------------------------------------------------------
// Tiled convert/transpose: fp32 [R,C] -> optional bf16 same layout (outN),
// optional bf16 transpose (outT).
__global__ __launch_bounds__(256) void convt_kernel(
    const float* __restrict__ in, long long sIn, int ldin,
    unsigned short* __restrict__ outN, long long sN,
    unsigned short* __restrict__ outT, long long sT, int ldT) {
    __shared__ float tile[64][65];
    const int tid = threadIdx.x;
    const long long bz = blockIdx.z;
    const int rowBase = blockIdx.y * 64, colBase = blockIdx.x * 64;
    const float* ip = in + bz * sIn;
#pragma unroll
    for (int i = 0; i < 4; ++i) {
        int r = (tid >> 4) * 4 + i;
        const float4 v = *(const float4*)(ip + (long long)(rowBase + r) * ldin + colBase + (tid & 15) * 4);
        tile[r][(tid & 15) * 4 + 0] = v.x;
        tile[r][(tid & 15) * 4 + 1] = v.y;
        tile[r][(tid & 15) * 4 + 2] = v.z;
        tile[r][(tid & 15) * 4 + 3] = v.w;
        if (outN) {
            ushort4 h;
            h.x = f2b(v.x); h.y = f2b(v.y); h.z = f2b(v.z); h.w = f2b(v.w);
            *(ushort4*)(outN + bz * sN + (long long)(rowBase + r) * ldin + colBase + (tid & 15) * 4) = h;
        }
    }
    __syncthreads();
    if (outT) {
#pragma unroll
        for (int i = 0; i < 4; ++i) {
            int oc = (tid >> 4) * 4 + i;
            ushort4 h;
            h.x = f2b(tile[(tid & 15) * 4 + 0][oc]);
            h.y = f2b(tile[(tid & 15) * 4 + 1][oc]);
            h.z = f2b(tile[(tid & 15) * 4 + 2][oc]);
            h.w = f2b(tile[(tid & 15) * 4 + 3][oc]);
            *(ushort4*)(outT + bz * sT + (long long)(colBase + oc) * ldT + rowBase + (tid & 15) * 4) = h;
        }
    }
}

// 6 weight matrices [256,256] -> transposed bf16
struct WPtrs { const float* in[6]; unsigned short* out[6]; };
__global__ __launch_bounds__(256) void wconv_kernel(WPtrs wp) {
    __shared__ float tile[64][65];
    const int tid = threadIdx.x;
    const float* in = wp.in[blockIdx.z];
    unsigned short* out = wp.out[blockIdx.z];
    const int rowBase = blockIdx.y * 64, colBase = blockIdx.x * 64;
#pragma unroll
    for (int i = 0; i < 4; ++i) {
        int r = (tid >> 4) * 4 + i;
        const float4 v = *(const float4*)(in + (long long)(rowBase + r) * 256 + colBase + (tid & 15) * 4);
        tile[r][(tid & 15) * 4 + 0] = v.x;
        tile[r][(tid & 15) * 4 + 1] = v.y;
        tile[r][(tid & 15) * 4 + 2] = v.z;
        tile[r][(tid & 15) * 4 + 3] = v.w;
    }
    __syncthreads();
#pragma unroll
    for (int i = 0; i < 4; ++i) {
        int oc = (tid >> 4) * 4 + i;
        ushort4 h;
        h.x = f2b(tile[(tid & 15) * 4 + 0][oc]);
        h.y = f2b(tile[(tid & 15) * 4 + 1][oc]);
        h.z = f2b(tile[(tid & 15) * 4 + 2][oc]);
        h.w = f2b(tile[(tid & 15) * 4 + 3][oc]);
        *(ushort4*)(out + (long long)(colBase + oc) * 256 + rowBase + (tid & 15) * 4) = h;
    }
}

// ---------------------------------------------------------------------------
// Fused adj pass + agg GEMM (v2: 64-row tile, 256 threads, 512 blocks = 2/CU).
// Reads adj fp32 ONCE, reg-stages to bf16 LDS (write-side swizzle), emits
// adj_bf, computes per-row 1/max(deg,1) in LDS, sum(adj^2) partials, and
// agg = (adj @ x) * deginv -> bf16.
struct AggP {
    const float* adj;            // [32,1024,1024] fp32
    const unsigned short* xT;    // [32,256,1024] bf16
    unsigned short* adj_bf;      // [32,1024,1024] bf16 out
    unsigned short* agg;         // [32,1024,256] bf16 out
    float* asq_part;             // [512]
};

__global__ __launch_bounds__(256) void aggdeg_mfma(AggP p) {
    __shared__ short As[2][2048];      // 64x32
    __shared__ short Bs[2][8192];      // 256x32
    __shared__ float deginv_lds[64];
    __shared__ float sred[256];
    const int tid = threadIdx.x;
    const int wave = tid >> 6, lane = tid & 63;
    const int quad = lane >> 4, l15 = lane & 15;
    const int wn = wave * 64;                      // 4 n-waves, all rows
    const int rowBase = blockIdx.x * 64;
    const long long bz = blockIdx.y;
    const int srow = tid >> 2, kq = tid & 3;       // srow 0..63
    const int sw = (srow >> 1) & 3;
    const int skg = ((kq ^ sw) * 8);
    const int rsw = (l15 >> 1) & 3;

    const float* adjp = p.adj + bz * 1048576 + (long long)(rowBase + srow) * 1024 + kq * 8;
    unsigned short* abf = p.adj_bf + bz * 1048576 + (long long)(rowBase + srow) * 1024 + kq * 8;
    const unsigned short* xTp = p.xT + bz * 262144;

    float4 ra, rb;
    float degacc = 0.f, sqacc = 0.f;

    auto loadA = [&](int t) {
        ra = *(const float4*)(adjp + t * 32);
        rb = *(const float4*)(adjp + t * 32 + 4);
    };
    auto procA = [&](int t, int buf) {
        u16x8 h;
        h[0] = f2b(ra.x); h[1] = f2b(ra.y); h[2] = f2b(ra.z); h[3] = f2b(ra.w);
        h[4] = f2b(rb.x); h[5] = f2b(rb.y); h[6] = f2b(rb.z); h[7] = f2b(rb.w);
        *(u16x8*)(abf + t * 32) = h;
        degacc += (ra.x + ra.y + ra.z + ra.w) + (rb.x + rb.y + rb.z + rb.w);
        sqacc = fmaf(ra.x, ra.x, sqacc); sqacc = fmaf(ra.y, ra.y, sqacc);
        sqacc = fmaf(ra.z, ra.z, sqacc); sqacc = fmaf(ra.w, ra.w, sqacc);
        sqacc = fmaf(rb.x, rb.x, sqacc); sqacc = fmaf(rb.y, rb.y, sqacc);
        sqacc = fmaf(rb.z, rb.z, sqacc); sqacc = fmaf(rb.w, rb.w, sqacc);
        *(u16x8*)(&As[buf][srow * 32 + ((kq ^ sw) * 8)]) = h;
    };
    auto stageB = [&](int t, int buf) {
        char* lb = (char*)Bs[buf] + wave * 1024;
        const unsigned short* src = xTp + (long long)srow * 1024 + t * 32 + skg;
        gl_lds16(src, lb);
        gl_lds16(src + 64 * 1024, lb + 4096);
        gl_lds16(src + 128 * 1024, lb + 8192);
        gl_lds16(src + 192 * 1024, lb + 12288);
    };

    f32x4 acc[4][4] = {{{0.f}}};
    loadA(0);
    stageB(0, 0);
    procA(0, 0);
    __syncthreads();
    int cur = 0;
    for (int t = 0; t < 32; ++t) {
        const bool more = (t + 1 < 32);
        if (more) { loadA(t + 1); stageB(t + 1, cur ^ 1); }
        bf16x8 af[4], bv[4];
#pragma unroll
        for (int i = 0; i < 4; ++i)
            af[i] = *(const bf16x8*)(&As[cur][(i * 16 + l15) * 32 + (quad ^ rsw) * 8]);
#pragma unroll
        for (int j = 0; j < 4; ++j)
            bv[j] = *(const bf16x8*)(&Bs[cur][(wn + j * 16 + l15) * 32 + (quad ^ rsw) * 8]);
#pragma unroll
        for (int i = 0; i < 4; ++i)
#pragma unroll
            for (int j = 0; j < 4; ++j)
                acc[i][j] = __builtin_amdgcn_mfma_f32_16x16x32_bf16(af[i], bv[j], acc[i][j], 0, 0, 0);
        if (more) procA(t + 1, cur ^ 1);
        __syncthreads();
        cur ^= 1;
    }

    // per-row degree: reduce over 4 k-slot lanes (xor 1,2)
    degacc += __shfl_xor(degacc, 1);
    degacc += __shfl_xor(degacc, 2);
    if (kq == 0) deginv_lds[srow] = 1.0f / fmaxf(degacc, 1.0f);
    sred[tid] = sqacc;
    __syncthreads();
    for (int k = 128; k > 0; k >>= 1) {
        if (tid < k) sred[tid] += sred[tid + k];
        __syncthreads();
    }
    if (tid == 0) p.asq_part[bz * 16 + blockIdx.x] = sred[0];

    unsigned short* og = p.agg + bz * 262144;
#pragma unroll
    for (int i = 0; i < 4; ++i)
#pragma unroll
        for (int r = 0; r < 4; ++r) {
            int lrow = i * 16 + quad * 4 + r;
            float sc = deginv_lds[lrow];
            long long ro = (long long)(rowBase + lrow) * 256;
#pragma unroll
            for (int j = 0; j < 4; ++j)
                og[ro + wn + j * 16 + l15] = f2b(acc[i][j][r] * sc);
        }
}

// ---------------------------------------------------------------------------
// MFMA GEMM: C[M,N] = A1[M,K1]·B1t[N,K1]^T (+ A2·B2t^T) (+bias)
// Double-buffered LDS + XOR-swizzled staging. Epilogue options:
//   outF fp32, outH bf16, outT bf16 TRANSPOSED (swizzled LDS round-trip,
//   batch inferred as bz + (row>>10)), dotN coalesced bf16 dot -> dot_part,
//   sq_part = sum(out^2) per block.
struct GemmP {
    const unsigned short* A1; long long sA1; int lda1; int K1;
    const unsigned short* B1; long long sB1; int ldb1;
    const unsigned short* A2; long long sA2; int lda2; int K2;
    const unsigned short* B2; long long sB2; int ldb2;
    float* outF; long long sF;
    unsigned short* outH; long long sH;
    unsigned short* outT; long long sT; int ldt;
    int ldc;
    const float* bias;
    const unsigned short* dotN; long long sDot;
    float* dot_part;
    float* sq_part;
};

__global__ __launch_bounds__(256) void gemm_mfma(GemmP p) {
    __shared__ char smem[32768];     // dbuf staging; reused as 128x128 T-tile
    __shared__ float dred[256];
    const int tid = threadIdx.x;
    const int wave = tid >> 6, lane = tid & 63;
    const int quad = lane >> 4, l15 = lane & 15;
    const int wm = (wave & 1) * 64, wn = (wave >> 1) * 64;
    const long long bz = blockIdx.z;
    const int rowBase = blockIdx.y * 128, colBase = blockIdx.x * 128;
    const int srow = tid >> 2;
    const int skg = (((tid & 3) ^ ((srow >> 1) & 3)) * 8);  // swizzled source k-offset
    const int rsw = (l15 >> 1) & 3;                          // read-side swizzle

    const int n1 = p.K1 >> 5;
    const int n2 = p.A2 ? (p.K2 >> 5) : 0;
    const int nTot = n1 + n2;

    const unsigned short* A1p = p.A1 + bz * p.sA1;
    const unsigned short* B1p = p.B1 + bz * p.sB1;
    const unsigned short* A2p = p.A2 ? p.A2 + bz * p.sA2 : nullptr;
    const unsigned short* B2p = p.B2 ? p.B2 + bz * p.sB2 : nullptr;

    auto stage = [&](int t, int buf) {
        const unsigned short *Ao, *Bo; int lda, ldb, ko;
        if (t < n1) { Ao = A1p; Bo = B1p; lda = p.lda1; ldb = p.ldb1; ko = t * 32; }
        else        { Ao = A2p; Bo = B2p; lda = p.lda2; ldb = p.ldb2; ko = (t - n1) * 32; }
        char* la = smem + buf * 16384 + wave * 1024;
        char* lb = smem + buf * 16384 + 8192 + wave * 1024;
        gl_lds16(Ao + (long long)(rowBase + srow) * lda + ko + skg, la);
        gl_lds16(Ao + (long long)(rowBase + 64 + srow) * lda + ko + skg, la + 4096);
        gl_lds16(Bo + (long long)(colBase + srow) * ldb + ko + skg, lb);
        gl_lds16(Bo + (long long)(colBase + 64 + srow) * ldb + ko + skg, lb + 4096);
    };

    f32x4 acc[4][4] = {{{0.f}}};
    stage(0, 0);
    __syncthreads();
    int cur = 0;
    for (int t = 0; t < nTot; ++t) {
        if (t + 1 < nTot) stage(t + 1, cur ^ 1);
        const short* Ab = (const short*)(smem + cur * 16384);
        const short* Bb = (const short*)(smem + cur * 16384 + 8192);
        bf16x8 af[4], bf[4];
#pragma unroll
        for (int i = 0; i < 4; ++i)
            af[i] = *(const bf16x8*)(Ab + (wm + i * 16 + l15) * 32 + (quad ^ rsw) * 8);
#pragma unroll
        for (int j = 0; j < 4; ++j)
            bf[j] = *(const bf16x8*)(Bb + (wn + j * 16 + l15) * 32 + (quad ^ rsw) * 8);
#pragma unroll
        for (int i = 0; i < 4; ++i)
#pragma unroll
            for (int j = 0; j < 4; ++j)
                acc[i][j] = __builtin_amdgcn_mfma_f32_16x16x32_bf16(af[i], bf[j], acc[i][j], 0, 0, 0);
        __syncthreads();
        cur ^= 1;
    }

    float* oF = p.outF ? p.outF + bz * p.sF : nullptr;
    unsigned short* oH = p.outH ? p.outH + bz * p.sH : nullptr;
    const unsigned short* dN = p.dotN ? p.dotN + bz * p.sDot : nullptr;
    unsigned short* tt = (unsigned short*)smem;   // swizzled 128x128 T-tile
    float bcol[4];
#pragma unroll
    for (int j = 0; j < 4; ++j)
        bcol[j] = p.bias ? p.bias[colBase + wn + j * 16 + l15] : 0.0f;
    float dacc = 0.f;
#pragma unroll
    for (int i = 0; i < 4; ++i) {
        ushort4 tp[4];
#pragma unroll
        for (int r = 0; r < 4; ++r) {
            int row = rowBase + wm + i * 16 + quad * 4 + r;
            long long ro = (long long)row * p.ldc;
#pragma unroll
            for (int j = 0; j < 4; ++j) {
                int col = colBase + wn + j * 16 + l15;
                float v = acc[i][j][r] + bcol[j];
                if (oF) oF[ro + col] = v;
                if (oH) oH[ro + col] = f2b(v);
                if (dN) dacc = fmaf(v, b2f(dN[ro + col]), dacc);
                if (p.sq_part) dacc = fmaf(v, v, dacc);
                ((unsigned short*)&tp[j])[r] = f2b(v);
            }
        }
        if (p.outT) {
            int lr = wm + i * 16 + quad * 4;
#pragma unroll
            for (int j = 0; j < 4; ++j) {
                int lc = wn + j * 16 + l15;
                *(ushort4*)&tt[lc * 128 + (lr ^ ((lc & 15) << 3))] = tp[j];
            }
        }
    }
    if (p.outT) {
        __syncthreads();
#pragma unroll
        for (int u = 0; u < 8; ++u) {
            int idx = u * 256 + tid;
            int c = idx >> 4;                // 0..127
            int r0 = (idx & 15) * 8;         // 0..120
            u16x8 val = *(const u16x8*)&tt[c * 128 + (r0 ^ ((c & 15) << 3))];
            int gr = rowBase + r0;
            long long tb = bz + (gr >> 10);
            *(u16x8*)(p.outT + tb * p.sT + (long long)(colBase + c) * p.ldt + (gr & 1023)) = val;
        }
    }
    if (p.dot_part || p.sq_part) {
        dred[tid] = dacc;
        __syncthreads();
        for (int k = 128; k > 0; k >>= 1) {
            if (tid < k) dred[tid] += dred[tid + k];
            __syncthreads();
        }
        if (tid == 0) {
            float* dst = p.dot_part ? p.dot_part : p.sq_part;
            dst[((long long)bz * gridDim.y + blockIdx.y) * gridDim.x + blockIdx.x] = dred[0];
        }
    }
}

// ---------------------------------------------------------------------------
// Fused SAGE pre-norm GEMM (v2: 64-row tile, 256 threads, 512 blocks = 2/CU):
// out[32768,256] = l2norm_relu(A1·B1t^T + A2·B2t^T + bias), bf16 out.
struct SageP {
    const unsigned short* A1; const unsigned short* B1;
    const unsigned short* A2; const unsigned short* B2;
    const float* bias;
    unsigned short* out;
};

__global__ __launch_bounds__(256) void sage_mfma(SageP p) {
    __shared__ short As[2][2048];      // 64x32
    __shared__ short Bs[2][8192];      // 256x32
    __shared__ float rsum[4][64];
    const int tid = threadIdx.x;
    const int wave = tid >> 6, lane = tid & 63;
    const int quad = lane >> 4, l15 = lane & 15;
    const int wn = wave * 64;                  // 4 n-waves, all rows
    const int rowBase = blockIdx.x * 64;
    const int srow = tid >> 2;                 // 0..63
    const int skg = (((tid & 3) ^ ((srow >> 1) & 3)) * 8);
    const int rsw = (l15 >> 1) & 3;

    auto stage = [&](int t, int buf) {
        const unsigned short* Ao = (t < 8) ? p.A1 : p.A2;
        const unsigned short* Bo = (t < 8) ? p.B1 : p.B2;
        int ko = (t & 7) * 32;
        char* la = (char*)As[buf] + wave * 1024;
        char* lb = (char*)Bs[buf] + wave * 1024;
        gl_lds16(Ao + (long long)(rowBase + srow) * 256 + ko + skg, la);
        const unsigned short* bs = Bo + (long long)srow * 256 + ko + skg;
        gl_lds16(bs, lb);
        gl_lds16(bs + 64 * 256, lb + 4096);
        gl_lds16(bs + 128 * 256, lb + 8192);
        gl_lds16(bs + 192 * 256, lb + 12288);
    };

    f32x4 acc[4][4] = {{{0.f}}};
    stage(0, 0);
    __syncthreads();
    int cur = 0;
    for (int t = 0; t < 16; ++t) {
        if (t + 1 < 16) stage(t + 1, cur ^ 1);
        bf16x8 af[4], bf[4];
#pragma unroll
        for (int i = 0; i < 4; ++i)
            af[i] = *(const bf16x8*)(&As[cur][(i * 16 + l15) * 32 + (quad ^ rsw) * 8]);
#pragma unroll
        for (int j = 0; j < 4; ++j)
            bf[j] = *(const bf16x8*)(&Bs[cur][(wn + j * 16 + l15) * 32 + (quad ^ rsw) * 8]);
#pragma unroll
        for (int i = 0; i < 4; ++i)
#pragma unroll
            for (int j = 0; j < 4; ++j)
                acc[i][j] = __builtin_amdgcn_mfma_f32_16x16x32_bf16(af[i], bf[j], acc[i][j], 0, 0, 0);
        __syncthreads();
        cur ^= 1;
    }

    float bcol[4];
#pragma unroll
    for (int j = 0; j < 4; ++j)
        bcol[j] = p.bias[wn + j * 16 + l15];

#pragma unroll
    for (int i = 0; i < 4; ++i)
#pragma unroll
        for (int r = 0; r < 4; ++r) {
            float ss = 0.f;
#pragma unroll
            for (int j = 0; j < 4; ++j) {
                float v = acc[i][j][r] + bcol[j];
                ss = fmaf(v, v, ss);
            }
#pragma unroll
            for (int off = 1; off < 16; off <<= 1) ss += __shfl_xor(ss, off);
            if (l15 == 0) rsum[wave][i * 16 + quad * 4 + r] = ss;
        }
    __syncthreads();
#pragma unroll
    for (int i = 0; i < 4; ++i)
#pragma unroll
        for (int r = 0; r < 4; ++r) {
            int lrow = i * 16 + quad * 4 + r;
            float tot = rsum[0][lrow] + rsum[1][lrow] + rsum[2][lrow] + rsum[3][lrow];
            float rn = 1.0f / fmaxf(sqrtf(tot), 1e-12f);
            long long ro = (long long)(rowBase + lrow) * 256;
#pragma unroll
            for (int j = 0; j < 4; ++j) {
                float v = (acc[i][j][r] + bcol[j]) * rn;
                p.out[ro + wn + j * 16 + l15] = f2b(fmaxf(v, 0.0f));
            }
        }
}

// ---------------------------------------------------------------------------
// Merged: xp = sT·nxT^T (fp32) AND G = sT·sT^T (bf16 + ssq/tr partials).
// v2: 64x64 tiles, grid (4,4,32) = 512 blocks, 256 threads.
__global__ __launch_bounds__(256) void xpg_mfma(
    const unsigned short* __restrict__ sT, const unsigned short* __restrict__ nxT,
    float* __restrict__ xp, unsigned short* __restrict__ gout,
    float* __restrict__ ssq_part, float* __restrict__ tr_part) {
    __shared__ char smem[24576];   // A:0, B1:8192, B2:16384 (each 2x4KB dbuf)
    __shared__ float red[2][256];
    const int tid = threadIdx.x;
    const int wave = tid >> 6, lane = tid & 63;
    const int quad = lane >> 4, l15 = lane & 15;
    const int wm = (wave & 1) * 32, wn = (wave >> 1) * 32;
    const long long bz = blockIdx.z;
    const unsigned short* S = sT + bz * 262144;
    const unsigned short* NX = nxT + bz * 262144;
    const int rowBase = blockIdx.y * 64, colBase = blockIdx.x * 64;
    const int srow = tid >> 2;
    const int skg = (((tid & 3) ^ ((srow >> 1) & 3)) * 8);
    const int rsw = (l15 >> 1) & 3;

    auto stage = [&](int t, int buf) {
        int ko = t * 32;
        char* la = smem + buf * 4096 + wave * 1024;
        char* l1 = smem + 8192 + buf * 4096 + wave * 1024;
        char* l2 = smem + 16384 + buf * 4096 + wave * 1024;
        gl_lds16(S + (long long)(rowBase + srow) * 1024 + ko + skg, la);
        gl_lds16(NX + (long long)(colBase + srow) * 1024 + ko + skg, l1);
        gl_lds16(S + (long long)(colBase + srow) * 1024 + ko + skg, l2);
    };

    f32x4 a1[2][2] = {{{0.f}}};
    f32x4 a2[2][2] = {{{0.f}}};
    stage(0, 0);
    __syncthreads();
    int cur = 0;
    for (int t = 0; t < 32; ++t) {
        if (t + 1 < 32) stage(t + 1, cur ^ 1);
        const short* Ab  = (const short*)(smem + cur * 4096);
        const short* B1b = (const short*)(smem + 8192 + cur * 4096);
        const short* B2b = (const short*)(smem + 16384 + cur * 4096);
        bf16x8 af[2], b1[2], b2[2];
#pragma unroll
        for (int i = 0; i < 2; ++i)
            af[i] = *(const bf16x8*)(Ab + (wm + i * 16 + l15) * 32 + (quad ^ rsw) * 8);
#pragma unroll
        for (int j = 0; j < 2; ++j) {
            int co = (wn + j * 16 + l15) * 32 + (quad ^ rsw) * 8;
            b1[j] = *(const bf16x8*)(B1b + co);
            b2[j] = *(const bf16x8*)(B2b + co);
        }
#pragma unroll
        for (int i = 0; i < 2; ++i)
#pragma unroll
            for (int j = 0; j < 2; ++j) {
                a1[i][j] = __builtin_amdgcn_mfma_f32_16x16x32_bf16(af[i], b1[j], a1[i][j], 0, 0, 0);
                a2[i][j] = __builtin_amdgcn_mfma_f32_16x16x32_bf16(af[i], b2[j], a2[i][j], 0, 0, 0);
            }
        __syncthreads();
        cur ^= 1;
    }

    float* xo = xp + bz * 65536;
    unsigned short* go = gout + bz * 65536;
    float ssq = 0.f, tr = 0.f;
#pragma unroll
    for (int i = 0; i < 2; ++i)
#pragma unroll
        for (int r = 0; r < 4; ++r) {
            int row = rowBase + wm + i * 16 + quad * 4 + r;
            long long ro = (long long)row * 256;
#pragma unroll
            for (int j = 0; j < 2; ++j) {
                int col = colBase + wn + j * 16 + l15;
                xo[ro + col] = a1[i][j][r];
                float v = a2[i][j][r];
                go[ro + col] = f2b(v);
                ssq = fmaf(v, v, ssq);
                if (row == col) tr += v;
            }
        }
    red[0][tid] = ssq;
    red[1][tid] = tr;
    __syncthreads();
    for (int k = 128; k > 0; k >>= 1) {
        if (tid < k) {
            red[0][tid] += red[0][tid + k];
            red[1][tid] += red[1][tid + k];
        }
        __syncthreads();
    }
    if (tid == 0) {
        int bid = (int)(blockIdx.z * 16 + blockIdx.y * 4 + blockIdx.x);
        ssq_part[bid] = red[0][0];
        tr_part[bid] = red[1][0];
    }
}

// ---------------------------------------------------------------------------
// trq = sum( (P·G) ∘ (G·P) ) = tr(G P^T G P)  [G symmetric].
// v2: 64x64 tiles, grid (4,4,32) = 512 blocks, 256 threads.
__global__ __launch_bounds__(256) void trq_mfma(
    const unsigned short* __restrict__ G, const unsigned short* __restrict__ P,
    const unsigned short* __restrict__ PT, float* __restrict__ trq_part) {
    __shared__ short sm[4][2][2048];   // [GA,PB,PA,GB][buf][64x32]
    __shared__ float dred[256];
    const int tid = threadIdx.x;
    const int wave = tid >> 6, lane = tid & 63;
    const int quad = lane >> 4, l15 = lane & 15;
    const int wm = (wave & 1) * 32, wn = (wave >> 1) * 32;
    const long long bz = blockIdx.z;
    const int rowBase = blockIdx.y * 64, colBase = blockIdx.x * 64;
    const int srow = tid >> 2;
    const int skg = (((tid & 3) ^ ((srow >> 1) & 3)) * 8);
    const int rsw = (l15 >> 1) & 3;
    const unsigned short* Gb = G + bz * 65536;
    const unsigned short* Pb = P + bz * 65536;
    const unsigned short* PTb = PT + bz * 65536;

    auto stage = [&](int t, int buf) {
        int ko = t * 32;
        long long rr = (long long)(rowBase + srow) * 256 + ko + skg;
        long long cc = (long long)(colBase + srow) * 256 + ko + skg;
        gl_lds16(Gb + rr,  (char*)sm[0][buf] + wave * 1024);
        gl_lds16(PTb + cc, (char*)sm[1][buf] + wave * 1024);
        gl_lds16(Pb + rr,  (char*)sm[2][buf] + wave * 1024);
        gl_lds16(Gb + cc,  (char*)sm[3][buf] + wave * 1024);
    };

    f32x4 a1[2][2] = {{{0.f}}};
    f32x4 a3[2][2] = {{{0.f}}};
    stage(0, 0);
    __syncthreads();
    int cur = 0;
    for (int t = 0; t < 8; ++t) {
        if (t + 1 < 8) stage(t + 1, cur ^ 1);
        bf16x8 gA[2], pB[2], pA[2], gB[2];
#pragma unroll
        for (int i = 0; i < 2; ++i) {
            int ro = (wm + i * 16 + l15) * 32 + (quad ^ rsw) * 8;
            gA[i] = *(const bf16x8*)(&sm[0][cur][ro]);
            pA[i] = *(const bf16x8*)(&sm[2][cur][ro]);
        }
#pragma unroll
        for (int j = 0; j < 2; ++j) {
            int co = (wn + j * 16 + l15) * 32 + (quad ^ rsw) * 8;
            pB[j] = *(const bf16x8*)(&sm[1][cur][co]);
            gB[j] = *(const bf16x8*)(&sm[3][cur][co]);
        }
#pragma unroll
        for (int i = 0; i < 2; ++i)
#pragma unroll
            for (int j = 0; j < 2; ++j) {
                a1[i][j] = __builtin_amdgcn_mfma_f32_16x16x32_bf16(gA[i], pB[j], a1[i][j], 0, 0, 0);
                a3[i][j] = __builtin_amdgcn_mfma_f32_16x16x32_bf16(pA[i], gB[j], a3[i][j], 0, 0, 0);
            }
        __syncthreads();
        cur ^= 1;
    }
    float dacc = 0.f;
#pragma unroll
    for (int i = 0; i < 2; ++i)
#pragma unroll
        for (int j = 0; j < 2; ++j)
#pragma unroll
            for (int r = 0; r < 4; ++r)
                dacc = fmaf(a3[i][j][r], a1[i][j][r], dacc);
    dred[tid] = dacc;
    __syncthreads();
    for (int k = 128; k > 0; k >>= 1) {
        if (tid < k) dred[tid] += dred[tid + k];
        __syncthreads();
    }
    if (tid == 0)
        trq_part[blockIdx.z * 16 + blockIdx.y * 4 + blockIdx.x] = dred[0];
}

// ---------------------------------------------------------------------------
// Pass 1 over bf16 logits: per-row softmax stats (max, 1/den) + column scores.
__global__ __launch_bounds__(256) void smstat_kernel(
    const unsigned short* __restrict__ s, float* __restrict__ rowmax,
    float* __restrict__ rowrden, float* __restrict__ scores) {
    __shared__ float sacc[4][256];
    const int tid = threadIdx.x;
    const int wave = tid >> 6, lane = tid & 63;
    const int b = blockIdx.x >> 5;
    const long long row0 = (long long)blockIdx.x * 32;
    float c0 = 0.f, c1 = 0.f, c2 = 0.f, c3 = 0.f;
#pragma unroll
    for (int q = 0; q < 8; ++q) {
        long long row = row0 + wave * 8 + q;
        const ushort4 v4 = *(const ushort4*)(s + row * 256 + lane * 4);
        float vx = b2f(v4.x), vy = b2f(v4.y), vz = b2f(v4.z), vw = b2f(v4.w);
        float m = fmaxf(fmaxf(vx, vy), fmaxf(vz, vw));
#pragma unroll
        for (int off = 32; off > 0; off >>= 1) m = fmaxf(m, __shfl_xor(m, off));
        float e0 = expf(vx - m), e1 = expf(vy - m);
        float e2 = expf(vz - m), e3 = expf(vw - m);
        float den = e0 + e1 + e2 + e3;
#pragma unroll
        for (int off = 32; off > 0; off >>= 1) den += __shfl_xor(den, off);
        float rd = 1.0f / den;
        if (lane == 0) { rowmax[row] = m; rowrden[row] = rd; }
        c0 = fmaf(e0, rd, c0); c1 = fmaf(e1, rd, c1);
        c2 = fmaf(e2, rd, c2); c3 = fmaf(e3, rd, c3);
    }
    sacc[wave][lane * 4 + 0] = c0;
    sacc[wave][lane * 4 + 1] = c1;
    sacc[wave][lane * 4 + 2] = c2;
    sacc[wave][lane * 4 + 3] = c3;
    __syncthreads();
    float t0 = sacc[0][tid] + sacc[1][tid] + sacc[2][tid] + sacc[3][tid];
    atomicAdd(&scores[b * 256 + tid], t0);
}

// fused top-k threshold + sigmoid gate
__global__ __launch_bounds__(256) void topkgate_kernel(const float* __restrict__ scores,
                                                       float* __restrict__ gate) {
    __shared__ float vals[256];
    __shared__ float th;
    int b = blockIdx.x, tid = threadIdx.x;
    float v = scores[b * 256 + tid];
    vals[tid] = v;
    __syncthreads();
    int rank = 0;
    for (int j = 0; j < 256; ++j) {
        float u = vals[j];
        rank += (u > v) || (u == v && j < tid);
    }
    if (rank == 127) th = v;
    __syncthreads();
    float z = (v - th) * 10.0f;  // 1/TEMP
    gate[b * 256 + tid] = 1.0f / (1.0f + expf(-z));
}

// ---------------------------------------------------------------------------
// Pass 2: gated softmax from bf16 logits + stats. Writes s fp32 (final out),
// s_bf (in-place over logits; slog/sbf intentionally NOT restrict — alias),
// sT bf16 transposed, entropy partials.
__global__ __launch_bounds__(256) void gatefin_kernel(
    const unsigned short* slog, float* __restrict__ s,
    const float* __restrict__ rowmax, const float* __restrict__ rowrden,
    const float* __restrict__ gate, unsigned short* sbf,
    unsigned short* __restrict__ sT, float* __restrict__ ent_part) {
    __shared__ float tile[64][65];
    __shared__ float red[256];
    const int tid = threadIdx.x;
    const long long bz = blockIdx.z;
    const int rowBase = blockIdx.y * 64, colBase = blockIdx.x * 64;
    const int c4 = (tid & 15) * 4;
    const float g0 = gate[bz * 256 + colBase + c4 + 0];
    const float g1 = gate[bz * 256 + colBase + c4 + 1];
    const float g2 = gate[bz * 256 + colBase + c4 + 2];
    const float g3 = gate[bz * 256 + colBase + c4 + 3];
    float ent = 0.f;
#pragma unroll
    for (int i = 0; i < 4; ++i) {
        int r = (tid >> 4) * 4 + i;
        long long grow = bz * 1024 + rowBase + r;
        ushort4 lv = *(const ushort4*)(slog + grow * 256 + colBase + c4);
        float m = rowmax[grow], rd = rowrden[grow];
        float p0 = expf(b2f(lv.x) - m) * rd * g0;
        float p1 = expf(b2f(lv.y) - m) * rd * g1;
        float p2 = expf(b2f(lv.z) - m) * rd * g2;
        float p3 = expf(b2f(lv.w) - m) * rd * g3;
        float4 pv; pv.x = p0; pv.y = p1; pv.z = p2; pv.w = p3;
        *(float4*)(s + grow * 256 + colBase + c4) = pv;
        ushort4 h;
        h.x = f2b(p0); h.y = f2b(p1); h.z = f2b(p2); h.w = f2b(p3);
        *(ushort4*)(sbf + grow * 256 + colBase + c4) = h;
        tile[r][c4 + 0] = p0; tile[r][c4 + 1] = p1;
        tile[r][c4 + 2] = p2; tile[r][c4 + 3] = p3;
        ent -= p0 * logf(p0 + 1e-15f) + p1 * logf(p1 + 1e-15f) +
               p2 * logf(p2 + 1e-15f) + p3 * logf(p3 + 1e-15f);
    }
    __syncthreads();
#pragma unroll
    for (int i = 0; i < 4; ++i) {
        int oc = (tid >> 4) * 4 + i;
        ushort4 h;
        h.x = f2b(tile[c4 + 0][oc]);
        h.y = f2b(tile[c4 + 1][oc]);
        h.z = f2b(tile[c4 + 2][oc]);
        h.w = f2b(tile[c4 + 3][oc]);
        *(ushort4*)(sT + bz * 262144 + (long long)(colBase + oc) * 1024 + rowBase + c4) = h;
    }
    red[tid] = ent;
    __syncthreads();
    for (int k = 128; k > 0; k >>= 1) {
        if (tid < k) red[tid] += red[tid + k];
        __syncthreads();
    }
    if (tid == 0)
        ent_part[((long long)bz * gridDim.y + blockIdx.y) * gridDim.x + blockIdx.x] = red[0];
}

// ---------------------------------------------------------------------------
__global__ __launch_bounds__(256) void finalize_kernel(const float* __restrict__ ent_part,
                                                       const float* __restrict__ asq_part,
                                                       const float* __restrict__ psq_part,
                                                       const float* __restrict__ sdot_part,
                                                       const float* __restrict__ trq_part,
                                                       const float* __restrict__ ssq_part,
                                                       const float* __restrict__ tr_part,
                                                       float* __restrict__ scal) {
    __shared__ float red[7][256];
    int tid = threadIdx.x;
    float e = 0.f, asq = 0.f, psq = 0.f, sd = 0.f, tq = 0.f, clu = 0.f, ssqa = 0.f;
    for (int i = tid; i < 2048; i += 256) e += ent_part[i];
    for (int i = tid; i < 512; i += 256) asq += asq_part[i];
    if (tid < 128) psq = psq_part[tid];
    for (int i = tid; i < 512; i += 256) sd += sdot_part[i];
    for (int i = tid; i < 512; i += 256) tq += trq_part[i];
    if (tid < 32) {
        float ssq = 0.f, tr = 0.f;
#pragma unroll
        for (int i = 0; i < 16; ++i) {
            ssq += ssq_part[tid * 16 + i];
            tr  += tr_part[tid * 16 + i];
        }
        ssqa = ssq;
        float fro = fmaxf(sqrtf(ssq), 1e-12f);
        float val = ssq / (fro * fro) - tr / (8.0f * fro) + 1.0f;  // ||G/fro - I/16||_F^2
        clu = sqrtf(fmaxf(val, 0.0f));
    }
    red[0][tid] = e; red[1][tid] = asq; red[2][tid] = psq; red[3][tid] = sd;
    red[4][tid] = tq; red[5][tid] = clu; red[6][tid] = ssqa;
    __syncthreads();
    for (int k = 128; k > 0; k >>= 1) {
        if (tid < k) {
#pragma unroll
            for (int q = 0; q < 7; ++q) red[q][tid] += red[q][tid + k];
        }
        __syncthreads();
    }
    if (tid == 0) {
        const float numel = 33554432.0f;  // B*N*N
        float linksq  = red[1][0] - 2.0f * red[3][0] + red[6][0];   // asq - 2<S,AS> + ||G||^2
        float reconsq = red[1][0] - 2.0f * red[2][0] + red[4][0];   // asq - 2||P||^2 + tr(GP'GP)
        scal[0] = sqrtf(fmaxf(linksq, 0.0f)) / numel;   // link
        scal[1] = red[0][0] / 32768.0f;                 // ent
        scal[2] = red[5][0] / 32.0f;                    // clu
        scal[3] = sqrtf(fmaxf(reconsq, 0.0f)) / numel;  // recon
    }
}

// ---------------------------------------------------------------------------
extern "C" void kernel_launch(void* const* d_in, const int* in_sizes, int n_in,
                              void* d_out, int out_size, void* d_ws, size_t ws_size,
                              hipStream_t stream) {
    const float* x    = (const float*)d_in[0];
    const float* adj  = (const float*)d_in[1];
    const float* Wr_p = (const float*)d_in[2];
    const float* br_p = (const float*)d_in[3];
    const float* Wo_p = (const float*)d_in[4];
    const float* Wl_p = (const float*)d_in[5];
    const float* bl_p = (const float*)d_in[6];
    const float* Wr_e = (const float*)d_in[7];
    const float* br_e = (const float*)d_in[8];
    const float* Wo_e = (const float*)d_in[9];
    const float* Wl_e = (const float*)d_in[10];
    const float* bl_e = (const float*)d_in[11];

    float* out    = (float*)d_out;
    float* xp     = out;              // [32,256,256]
    float* adj_p  = out + 2097152;    // [32,256,256]
    float* s      = out + 4194304;    // [32,1024,256] fp32
    float* scal   = out + 12582912;
    float* node_x = out + 12582916;   // [32,1024,256] fp32

    char* w = (char*)d_ws;
    float* rowmax     = (float*)w; w += 32768 * 4;
    float* scores     = (float*)w; w += 8192 * 4;
    float* thresh     = (float*)w; w += 256 * 4;     // unused, layout keep
    float* gatep      = (float*)w; w += 8192 * 4;
    float* ent_part   = (float*)w; w += 32768 * 4;   // 2048 used
    float* asq_part   = (float*)w; w += 8192 * 4;    // 512 used
    float* psq_part   = (float*)w; w += 512 * 4;     // 128 used
    float* sdot_part  = (float*)w; w += 1024 * 4;    // 512 used
    float* trq_part   = (float*)w; w += 512 * 4;     // 512 used
    float* ssq_part   = (float*)w; w += 512 * 4;     // 512 used
    float* tr_part    = (float*)w; w += 512 * 4;     // 512 used
    unsigned short* WT   = (unsigned short*)w; w += 6LL * 65536 * 2;
    unsigned short* bufA = (unsigned short*)w; w += 33554432LL * 2;  // adj_bf
    unsigned short* bufB = (unsigned short*)w; w += 8388608LL * 2;   // x_bf -> {G_bf, PT_bf}
    unsigned short* bufC = (unsigned short*)w; w += 8388608LL * 2;   // xT_bf -> sT_bf
    unsigned short* bufD = (unsigned short*)w; w += 8388608LL * 2;   // agg_bf -> nxT_bf
    unsigned short* bufE = (unsigned short*)w; w += 8388608LL * 2;   // h_bf
    unsigned short* bufF = (unsigned short*)w; w += 8388608LL * 2;   // aTsT_bf
    unsigned short* bufG = (unsigned short*)w; w += 8388608LL * 2;   // logits_bf -> s_bf
    unsigned short* bufH = (unsigned short*)w; w += 2097152LL * 2;   // rowrden, then P_bf

    unsigned short* G_bf  = bufB;                        // [32,256,256] bf16
    unsigned short* PT_bf = bufB + 2097152;              // [32,256,256] bf16
    float* rowrden = (float*)bufH;   // bufH not P_bf until step 11
    (void)thresh;

    hipMemsetAsync(scores, 0, 8192 * sizeof(float), stream);

    // 1) x -> x_bf + xT_bf
    convt_kernel<<<dim3(4, 16, 32), 256, 0, stream>>>(
        x, 262144LL, 256, bufB, 262144LL, bufC, 262144LL, 1024);

    // 2) weights -> transposed bf16
    WPtrs wp;
    wp.in[0] = Wr_p; wp.in[1] = Wo_p; wp.in[2] = Wl_p;
    wp.in[3] = Wr_e; wp.in[4] = Wo_e; wp.in[5] = Wl_e;
    for (int i = 0; i < 6; ++i) wp.out[i] = WT + (long long)i * 65536;
    wconv_kernel<<<dim3(4, 4, 6), 256, 0, stream>>>(wp);

    // 3) fused adj pass: adj_bf + deg (in LDS) + asq + agg = (adj@x)/deg
    //    v2: 64-row tiles, 512 blocks (2/CU)
    AggP ap;
    ap.adj = adj; ap.xT = bufC; ap.adj_bf = bufA; ap.agg = bufD; ap.asq_part = asq_part;
    aggdeg_mfma<<<dim3(16, 32), 256, 0, stream>>>(ap);

    // 4) pool pre-norm fused: h_p = l2relu(agg@Wr_p + x@Wo_p + br_p) -> bufE
    SageP sp;
    sp.A1 = bufD; sp.B1 = WT + 0 * 65536;
    sp.A2 = bufB; sp.B2 = WT + 1 * 65536;
    sp.bias = br_p; sp.out = bufE;
    sage_mfma<<<512, 256, 0, stream>>>(sp);

    GemmP g;
    // 5) s_logits = h @ Wl_p + bl_p -> bf16 logits (bufG)
    g = {};
    g.A1 = bufE; g.sA1 = 0; g.lda1 = 256; g.K1 = 256; g.B1 = WT + 2 * 65536; g.sB1 = 0; g.ldb1 = 256;
    g.outH = bufG; g.sH = 0; g.ldc = 256; g.bias = bl_p;
    gemm_mfma<<<dim3(2, 256, 1), 256, 0, stream>>>(g);

    // 6) embed pre-norm fused -> bufE
    sp.A1 = bufD; sp.B1 = WT + 3 * 65536;
    sp.A2 = bufB; sp.B2 = WT + 4 * 65536;
    sp.bias = br_e; sp.out = bufE;
    sage_mfma<<<512, 256, 0, stream>>>(sp);

    // 7) node_x = h_e @ Wl_e + bl_e (fp32) + transposed bf16 -> bufD (nxT)
    g = {};
    g.A1 = bufE; g.sA1 = 0; g.lda1 = 256; g.K1 = 256; g.B1 = WT + 5 * 65536; g.sB1 = 0; g.ldb1 = 256;
    g.outF = node_x; g.sF = 0; g.ldc = 256; g.bias = bl_e;
    g.outT = bufD; g.sT = 262144; g.ldt = 1024;
    gemm_mfma<<<dim3(2, 256, 1), 256, 0, stream>>>(g);

    // 8) softmax stats + scores; topk+gate; gated finalize (s, s_bf, sT, ent)
    smstat_kernel<<<1024, 256, 0, stream>>>(bufG, rowmax, rowrden, scores);
    topkgate_kernel<<<32, 256, 0, stream>>>(scores, gatep);
    gatefin_kernel<<<dim3(4, 16, 32), 256, 0, stream>>>(
        bufG, s, rowmax, rowrden, gatep, bufG, bufC, ent_part);

    // 9) xp = sT·nxT^T (fp32) + G = sT·sT^T (bf16 + ssq/tr) — merged, 512 blocks
    xpg_mfma<<<dim3(4, 4, 32), 256, 0, stream>>>(bufC, bufD, xp, G_bf, ssq_part, tr_part);

    // 10) aTs = adj · s: transposed bf16 -> bufF, link dot <S, A·S> -> sdot
    g = {};
    g.A1 = bufA; g.sA1 = 1048576; g.lda1 = 1024; g.K1 = 1024;
    g.B1 = bufC; g.sB1 = 262144; g.ldb1 = 1024;
    g.ldc = 256;
    g.outT = bufF; g.sT = 262144; g.ldt = 1024;
    g.dotN = bufG; g.sDot = 262144; g.dot_part = sdot_part;
    gemm_mfma<<<dim3(2, 8, 32), 256, 0, stream>>>(g);

    // 11) adj_p = sT · aTsT^T: fp32 out + P_bf + PT_bf + ||P||^2 partials
    g = {};
    g.A1 = bufC; g.sA1 = 262144; g.lda1 = 1024; g.K1 = 1024;
    g.B1 = bufF; g.sB1 = 262144; g.ldb1 = 1024;
    g.outF = adj_p; g.sF = 65536; g.ldc = 256;
    g.outH = bufH; g.sH = 65536;
    g.outT = PT_bf; g.sT = 65536; g.ldt = 256;
    g.sq_part = psq_part;
    gemm_mfma<<<dim3(2, 2, 32), 256, 0, stream>>>(g);

    // 12) trq = <P·G, G·P> (recon trace term), register-local dot, 512 blocks
    trq_mfma<<<dim3(4, 4, 32), 256, 0, stream>>>(G_bf, bufH, PT_bf, trq_part);

    // 13) finalize
    finalize_kernel<<<1, 256, 0, stream>>>(ent_part, asq_part, psq_part, sdot_part,
                                           trq_part, ssq_part, tr_part, scal);
}